// Round 7
// baseline (302.613 us; speedup 1.0000x reference)
//
#include <hip/hip_runtime.h>
#include <stdint.h>

typedef unsigned short u16;
typedef unsigned int u32;

using bf16x8 = __attribute__((ext_vector_type(8))) short;
using f32x4  = __attribute__((ext_vector_type(4))) float;

#define DEVINL __device__ __forceinline__

DEVINL float b2f(u16 u) { return __builtin_bit_cast(float, (u32)u << 16); }
DEVINL u16 f2b(float f) {
  u32 u = __builtin_bit_cast(u32, f);
  u += 0x7FFFu + ((u >> 16) & 1u);   // round-to-nearest-even
  return (u16)(u >> 16);
}

DEVINL void gll16(const u16* src, u16* dst) {
  __builtin_amdgcn_global_load_lds(
      (const __attribute__((address_space(1))) void*)(uintptr_t)src,
      (__attribute__((address_space(3))) void*)(uintptr_t)dst, 16, 0, 0);
}

#define MFMA __builtin_amdgcn_mfma_f32_16x16x32_bf16
#define NROLE 6

// ---------------------------------------------------------------- mega0:
// transposes (blocks 0..1151) | role_count (1152..1279) | rnn copy (1280..1407).
DEVINL void tp_tile(const float* __restrict__ s, u16* __restrict__ d,
                    int R, int C, int bx, int by, int z)
{
  __shared__ u16 tile[32][33];
  const size_t mstride = (size_t)R * C;
  s += (size_t)z * mstride;
  d += (size_t)z * mstride;
  int r0 = bx * 32, c0 = by * 32;
  int tx = threadIdx.x & 31, ty = threadIdx.x >> 5;
#pragma unroll
  for (int i = 0; i < 32; i += 8)
    tile[ty + i][tx] = f2b(s[(size_t)(r0 + ty + i) * C + (c0 + tx)]);
  __syncthreads();
#pragma unroll
  for (int i = 0; i < 32; i += 8)
    d[(size_t)(c0 + ty + i) * R + (r0 + tx)] = tile[tx][ty + i];
}

__global__ __launch_bounds__(256) void mega0(
    const float* W0, const float* W1, const float* Wr0, const float* Wr1, const float* Wh0,
    u16* W0t, u16* W1t, u16* Wr0t, u16* Wr1t, u16* Wh0t,
    const int* __restrict__ rid, int* __restrict__ blkCnt,
    const float* __restrict__ rnn, float* __restrict__ outRnn)
{
  int b = blockIdx.x;
  const int tid = threadIdx.x;
  if (b < 1152) {
    if (b < 128)      {            tp_tile(W0, W0t, 256, 512, b % 8,  b / 8, 0); }
    else if (b < 384) { b -= 128;  tp_tile(W1, W1t, 512, 512, b % 16, b / 16, 0); }
    else if (b < 576) { b -= 384;  int t = b / 8;  tp_tile(Wr0, Wr0t, 256, 128, b % 8,  t % 4,  t / 4); }
    else if (b < 960) { b -= 576;  int t = b / 4;  tp_tile(Wr1, Wr1t, 128, 512, b % 4,  t % 16, t / 16); }
    else              { b -= 960;  int t = b / 16; tp_tile(Wh0, Wh0t, 512, 64,  b % 16, t % 2,  t / 2); }
  } else if (b < 1280) {
    b -= 1152;
    __shared__ int h[NROLE];
    if (tid < NROLE) h[tid] = 0;
    __syncthreads();
    atomicAdd(&h[rid[b * 256 + tid]], 1);
    __syncthreads();
    if (tid < NROLE) blkCnt[b * NROLE + tid] = h[tid];
  } else {
    b -= 1280;
    const float4* src = (const float4*)rnn;
    float4* dst = (float4*)outRnn;
    int base = (b * 256 + tid) * 4;
#pragma unroll
    for (int i = 0; i < 4; ++i) dst[base + i] = src[base + i];
  }
}

// ---------------------------------------------------------------- base2v (32-row tile):
// blocks 0..1023: fused obs-LN + gemm0 + LN0 + gemm1 + LN1 for 32 rows.
//   LDS 33792 B -> 4 blocks/CU (16 waves/CU; round-6's 64-row tile was
//   2 blocks/CU, latency-bound at 22% occupancy).
//   Epilogue: LN1 -> LDS linear [32][512] (overlays dead e0) -> coalesced
//   uint4 copy to global (round-6 scalar u16 stores caused ~17 MB write-amp).
// blocks 1024..1151: fill2 (scan + bucket fill), verbatim.
// LDS map (u16 units):
//   A0  [0,8192)     32x256 swizzled (dead after gemm0)
//   e0  [0,16384)    32x512 swizzled (overlays A0; then overlaid by out-tile)
//   red [16384,16896)  redS 128 f32 | redSS 128 f32
__global__ __launch_bounds__(256, 4) void base2v(
    const float* __restrict__ obs, const float* __restrict__ fn_s,
    const float* __restrict__ fn_b, const u16* __restrict__ W0t,
    const float* __restrict__ b0, const float* __restrict__ ln0sc,
    const float* __restrict__ ln0bi, const u16* __restrict__ W1t,
    const float* __restrict__ b1, const float* __restrict__ ln1sc,
    const float* __restrict__ ln1bi, u16* __restrict__ obs_n,
    u16* __restrict__ C,
    const int* __restrict__ rid, const int* __restrict__ blkCnt,
    int* __restrict__ bucket, int* __restrict__ baseArr, int* __restrict__ cntArr)
{
  __shared__ __align__(16) u16 smem[16896];   // 33792 B
  const int tid = threadIdx.x;

  if (blockIdx.x >= 1024) {
    const int bx = blockIdx.x - 1024;
    int* c = (int*)smem;
    int* preArr = c + 768;
    int* scnt   = c + 776;
    int* sbase  = c + 784;
    int* h      = c + 792;
    for (int i = tid; i < 128 * NROLE; i += 256) c[i] = blkCnt[i];
    if (tid < NROLE) h[tid] = 0;
    __syncthreads();
    if (tid < NROLE) {
      int k = tid, run = 0, pre = 0;
      for (int b = 0; b < 128; ++b) { if (b == bx) pre = run; run += c[b * NROLE + k]; }
      scnt[k] = run; preArr[k] = pre;
    }
    __syncthreads();
    if (tid == 0) {
      int r = 0;
      for (int k = 0; k < NROLE; ++k) { sbase[k] = r; r += scnt[k]; }
    }
    __syncthreads();
    if (bx == 0 && tid < NROLE) { baseArr[tid] = sbase[tid]; cntArr[tid] = scnt[tid]; }
    int i = bx * 256 + tid;
    int k = rid[i];
    int pos = atomicAdd(&h[k], 1);
    bucket[sbase[k] + preArr[k] + pos] = i;
    return;
  }

  float* redS  = (float*)&smem[16384];   // [32][4]
  float* redSS = redS + 128;             // [32][4]
  const int rowBase = blockIdx.x * 32;
  const int lane = tid & 63, wave = tid >> 6;
  const int quad = lane >> 4, lm = lane & 15, l7 = lm & 7;
  const int wn = wave * 128;

  // ---- obs-LN staging (32 rows): thread owns row tid>>3, col-eighth (tid&7)*32
  {
    const int r = tid >> 3, q = tid & 7;
    const float* xr = obs + (size_t)(rowBase + r) * 256 + q * 32;
    float x[32];
#pragma unroll
    for (int jj = 0; jj < 8; ++jj)
      *(float4*)&x[jj * 4] = *(const float4*)(xr + jj * 4);
    float s = 0.f, s2 = 0.f;
#pragma unroll
    for (int p = 0; p < 32; ++p) { s += x[p]; s2 += x[p] * x[p]; }
    s  += __shfl_xor(s, 1, 64);  s  += __shfl_xor(s, 2, 64);  s  += __shfl_xor(s, 4, 64);
    s2 += __shfl_xor(s2, 1, 64); s2 += __shfl_xor(s2, 2, 64); s2 += __shfl_xor(s2, 4, 64);
    float m = s * (1.f / 256.f);
    float var = s2 * (1.f / 256.f) - m * m;
    float inv = rsqrtf(var + 1e-5f);
    const float* fs = fn_s + q * 32;
    const float* fb = fn_b + q * 32;
    u16* og = obs_n + (size_t)(rowBase + r) * 256 + q * 32;
#pragma unroll
    for (int j = 0; j < 4; ++j) {
      float4 fs0 = *(const float4*)(fs + j * 8);
      float4 fs1 = *(const float4*)(fs + j * 8 + 4);
      float4 fb0 = *(const float4*)(fb + j * 8);
      float4 fb1 = *(const float4*)(fb + j * 8 + 4);
      u16 yy[8] __attribute__((aligned(16)));
      yy[0] = f2b((x[j*8+0] - m) * inv * fs0.x + fb0.x);
      yy[1] = f2b((x[j*8+1] - m) * inv * fs0.y + fb0.y);
      yy[2] = f2b((x[j*8+2] - m) * inv * fs0.z + fb0.z);
      yy[3] = f2b((x[j*8+3] - m) * inv * fs0.w + fb0.w);
      yy[4] = f2b((x[j*8+4] - m) * inv * fs1.x + fb1.x);
      yy[5] = f2b((x[j*8+5] - m) * inv * fs1.y + fb1.y);
      yy[6] = f2b((x[j*8+6] - m) * inv * fs1.z + fb1.z);
      yy[7] = f2b((x[j*8+7] - m) * inv * fs1.w + fb1.w);
      int cch = q * 4 + j;
      *(uint4*)&smem[r * 256 + ((cch ^ (r & 7)) * 8)] = *(uint4*)yy;
      *(uint4*)(og + j * 8) = *(uint4*)yy;
    }
  }
  __syncthreads();   // B1: A0 staged

  // ---- gemm0: acc = A0 @ W0t^T  (K=256, N=512; wave = 128 cols); ring-1
  u32 bOff0[8];
#pragma unroll
  for (int j = 0; j < 8; ++j)
    bOff0[j] = (u32)(wn + j * 16 + lm) * 256u + (u32)(quad * 8);
  f32x4 acc[2][8] = {};
  {
    bf16x8 bP[8];
#pragma unroll
    for (int j = 0; j < 8; ++j) bP[j] = *(const bf16x8*)(W0t + bOff0[j]);
#pragma unroll
    for (int g = 0; g < 8; ++g) {
      bf16x8 bN[8];
      if (g + 1 < 8) {
#pragma unroll
        for (int j = 0; j < 8; ++j)
          bN[j] = *(const bf16x8*)(W0t + bOff0[j] + (g + 1) * 32);
      }
      const int kc = g * 4;
      bf16x8 af[2];
#pragma unroll
      for (int i2 = 0; i2 < 2; ++i2)
        af[i2] = *(const bf16x8*)&smem[(i2 * 16 + lm) * 256 + (((quad + kc) ^ l7) * 8)];
#pragma unroll
      for (int i2 = 0; i2 < 2; ++i2)
#pragma unroll
        for (int j = 0; j < 8; ++j)
          acc[i2][j] = MFMA(af[i2], bP[j], acc[i2][j], 0, 0, 0);
      if (g + 1 < 8) {
#pragma unroll
        for (int j = 0; j < 8; ++j) bP[j] = bN[j];
      }
    }
  }

  // ---- ReLU + LN0 partials
  {
    float b0v[8];
#pragma unroll
    for (int j = 0; j < 8; ++j) b0v[j] = b0[wn + j * 16 + lm];
#pragma unroll
    for (int i2 = 0; i2 < 2; ++i2) {
#pragma unroll
      for (int r2 = 0; r2 < 4; ++r2) {
        float s = 0.f, ss = 0.f;
#pragma unroll
        for (int j = 0; j < 8; ++j) {
          float v = fmaxf(acc[i2][j][r2] + b0v[j], 0.f);
          acc[i2][j][r2] = v;
          s += v; ss += v * v;
        }
#pragma unroll
        for (int o = 1; o < 16; o <<= 1) { s += __shfl_xor(s, o, 64); ss += __shfl_xor(ss, o, 64); }
        if (lm == 0) {
          int row = i2 * 16 + quad * 4 + r2;
          redS[row * 4 + wave] = s;
          redSS[row * 4 + wave] = ss;
        }
      }
    }
  }
  __syncthreads();   // B2: red0 done AND all A0 reads done

  // ---- LN0 finalize -> e0 bf16 into [0,32768)B (overlays dead A0)
  {
    float s0v[8], s0b[8];
#pragma unroll
    for (int j = 0; j < 8; ++j) {
      s0v[j] = ln0sc[wn + j * 16 + lm];
      s0b[j] = ln0bi[wn + j * 16 + lm];
    }
#pragma unroll
    for (int i2 = 0; i2 < 2; ++i2) {
#pragma unroll
      for (int r2 = 0; r2 < 4; ++r2) {
        int row = i2 * 16 + quad * 4 + r2;
        float ts  = redS[row * 4 + 0] + redS[row * 4 + 1] + redS[row * 4 + 2] + redS[row * 4 + 3];
        float tss = redSS[row * 4 + 0] + redSS[row * 4 + 1] + redSS[row * 4 + 2] + redSS[row * 4 + 3];
        float m = ts * (1.f / 512.f);
        float var = tss * (1.f / 512.f) - m * m;
        float inv = rsqrtf(var + 1e-5f);
#pragma unroll
        for (int j = 0; j < 8; ++j) {
          int col = wn + j * 16 + lm;
          float y = (acc[i2][j][r2] - m) * inv * s0v[j] + s0b[j];
          smem[row * 512 + (((col >> 3) ^ (row & 7)) * 8) + (col & 7)] = f2b(y);
        }
      }
    }
  }
  __syncthreads();   // B3: e0 visible

  // ---- gemm1: acc = e0 @ W1t^T  (K=512, N=512); ring-1
  u32 bOff1[8];
#pragma unroll
  for (int j = 0; j < 8; ++j)
    bOff1[j] = (u32)(wn + j * 16 + lm) * 512u + (u32)(quad * 8);
#pragma unroll
  for (int i2 = 0; i2 < 2; ++i2)
#pragma unroll
    for (int j = 0; j < 8; ++j)
      acc[i2][j] = (f32x4){0.f, 0.f, 0.f, 0.f};
  {
    bf16x8 bP[8];
#pragma unroll
    for (int j = 0; j < 8; ++j) bP[j] = *(const bf16x8*)(W1t + bOff1[j]);
#pragma unroll
    for (int g = 0; g < 16; ++g) {
      bf16x8 bN[8];
      if (g + 1 < 16) {
#pragma unroll
        for (int j = 0; j < 8; ++j)
          bN[j] = *(const bf16x8*)(W1t + bOff1[j] + (g + 1) * 32);
      }
      const int kc = g * 4;
      bf16x8 af[2];
#pragma unroll
      for (int i2 = 0; i2 < 2; ++i2)
        af[i2] = *(const bf16x8*)&smem[(i2 * 16 + lm) * 512 + (((quad + kc) ^ l7) * 8)];
#pragma unroll
      for (int i2 = 0; i2 < 2; ++i2)
#pragma unroll
        for (int j = 0; j < 8; ++j)
          acc[i2][j] = MFMA(af[i2], bP[j], acc[i2][j], 0, 0, 0);
      if (g + 1 < 16) {
#pragma unroll
        for (int j = 0; j < 8; ++j) bP[j] = bN[j];
      }
    }
  }

  // ---- ReLU + LN1 partials
  {
    float b1v[8];
#pragma unroll
    for (int j = 0; j < 8; ++j) b1v[j] = b1[wn + j * 16 + lm];
#pragma unroll
    for (int i2 = 0; i2 < 2; ++i2) {
#pragma unroll
      for (int r2 = 0; r2 < 4; ++r2) {
        float s = 0.f, ss = 0.f;
#pragma unroll
        for (int j = 0; j < 8; ++j) {
          float v = fmaxf(acc[i2][j][r2] + b1v[j], 0.f);
          acc[i2][j][r2] = v;
          s += v; ss += v * v;
        }
#pragma unroll
        for (int o = 1; o < 16; o <<= 1) { s += __shfl_xor(s, o, 64); ss += __shfl_xor(ss, o, 64); }
        if (lm == 0) {
          int row = i2 * 16 + quad * 4 + r2;
          redS[row * 4 + wave] = s;
          redSS[row * 4 + wave] = ss;
        }
      }
    }
  }
  __syncthreads();   // B4: red1 done; all e0 reads done

  // ---- LN1 finalize -> LDS out-tile (linear [32][512], overlays dead e0)
  {
    float s1v[8], s1b[8];
#pragma unroll
    for (int j = 0; j < 8; ++j) {
      s1v[j] = ln1sc[wn + j * 16 + lm];
      s1b[j] = ln1bi[wn + j * 16 + lm];
    }
#pragma unroll
    for (int i2 = 0; i2 < 2; ++i2) {
#pragma unroll
      for (int r2 = 0; r2 < 4; ++r2) {
        int row = i2 * 16 + quad * 4 + r2;
        float ts  = redS[row * 4 + 0] + redS[row * 4 + 1] + redS[row * 4 + 2] + redS[row * 4 + 3];
        float tss = redSS[row * 4 + 0] + redSS[row * 4 + 1] + redSS[row * 4 + 2] + redSS[row * 4 + 3];
        float m = ts * (1.f / 512.f);
        float var = tss * (1.f / 512.f) - m * m;
        float inv = rsqrtf(var + 1e-5f);
#pragma unroll
        for (int j = 0; j < 8; ++j) {
          int col = wn + j * 16 + lm;
          float y = (acc[i2][j][r2] - m) * inv * s1v[j] + s1b[j];
          smem[row * 512 + col] = f2b(y);
        }
      }
    }
  }
  __syncthreads();   // B5: out-tile complete

  // ---- coalesced copy LDS -> bufB (32 KB; 1KB per wave-instruction)
  {
    u16* dst = C + (size_t)rowBase * 512;
#pragma unroll
    for (int it = 0; it < 8; ++it) {
      int idx = (it * 256 + tid) * 8;   // u16 units
      *(uint4*)(dst + idx) = *(const uint4*)&smem[idx];
    }
  }
}

// ---------------------------------------------------------------- route_head (round-2 verified, 67-68 us)
__global__ __launch_bounds__(256, 4) void route_head(
    const u16* __restrict__ obs_n, const u16* __restrict__ e,
    const u16* __restrict__ Wr0t, const float* __restrict__ br0,
    const u16* __restrict__ Wr1t, const float* __restrict__ br1,
    const u16* __restrict__ Wh0t, const float* __restrict__ bh0,
    const float* __restrict__ Wh1, const float* __restrict__ bh1,
    const float* __restrict__ Wh2, const float* __restrict__ bh2,
    const float* __restrict__ avail,
    const int* __restrict__ bucket, const int* __restrict__ baseArr,
    const int* __restrict__ cntArr, float* __restrict__ outLogits)
{
  __shared__ __align__(16) u16 sm[20480];   // 40960 B
  const int tid = threadIdx.x;

  int cA0, cA1, cA2, cA3, cA4, cA5, bA0, bA1, bA2, bA3, bA4, bA5;
  {
    int4 ca = *(const int4*)cntArr;  int2 cb = *(const int2*)(cntArr + 4);
    int4 ba = *(const int4*)baseArr; int2 bb = *(const int2*)(baseArr + 4);
    cA0 = ca.x; cA1 = ca.y; cA2 = ca.z; cA3 = ca.w; cA4 = cb.x; cA5 = cb.y;
    bA0 = ba.x; bA1 = ba.y; bA2 = ba.z; bA3 = ba.w; bA4 = bb.x; bA5 = bb.y;
  }
  int role = -1, rem = blockIdx.x, cnt = 0, roleBase = 0;
#define TRY_ROLE(k, ck, bk)                                        \
  if (role < 0) {                                                  \
    int tiles = ((ck) + 31) >> 5;                                  \
    if (rem < tiles) { role = (k); cnt = (ck); roleBase = (bk); }  \
    else rem -= tiles;                                             \
  }
  TRY_ROLE(0, cA0, bA0) TRY_ROLE(1, cA1, bA1) TRY_ROLE(2, cA2, bA2)
  TRY_ROLE(3, cA3, bA3) TRY_ROLE(4, cA4, bA4) TRY_ROLE(5, cA5, bA5)
#undef TRY_ROLE
  if (role < 0) return;
  const int limit = cnt;
  const int rowBase = rem * 32;

  const int lane = tid & 63, wave = tid >> 6;
  const int quad = lane >> 4, lm = lane & 15, l7 = lm & 7;

#pragma unroll
  for (int r = 0; r < 8; ++r) {
    int lrow = r * 4 + wave;
    int i = rowBase + lrow;
    if (i >= limit) i = rowBase;
    int grow = bucket[roleBase + i];
    int chunk = tid & 63;
    int sw = (chunk & 56) | ((chunk ^ lrow) & 7);
    gll16(e + (u32)grow * 512u + (u32)(sw * 8), &sm[r * 2048 + wave * 512]);
  }

  int growA0, growA1;
  {
    int i0 = rowBase + lm;        if (i0 >= limit) i0 = rowBase;
    int i1 = rowBase + 16 + lm;   if (i1 >= limit) i1 = rowBase;
    growA0 = bucket[roleBase + i0];
    growA1 = bucket[roleBase + i1];
  }
  const u16* Ag0 = obs_n + (size_t)growA0 * 256;
  const u16* Ag1 = obs_n + (size_t)growA1 * 256;

  // ---- stage0
  const int wn0 = wave * 32;
  const u16* B0 = Wr0t + (size_t)role * 128 * 256;
  f32x4 acc0[2][2] = {};
  bf16x8 b0R[2][2];
#pragma unroll
  for (int p = 0; p < 2; ++p)
#pragma unroll
    for (int j = 0; j < 2; ++j)
      b0R[p][j] = *(const bf16x8*)(B0 + (u32)(wn0 + j * 16 + lm) * 256u + (u32)(quad * 8 + p * 32));
  bf16x8 aR[4][2];
#pragma unroll
  for (int p = 0; p < 4; ++p) {
    aR[p][0] = *(const bf16x8*)(Ag0 + (u32)(quad * 8 + p * 32));
    aR[p][1] = *(const bf16x8*)(Ag1 + (u32)(quad * 8 + p * 32));
  }
  float bias0[2] = { br0[role * 128 + wn0 + lm], br0[role * 128 + wn0 + 16 + lm] };
#pragma unroll
  for (int it = 0; it < 8; ++it) {
    bf16x8 a0 = aR[it & 3][0], a1 = aR[it & 3][1];
    bf16x8 cur0 = b0R[it & 1][0], cur1 = b0R[it & 1][1];
    if (it + 2 < 8) {
#pragma unroll
      for (int j = 0; j < 2; ++j)
        b0R[it & 1][j] = *(const bf16x8*)(B0 + (u32)(wn0 + j * 16 + lm) * 256u + (u32)(quad * 8 + (it + 2) * 32));
    }
    if (it + 4 < 8) {
      aR[it & 3][0] = *(const bf16x8*)(Ag0 + (u32)(quad * 8 + (it + 4) * 32));
      aR[it & 3][1] = *(const bf16x8*)(Ag1 + (u32)(quad * 8 + (it + 4) * 32));
    }
    acc0[0][0] = MFMA(a0, cur0, acc0[0][0], 0, 0, 0);
    acc0[0][1] = MFMA(a0, cur1, acc0[0][1], 0, 0, 0);
    acc0[1][0] = MFMA(a1, cur0, acc0[1][0], 0, 0, 0);
    acc0[1][1] = MFMA(a1, cur1, acc0[1][1], 0, 0, 0);
  }
  u16* r1 = sm + 16384;
#pragma unroll
  for (int i2 = 0; i2 < 2; ++i2) {
#pragma unroll
    for (int r2 = 0; r2 < 4; ++r2) {
      int row = i2 * 16 + quad * 4 + r2;
#pragma unroll
      for (int j = 0; j < 2; ++j) {
        int col = wn0 + j * 16 + lm;
        float v = fmaxf(acc0[i2][j][r2] + bias0[j], 0.f);
        r1[row * 128 + (((col >> 3) ^ (row & 7)) * 8) + (col & 7)] = f2b(v);
      }
    }
  }
  __syncthreads();   // B1

  // ---- stage1: two 64-col halves
  const int wn1 = wave * 128;
  const u16* B1 = Wr1t + (size_t)role * 512 * 128;
#pragma unroll
  for (int h = 0; h < 2; ++h) {
    const int wnh = wn1 + h * 64;
    float b1v[4];
#pragma unroll
    for (int j = 0; j < 4; ++j) b1v[j] = br1[role * 512 + wnh + j * 16 + lm];
    f32x4 acc1[2][4] = {};
    bf16x8 b1P[4];
#pragma unroll
    for (int j = 0; j < 4; ++j)
      b1P[j] = *(const bf16x8*)(B1 + (u32)(wnh + j * 16 + lm) * 128u + (u32)(quad * 8));
#pragma unroll
    for (int kk = 0; kk < 128; kk += 32) {
      bf16x8 b1N[4];
      if (kk + 32 < 128) {
#pragma unroll
        for (int j = 0; j < 4; ++j)
          b1N[j] = *(const bf16x8*)(B1 + (u32)(wnh + j * 16 + lm) * 128u + (u32)(quad * 8 + kk + 32));
      }
      const int kc = kk >> 3;
      bf16x8 af[2];
#pragma unroll
      for (int i2 = 0; i2 < 2; ++i2)
        af[i2] = *(const bf16x8*)&r1[(i2 * 16 + lm) * 128 + (((quad + kc) ^ l7) * 8)];
#pragma unroll
      for (int i2 = 0; i2 < 2; ++i2)
#pragma unroll
        for (int j = 0; j < 4; ++j)
          acc1[i2][j] = MFMA(af[i2], b1P[j], acc1[i2][j], 0, 0, 0);
      if (kk + 32 < 128) {
#pragma unroll
        for (int j = 0; j < 4; ++j) b1P[j] = b1N[j];
      }
    }
#pragma unroll
    for (int i2 = 0; i2 < 2; ++i2) {
#pragma unroll
      for (int r2 = 0; r2 < 4; ++r2) {
        int row = i2 * 16 + quad * 4 + r2;
#pragma unroll
        for (int j = 0; j < 4; ++j) {
          int col = wnh + j * 16 + lm;
          int addr = row * 512 + (((col >> 3) ^ (row & 7)) * 8) + (col & 7);
          float v = fmaxf(acc1[i2][j][r2] + b1v[j], 0.f) + b2f(sm[addr]);
          sm[addr] = f2b(v);
        }
      }
    }
  }
  __syncthreads();

  // ---- stage2
  const int wn2 = wave * 16;
  const u16* B2 = Wh0t + (size_t)role * 64 * 512;
  float b2v = bh0[role * 64 + wn2 + lm];
  f32x4 acc2[2] = {};
  bf16x8 b2R[4];
#pragma unroll
  for (int p = 0; p < 4; ++p)
    b2R[p] = *(const bf16x8*)(B2 + (u32)(wn2 + lm) * 512u + (u32)(quad * 8 + p * 32));
#pragma unroll
  for (int it = 0; it < 16; ++it) {
    bf16x8 cur = b2R[it & 3];
    if (it + 4 < 16)
      b2R[it & 3] = *(const bf16x8*)(B2 + (u32)(wn2 + lm) * 512u + (u32)(quad * 8 + (it + 4) * 32));
    const int kc = it * 4;
    bf16x8 af[2];
#pragma unroll
    for (int i2 = 0; i2 < 2; ++i2)
      af[i2] = *(const bf16x8*)&sm[(i2 * 16 + lm) * 512 + (((quad + kc) ^ l7) * 8)];
#pragma unroll
    for (int i2 = 0; i2 < 2; ++i2)
      acc2[i2] = MFMA(af[i2], cur, acc2[i2], 0, 0, 0);
  }
  u16* h0s = sm + 16384;
#pragma unroll
  for (int i2 = 0; i2 < 2; ++i2) {
#pragma unroll
    for (int r2 = 0; r2 < 4; ++r2) {
      int row = i2 * 16 + quad * 4 + r2;
      int col = wn2 + lm;
      h0s[row * 68 + col] = f2b(fmaxf(acc2[i2][r2] + b2v, 0.f));
    }
  }
  __syncthreads();

  // ---- stage3
  {
    float* h1s = (float*)&sm[16384];
    const int r = tid >> 3;
    const int n0 = (tid & 7) * 4;
    const bool valid = (rowBase + r) < limit;
    const float* W1k = Wh1 + (size_t)role * 64 * 32;
    const float* W2k = Wh2 + (size_t)role * 32 * 32;
    float4 a1 = *(const float4*)(bh1 + role * 32 + n0);
#pragma unroll 8
    for (int j = 0; j < 64; ++j) {
      float hj = b2f(h0s[r * 68 + j]);
      float4 wv = *(const float4*)(W1k + j * 32 + n0);
      a1.x += hj * wv.x; a1.y += hj * wv.y; a1.z += hj * wv.z; a1.w += hj * wv.w;
    }
    a1.x = fmaxf(a1.x, 0.f); a1.y = fmaxf(a1.y, 0.f);
    a1.z = fmaxf(a1.z, 0.f); a1.w = fmaxf(a1.w, 0.f);
    __syncthreads();
    h1s[r * 36 + n0 + 0] = a1.x;
    h1s[r * 36 + n0 + 1] = a1.y;
    h1s[r * 36 + n0 + 2] = a1.z;
    h1s[r * 36 + n0 + 3] = a1.w;
    __syncthreads();
    float4 a2 = *(const float4*)(bh2 + role * 32 + n0);
#pragma unroll 8
    for (int n = 0; n < 32; ++n) {
      float hn = h1s[r * 36 + n];
      float4 wv = *(const float4*)(W2k + n * 32 + n0);
      a2.x += hn * wv.x; a2.y += hn * wv.y; a2.z += hn * wv.z; a2.w += hn * wv.w;
    }
    if (valid) {
      int g = bucket[roleBase + rowBase + r];
      float4 av = *(const float4*)(avail + (size_t)g * 32 + n0);
      float4 o;
      o.x = (av.x > 0.5f) ? a2.x : -1e10f;
      o.y = (av.y > 0.5f) ? a2.y : -1e10f;
      o.z = (av.z > 0.5f) ? a2.z : -1e10f;
      o.w = (av.w > 0.5f) ? a2.w : -1e10f;
      *(float4*)(outLogits + (size_t)g * 32 + n0) = o;
    }
  }
}

// ---------------------------------------------------------------- launcher
extern "C" void kernel_launch(void* const* d_in, const int* in_sizes, int n_in,
                              void* d_out, int out_size, void* d_ws, size_t ws_size,
                              hipStream_t stream)
{
  const float* rnn  = (const float*)d_in[0];
  const float* obs  = (const float*)d_in[1];
  const float* avail= (const float*)d_in[3];
  const int*   rid  = (const int*)d_in[4];
  const float* fn_s = (const float*)d_in[5];
  const float* fn_b = (const float*)d_in[6];
  const float* W0   = (const float*)d_in[7];
  const float* b0   = (const float*)d_in[8];
  const float* ln0s = (const float*)d_in[9];
  const float* ln0b = (const float*)d_in[10];
  const float* W1   = (const float*)d_in[11];
  const float* b1   = (const float*)d_in[12];
  const float* ln1s = (const float*)d_in[13];
  const float* ln1b = (const float*)d_in[14];
  const float* Wr0  = (const float*)d_in[15];
  const float* br0  = (const float*)d_in[16];
  const float* Wr1  = (const float*)d_in[17];
  const float* br1  = (const float*)d_in[18];
  const float* Wh0  = (const float*)d_in[19];
  const float* bh0  = (const float*)d_in[20];
  const float* Wh1  = (const float*)d_in[21];
  const float* bh1  = (const float*)d_in[22];
  const float* Wh2  = (const float*)d_in[23];
  const float* bh2  = (const float*)d_in[24];

  const int ROWS = 32768;

  char* w = (char*)d_ws;
  auto carve = [&](size_t bytes) { char* p = w; w += (bytes + 255) & ~(size_t)255; return p; };
  u16* obs_n  = (u16*)carve((size_t)ROWS * 256 * 2);
  u16* bufB   = (u16*)carve((size_t)ROWS * 512 * 2);   // e
  u16* W0t    = (u16*)carve((size_t)512 * 256 * 2);
  u16* W1t    = (u16*)carve((size_t)512 * 512 * 2);
  u16* Wr0t   = (u16*)carve((size_t)6 * 128 * 256 * 2);
  u16* Wr1t   = (u16*)carve((size_t)6 * 512 * 128 * 2);
  u16* Wh0t   = (u16*)carve((size_t)6 * 64 * 512 * 2);
  int* bucket = (int*)carve((size_t)ROWS * 4);
  int* blkCnt = (int*)carve((size_t)128 * NROLE * 4);
  int* baseArr= (int*)carve(256);
  int* cntArr = (int*)carve(256);

  float* outLogits = (float*)d_out + (size_t)1024 * 512;

  // mega0: weight transposes + role_count + rnn passthrough
  mega0<<<1408, 256, 0, stream>>>(W0, W1, Wr0, Wr1, Wh0, W0t, W1t, Wr0t, Wr1t, Wh0t,
                                  rid, blkCnt, rnn, (float*)d_out);

  // fused obs-LN + gemm0 + LN0 + gemm1 + LN1, 32-row tiles (0..1023) + fill2 (1024..1151)
  base2v<<<1152, 256, 0, stream>>>(obs, fn_s, fn_b, W0t, b0, ln0s, ln0b,
                                   W1t, b1, ln1s, ln1b, obs_n, bufB,
                                   rid, blkCnt, bucket, baseArr, cntArr);

  // fused role route + full head (round-2 verified)
  route_head<<<1029, 256, 0, stream>>>(obs_n, bufB, Wr0t, br0, Wr1t, br1, Wh0t, bh0,
                                       Wh1, bh1, Wh2, bh2, avail,
                                       bucket, baseArr, cntArr, outLogits);
}

// Round 8
// 299.597 us; speedup vs baseline: 1.0101x; 1.0101x over previous
//
#include <hip/hip_runtime.h>
#include <stdint.h>

typedef unsigned short u16;
typedef unsigned int u32;

using bf16x8 = __attribute__((ext_vector_type(8))) short;
using f32x4  = __attribute__((ext_vector_type(4))) float;

#define DEVINL __device__ __forceinline__

DEVINL float b2f(u16 u) { return __builtin_bit_cast(float, (u32)u << 16); }
DEVINL u16 f2b(float f) {
  u32 u = __builtin_bit_cast(u32, f);
  u += 0x7FFFu + ((u >> 16) & 1u);   // round-to-nearest-even
  return (u16)(u >> 16);
}

DEVINL void gll16(const u16* src, u16* dst) {
  __builtin_amdgcn_global_load_lds(
      (const __attribute__((address_space(1))) void*)(uintptr_t)src,
      (__attribute__((address_space(3))) void*)(uintptr_t)dst, 16, 0, 0);
}

#define MFMA __builtin_amdgcn_mfma_f32_16x16x32_bf16
#define NROLE 6

// ---------------------------------------------------------------- mega0:
// transposes (blocks 0..1151) | role_count (1152..1279) | rnn copy (1280..1407).
DEVINL void tp_tile(const float* __restrict__ s, u16* __restrict__ d,
                    int R, int C, int bx, int by, int z)
{
  __shared__ u16 tile[32][33];
  const size_t mstride = (size_t)R * C;
  s += (size_t)z * mstride;
  d += (size_t)z * mstride;
  int r0 = bx * 32, c0 = by * 32;
  int tx = threadIdx.x & 31, ty = threadIdx.x >> 5;
#pragma unroll
  for (int i = 0; i < 32; i += 8)
    tile[ty + i][tx] = f2b(s[(size_t)(r0 + ty + i) * C + (c0 + tx)]);
  __syncthreads();
#pragma unroll
  for (int i = 0; i < 32; i += 8)
    d[(size_t)(c0 + ty + i) * R + (r0 + tx)] = tile[tx][ty + i];
}

__global__ __launch_bounds__(256) void mega0(
    const float* W0, const float* W1, const float* Wr0, const float* Wr1, const float* Wh0,
    u16* W0t, u16* W1t, u16* Wr0t, u16* Wr1t, u16* Wh0t,
    const int* __restrict__ rid, int* __restrict__ blkCnt,
    const float* __restrict__ rnn, float* __restrict__ outRnn)
{
  int b = blockIdx.x;
  const int tid = threadIdx.x;
  if (b < 1152) {
    if (b < 128)      {            tp_tile(W0, W0t, 256, 512, b % 8,  b / 8, 0); }
    else if (b < 384) { b -= 128;  tp_tile(W1, W1t, 512, 512, b % 16, b / 16, 0); }
    else if (b < 576) { b -= 384;  int t = b / 8;  tp_tile(Wr0, Wr0t, 256, 128, b % 8,  t % 4,  t / 4); }
    else if (b < 960) { b -= 576;  int t = b / 4;  tp_tile(Wr1, Wr1t, 128, 512, b % 4,  t % 16, t / 16); }
    else              { b -= 960;  int t = b / 16; tp_tile(Wh0, Wh0t, 512, 64,  b % 16, t % 2,  t / 2); }
  } else if (b < 1280) {
    b -= 1152;
    __shared__ int h[NROLE];
    if (tid < NROLE) h[tid] = 0;
    __syncthreads();
    atomicAdd(&h[rid[b * 256 + tid]], 1);
    __syncthreads();
    if (tid < NROLE) blkCnt[b * NROLE + tid] = h[tid];
  } else {
    b -= 1280;
    const float4* src = (const float4*)rnn;
    float4* dst = (float4*)outRnn;
    int base = (b * 256 + tid) * 4;
#pragma unroll
    for (int i = 0; i < 4; ++i) dst[base + i] = src[base + i];
  }
}

// ---------------------------------------------------------------- base2v (32-row tile, half-split gemms):
// blocks 0..1023: fused obs-LN + gemm0 + LN0 + gemm1 + LN1 for 32 rows.
//   LDS 33792 B -> 4 blocks/CU (16 waves/CU).
//   SPILL FIX (round-7 regression): at (256,4) the unified budget is 128
//   regs/wave; acc takes 64 AGPR, so the B-ring must be 4-wide, not 8.
//   Each wave's 128 cols are processed as two sequential 64-col passes
//   over full K (round-2-verified pattern). acc[2][2][4] = same 64 AGPRs.
//   Epilogue: LN1 -> LDS linear [32][512] -> coalesced uint4 copy to global.
// blocks 1024..1151: fill2 (scan + bucket fill), verbatim.
// LDS map (u16 units):
//   A0  [0,8192)     32x256 swizzled (dead after gemm0)
//   e0  [0,16384)    32x512 swizzled (overlays A0; then overlaid by out-tile)
//   red [16384,16896)  redS 128 f32 | redSS 128 f32
__global__ __launch_bounds__(256, 4) void base2v(
    const float* __restrict__ obs, const float* __restrict__ fn_s,
    const float* __restrict__ fn_b, const u16* __restrict__ W0t,
    const float* __restrict__ b0, const float* __restrict__ ln0sc,
    const float* __restrict__ ln0bi, const u16* __restrict__ W1t,
    const float* __restrict__ b1, const float* __restrict__ ln1sc,
    const float* __restrict__ ln1bi, u16* __restrict__ obs_n,
    u16* __restrict__ C,
    const int* __restrict__ rid, const int* __restrict__ blkCnt,
    int* __restrict__ bucket, int* __restrict__ baseArr, int* __restrict__ cntArr)
{
  __shared__ __align__(16) u16 smem[16896];   // 33792 B
  const int tid = threadIdx.x;

  if (blockIdx.x >= 1024) {
    const int bx = blockIdx.x - 1024;
    int* c = (int*)smem;
    int* preArr = c + 768;
    int* scnt   = c + 776;
    int* sbase  = c + 784;
    int* h      = c + 792;
    for (int i = tid; i < 128 * NROLE; i += 256) c[i] = blkCnt[i];
    if (tid < NROLE) h[tid] = 0;
    __syncthreads();
    if (tid < NROLE) {
      int k = tid, run = 0, pre = 0;
      for (int b = 0; b < 128; ++b) { if (b == bx) pre = run; run += c[b * NROLE + k]; }
      scnt[k] = run; preArr[k] = pre;
    }
    __syncthreads();
    if (tid == 0) {
      int r = 0;
      for (int k = 0; k < NROLE; ++k) { sbase[k] = r; r += scnt[k]; }
    }
    __syncthreads();
    if (bx == 0 && tid < NROLE) { baseArr[tid] = sbase[tid]; cntArr[tid] = scnt[tid]; }
    int i = bx * 256 + tid;
    int k = rid[i];
    int pos = atomicAdd(&h[k], 1);
    bucket[sbase[k] + preArr[k] + pos] = i;
    return;
  }

  float* redS  = (float*)&smem[16384];   // [32][4]
  float* redSS = redS + 128;             // [32][4]
  const int rowBase = blockIdx.x * 32;
  const int lane = tid & 63, wave = tid >> 6;
  const int quad = lane >> 4, lm = lane & 15, l7 = lm & 7;
  const int wn = wave * 128;

  // ---- obs-LN staging (32 rows): thread owns row tid>>3, col-eighth (tid&7)*32
  {
    const int r = tid >> 3, q = tid & 7;
    const float* xr = obs + (size_t)(rowBase + r) * 256 + q * 32;
    float x[32];
#pragma unroll
    for (int jj = 0; jj < 8; ++jj)
      *(float4*)&x[jj * 4] = *(const float4*)(xr + jj * 4);
    float s = 0.f, s2 = 0.f;
#pragma unroll
    for (int p = 0; p < 32; ++p) { s += x[p]; s2 += x[p] * x[p]; }
    s  += __shfl_xor(s, 1, 64);  s  += __shfl_xor(s, 2, 64);  s  += __shfl_xor(s, 4, 64);
    s2 += __shfl_xor(s2, 1, 64); s2 += __shfl_xor(s2, 2, 64); s2 += __shfl_xor(s2, 4, 64);
    float m = s * (1.f / 256.f);
    float var = s2 * (1.f / 256.f) - m * m;
    float inv = rsqrtf(var + 1e-5f);
    const float* fs = fn_s + q * 32;
    const float* fb = fn_b + q * 32;
    u16* og = obs_n + (size_t)(rowBase + r) * 256 + q * 32;
#pragma unroll
    for (int j = 0; j < 4; ++j) {
      float4 fs0 = *(const float4*)(fs + j * 8);
      float4 fs1 = *(const float4*)(fs + j * 8 + 4);
      float4 fb0 = *(const float4*)(fb + j * 8);
      float4 fb1 = *(const float4*)(fb + j * 8 + 4);
      u16 yy[8] __attribute__((aligned(16)));
      yy[0] = f2b((x[j*8+0] - m) * inv * fs0.x + fb0.x);
      yy[1] = f2b((x[j*8+1] - m) * inv * fs0.y + fb0.y);
      yy[2] = f2b((x[j*8+2] - m) * inv * fs0.z + fb0.z);
      yy[3] = f2b((x[j*8+3] - m) * inv * fs0.w + fb0.w);
      yy[4] = f2b((x[j*8+4] - m) * inv * fs1.x + fb1.x);
      yy[5] = f2b((x[j*8+5] - m) * inv * fs1.y + fb1.y);
      yy[6] = f2b((x[j*8+6] - m) * inv * fs1.z + fb1.z);
      yy[7] = f2b((x[j*8+7] - m) * inv * fs1.w + fb1.w);
      int cch = q * 4 + j;
      *(uint4*)&smem[r * 256 + ((cch ^ (r & 7)) * 8)] = *(uint4*)yy;
      *(uint4*)(og + j * 8) = *(uint4*)yy;
    }
  }
  __syncthreads();   // B1: A0 staged

  // ---- gemm0: two sequential 64-col passes (B-ring 4-wide; no spill)
  f32x4 acc[2][2][4] = {};   // [half][i2][j] -> 64 AGPRs
#pragma unroll
  for (int h = 0; h < 2; ++h) {
    u32 bOff[4];
#pragma unroll
    for (int j = 0; j < 4; ++j)
      bOff[j] = (u32)(wn + h * 64 + j * 16 + lm) * 256u + (u32)(quad * 8);
    bf16x8 bP[4];
#pragma unroll
    for (int j = 0; j < 4; ++j) bP[j] = *(const bf16x8*)(W0t + bOff[j]);
#pragma unroll
    for (int g = 0; g < 8; ++g) {
      bf16x8 bN[4];
      if (g + 1 < 8) {
#pragma unroll
        for (int j = 0; j < 4; ++j)
          bN[j] = *(const bf16x8*)(W0t + bOff[j] + (g + 1) * 32);
      }
      const int kc = g * 4;
      bf16x8 af[2];
#pragma unroll
      for (int i2 = 0; i2 < 2; ++i2)
        af[i2] = *(const bf16x8*)&smem[(i2 * 16 + lm) * 256 + (((quad + kc) ^ l7) * 8)];
#pragma unroll
      for (int i2 = 0; i2 < 2; ++i2)
#pragma unroll
        for (int j = 0; j < 4; ++j)
          acc[h][i2][j] = MFMA(af[i2], bP[j], acc[h][i2][j], 0, 0, 0);
      if (g + 1 < 8) {
#pragma unroll
        for (int j = 0; j < 4; ++j) bP[j] = bN[j];
      }
    }
  }

  // ---- ReLU + LN0 partials (both halves)
  {
    float b0v[2][4];
#pragma unroll
    for (int h = 0; h < 2; ++h)
#pragma unroll
      for (int j = 0; j < 4; ++j) b0v[h][j] = b0[wn + h * 64 + j * 16 + lm];
#pragma unroll
    for (int i2 = 0; i2 < 2; ++i2) {
#pragma unroll
      for (int r2 = 0; r2 < 4; ++r2) {
        float s = 0.f, ss = 0.f;
#pragma unroll
        for (int h = 0; h < 2; ++h) {
#pragma unroll
          for (int j = 0; j < 4; ++j) {
            float v = fmaxf(acc[h][i2][j][r2] + b0v[h][j], 0.f);
            acc[h][i2][j][r2] = v;
            s += v; ss += v * v;
          }
        }
#pragma unroll
        for (int o = 1; o < 16; o <<= 1) { s += __shfl_xor(s, o, 64); ss += __shfl_xor(ss, o, 64); }
        if (lm == 0) {
          int row = i2 * 16 + quad * 4 + r2;
          redS[row * 4 + wave] = s;
          redSS[row * 4 + wave] = ss;
        }
      }
    }
  }
  __syncthreads();   // B2: red0 done AND all A0 reads done

  // ---- LN0 finalize -> e0 bf16 into [0,32768)B (overlays dead A0)
  {
    float s0v[2][4], s0b[2][4];
#pragma unroll
    for (int h = 0; h < 2; ++h)
#pragma unroll
      for (int j = 0; j < 4; ++j) {
        s0v[h][j] = ln0sc[wn + h * 64 + j * 16 + lm];
        s0b[h][j] = ln0bi[wn + h * 64 + j * 16 + lm];
      }
#pragma unroll
    for (int i2 = 0; i2 < 2; ++i2) {
#pragma unroll
      for (int r2 = 0; r2 < 4; ++r2) {
        int row = i2 * 16 + quad * 4 + r2;
        float ts  = redS[row * 4 + 0] + redS[row * 4 + 1] + redS[row * 4 + 2] + redS[row * 4 + 3];
        float tss = redSS[row * 4 + 0] + redSS[row * 4 + 1] + redSS[row * 4 + 2] + redSS[row * 4 + 3];
        float m = ts * (1.f / 512.f);
        float var = tss * (1.f / 512.f) - m * m;
        float inv = rsqrtf(var + 1e-5f);
#pragma unroll
        for (int h = 0; h < 2; ++h) {
#pragma unroll
          for (int j = 0; j < 4; ++j) {
            int col = wn + h * 64 + j * 16 + lm;
            float y = (acc[h][i2][j][r2] - m) * inv * s0v[h][j] + s0b[h][j];
            smem[row * 512 + (((col >> 3) ^ (row & 7)) * 8) + (col & 7)] = f2b(y);
          }
        }
      }
    }
  }
  __syncthreads();   // B3: e0 visible

  // ---- gemm1: two sequential 64-col passes over K=512
#pragma unroll
  for (int h = 0; h < 2; ++h)
#pragma unroll
    for (int i2 = 0; i2 < 2; ++i2)
#pragma unroll
      for (int j = 0; j < 4; ++j)
        acc[h][i2][j] = (f32x4){0.f, 0.f, 0.f, 0.f};
#pragma unroll
  for (int h = 0; h < 2; ++h) {
    u32 bOff[4];
#pragma unroll
    for (int j = 0; j < 4; ++j)
      bOff[j] = (u32)(wn + h * 64 + j * 16 + lm) * 512u + (u32)(quad * 8);
    bf16x8 bP[4];
#pragma unroll
    for (int j = 0; j < 4; ++j) bP[j] = *(const bf16x8*)(W1t + bOff[j]);
#pragma unroll
    for (int g = 0; g < 16; ++g) {
      bf16x8 bN[4];
      if (g + 1 < 16) {
#pragma unroll
        for (int j = 0; j < 4; ++j)
          bN[j] = *(const bf16x8*)(W1t + bOff[j] + (g + 1) * 32);
      }
      const int kc = g * 4;
      bf16x8 af[2];
#pragma unroll
      for (int i2 = 0; i2 < 2; ++i2)
        af[i2] = *(const bf16x8*)&smem[(i2 * 16 + lm) * 512 + (((quad + kc) ^ l7) * 8)];
#pragma unroll
      for (int i2 = 0; i2 < 2; ++i2)
#pragma unroll
        for (int j = 0; j < 4; ++j)
          acc[h][i2][j] = MFMA(af[i2], bP[j], acc[h][i2][j], 0, 0, 0);
      if (g + 1 < 16) {
#pragma unroll
        for (int j = 0; j < 4; ++j) bP[j] = bN[j];
      }
    }
  }

  // ---- ReLU + LN1 partials
  {
    float b1v[2][4];
#pragma unroll
    for (int h = 0; h < 2; ++h)
#pragma unroll
      for (int j = 0; j < 4; ++j) b1v[h][j] = b1[wn + h * 64 + j * 16 + lm];
#pragma unroll
    for (int i2 = 0; i2 < 2; ++i2) {
#pragma unroll
      for (int r2 = 0; r2 < 4; ++r2) {
        float s = 0.f, ss = 0.f;
#pragma unroll
        for (int h = 0; h < 2; ++h) {
#pragma unroll
          for (int j = 0; j < 4; ++j) {
            float v = fmaxf(acc[h][i2][j][r2] + b1v[h][j], 0.f);
            acc[h][i2][j][r2] = v;
            s += v; ss += v * v;
          }
        }
#pragma unroll
        for (int o = 1; o < 16; o <<= 1) { s += __shfl_xor(s, o, 64); ss += __shfl_xor(ss, o, 64); }
        if (lm == 0) {
          int row = i2 * 16 + quad * 4 + r2;
          redS[row * 4 + wave] = s;
          redSS[row * 4 + wave] = ss;
        }
      }
    }
  }
  __syncthreads();   // B4: red1 done; all e0 reads done

  // ---- LN1 finalize -> LDS out-tile (linear [32][512], overlays dead e0)
  {
    float s1v[2][4], s1b[2][4];
#pragma unroll
    for (int h = 0; h < 2; ++h)
#pragma unroll
      for (int j = 0; j < 4; ++j) {
        s1v[h][j] = ln1sc[wn + h * 64 + j * 16 + lm];
        s1b[h][j] = ln1bi[wn + h * 64 + j * 16 + lm];
      }
#pragma unroll
    for (int i2 = 0; i2 < 2; ++i2) {
#pragma unroll
      for (int r2 = 0; r2 < 4; ++r2) {
        int row = i2 * 16 + quad * 4 + r2;
        float ts  = redS[row * 4 + 0] + redS[row * 4 + 1] + redS[row * 4 + 2] + redS[row * 4 + 3];
        float tss = redSS[row * 4 + 0] + redSS[row * 4 + 1] + redSS[row * 4 + 2] + redSS[row * 4 + 3];
        float m = ts * (1.f / 512.f);
        float var = tss * (1.f / 512.f) - m * m;
        float inv = rsqrtf(var + 1e-5f);
#pragma unroll
        for (int h = 0; h < 2; ++h) {
#pragma unroll
          for (int j = 0; j < 4; ++j) {
            int col = wn + h * 64 + j * 16 + lm;
            float y = (acc[h][i2][j][r2] - m) * inv * s1v[h][j] + s1b[h][j];
            smem[row * 512 + col] = f2b(y);
          }
        }
      }
    }
  }
  __syncthreads();   // B5: out-tile complete

  // ---- coalesced copy LDS -> bufB (32 KB; 1KB per wave-instruction)
  {
    u16* dst = C + (size_t)rowBase * 512;
#pragma unroll
    for (int it = 0; it < 8; ++it) {
      int idx = (it * 256 + tid) * 8;   // u16 units
      *(uint4*)(dst + idx) = *(const uint4*)&smem[idx];
    }
  }
}

// ---------------------------------------------------------------- route_head (round-2 verified, 67-68 us)
__global__ __launch_bounds__(256, 4) void route_head(
    const u16* __restrict__ obs_n, const u16* __restrict__ e,
    const u16* __restrict__ Wr0t, const float* __restrict__ br0,
    const u16* __restrict__ Wr1t, const float* __restrict__ br1,
    const u16* __restrict__ Wh0t, const float* __restrict__ bh0,
    const float* __restrict__ Wh1, const float* __restrict__ bh1,
    const float* __restrict__ Wh2, const float* __restrict__ bh2,
    const float* __restrict__ avail,
    const int* __restrict__ bucket, const int* __restrict__ baseArr,
    const int* __restrict__ cntArr, float* __restrict__ outLogits)
{
  __shared__ __align__(16) u16 sm[20480];   // 40960 B
  const int tid = threadIdx.x;

  int cA0, cA1, cA2, cA3, cA4, cA5, bA0, bA1, bA2, bA3, bA4, bA5;
  {
    int4 ca = *(const int4*)cntArr;  int2 cb = *(const int2*)(cntArr + 4);
    int4 ba = *(const int4*)baseArr; int2 bb = *(const int2*)(baseArr + 4);
    cA0 = ca.x; cA1 = ca.y; cA2 = ca.z; cA3 = ca.w; cA4 = cb.x; cA5 = cb.y;
    bA0 = ba.x; bA1 = ba.y; bA2 = ba.z; bA3 = ba.w; bA4 = bb.x; bA5 = bb.y;
  }
  int role = -1, rem = blockIdx.x, cnt = 0, roleBase = 0;
#define TRY_ROLE(k, ck, bk)                                        \
  if (role < 0) {                                                  \
    int tiles = ((ck) + 31) >> 5;                                  \
    if (rem < tiles) { role = (k); cnt = (ck); roleBase = (bk); }  \
    else rem -= tiles;                                             \
  }
  TRY_ROLE(0, cA0, bA0) TRY_ROLE(1, cA1, bA1) TRY_ROLE(2, cA2, bA2)
  TRY_ROLE(3, cA3, bA3) TRY_ROLE(4, cA4, bA4) TRY_ROLE(5, cA5, bA5)
#undef TRY_ROLE
  if (role < 0) return;
  const int limit = cnt;
  const int rowBase = rem * 32;

  const int lane = tid & 63, wave = tid >> 6;
  const int quad = lane >> 4, lm = lane & 15, l7 = lm & 7;

#pragma unroll
  for (int r = 0; r < 8; ++r) {
    int lrow = r * 4 + wave;
    int i = rowBase + lrow;
    if (i >= limit) i = rowBase;
    int grow = bucket[roleBase + i];
    int chunk = tid & 63;
    int sw = (chunk & 56) | ((chunk ^ lrow) & 7);
    gll16(e + (u32)grow * 512u + (u32)(sw * 8), &sm[r * 2048 + wave * 512]);
  }

  int growA0, growA1;
  {
    int i0 = rowBase + lm;        if (i0 >= limit) i0 = rowBase;
    int i1 = rowBase + 16 + lm;   if (i1 >= limit) i1 = rowBase;
    growA0 = bucket[roleBase + i0];
    growA1 = bucket[roleBase + i1];
  }
  const u16* Ag0 = obs_n + (size_t)growA0 * 256;
  const u16* Ag1 = obs_n + (size_t)growA1 * 256;

  // ---- stage0
  const int wn0 = wave * 32;
  const u16* B0 = Wr0t + (size_t)role * 128 * 256;
  f32x4 acc0[2][2] = {};
  bf16x8 b0R[2][2];
#pragma unroll
  for (int p = 0; p < 2; ++p)
#pragma unroll
    for (int j = 0; j < 2; ++j)
      b0R[p][j] = *(const bf16x8*)(B0 + (u32)(wn0 + j * 16 + lm) * 256u + (u32)(quad * 8 + p * 32));
  bf16x8 aR[4][2];
#pragma unroll
  for (int p = 0; p < 4; ++p) {
    aR[p][0] = *(const bf16x8*)(Ag0 + (u32)(quad * 8 + p * 32));
    aR[p][1] = *(const bf16x8*)(Ag1 + (u32)(quad * 8 + p * 32));
  }
  float bias0[2] = { br0[role * 128 + wn0 + lm], br0[role * 128 + wn0 + 16 + lm] };
#pragma unroll
  for (int it = 0; it < 8; ++it) {
    bf16x8 a0 = aR[it & 3][0], a1 = aR[it & 3][1];
    bf16x8 cur0 = b0R[it & 1][0], cur1 = b0R[it & 1][1];
    if (it + 2 < 8) {
#pragma unroll
      for (int j = 0; j < 2; ++j)
        b0R[it & 1][j] = *(const bf16x8*)(B0 + (u32)(wn0 + j * 16 + lm) * 256u + (u32)(quad * 8 + (it + 2) * 32));
    }
    if (it + 4 < 8) {
      aR[it & 3][0] = *(const bf16x8*)(Ag0 + (u32)(quad * 8 + (it + 4) * 32));
      aR[it & 3][1] = *(const bf16x8*)(Ag1 + (u32)(quad * 8 + (it + 4) * 32));
    }
    acc0[0][0] = MFMA(a0, cur0, acc0[0][0], 0, 0, 0);
    acc0[0][1] = MFMA(a0, cur1, acc0[0][1], 0, 0, 0);
    acc0[1][0] = MFMA(a1, cur0, acc0[1][0], 0, 0, 0);
    acc0[1][1] = MFMA(a1, cur1, acc0[1][1], 0, 0, 0);
  }
  u16* r1 = sm + 16384;
#pragma unroll
  for (int i2 = 0; i2 < 2; ++i2) {
#pragma unroll
    for (int r2 = 0; r2 < 4; ++r2) {
      int row = i2 * 16 + quad * 4 + r2;
#pragma unroll
      for (int j = 0; j < 2; ++j) {
        int col = wn0 + j * 16 + lm;
        float v = fmaxf(acc0[i2][j][r2] + bias0[j], 0.f);
        r1[row * 128 + (((col >> 3) ^ (row & 7)) * 8) + (col & 7)] = f2b(v);
      }
    }
  }
  __syncthreads();   // B1

  // ---- stage1: two 64-col halves
  const int wn1 = wave * 128;
  const u16* B1 = Wr1t + (size_t)role * 512 * 128;
#pragma unroll
  for (int h = 0; h < 2; ++h) {
    const int wnh = wn1 + h * 64;
    float b1v[4];
#pragma unroll
    for (int j = 0; j < 4; ++j) b1v[j] = br1[role * 512 + wnh + j * 16 + lm];
    f32x4 acc1[2][4] = {};
    bf16x8 b1P[4];
#pragma unroll
    for (int j = 0; j < 4; ++j)
      b1P[j] = *(const bf16x8*)(B1 + (u32)(wnh + j * 16 + lm) * 128u + (u32)(quad * 8));
#pragma unroll
    for (int kk = 0; kk < 128; kk += 32) {
      bf16x8 b1N[4];
      if (kk + 32 < 128) {
#pragma unroll
        for (int j = 0; j < 4; ++j)
          b1N[j] = *(const bf16x8*)(B1 + (u32)(wnh + j * 16 + lm) * 128u + (u32)(quad * 8 + kk + 32));
      }
      const int kc = kk >> 3;
      bf16x8 af[2];
#pragma unroll
      for (int i2 = 0; i2 < 2; ++i2)
        af[i2] = *(const bf16x8*)&r1[(i2 * 16 + lm) * 128 + (((quad + kc) ^ l7) * 8)];
#pragma unroll
      for (int i2 = 0; i2 < 2; ++i2)
#pragma unroll
        for (int j = 0; j < 4; ++j)
          acc1[i2][j] = MFMA(af[i2], b1P[j], acc1[i2][j], 0, 0, 0);
      if (kk + 32 < 128) {
#pragma unroll
        for (int j = 0; j < 4; ++j) b1P[j] = b1N[j];
      }
    }
#pragma unroll
    for (int i2 = 0; i2 < 2; ++i2) {
#pragma unroll
      for (int r2 = 0; r2 < 4; ++r2) {
        int row = i2 * 16 + quad * 4 + r2;
#pragma unroll
        for (int j = 0; j < 4; ++j) {
          int col = wnh + j * 16 + lm;
          int addr = row * 512 + (((col >> 3) ^ (row & 7)) * 8) + (col & 7);
          float v = fmaxf(acc1[i2][j][r2] + b1v[j], 0.f) + b2f(sm[addr]);
          sm[addr] = f2b(v);
        }
      }
    }
  }
  __syncthreads();

  // ---- stage2
  const int wn2 = wave * 16;
  const u16* B2 = Wh0t + (size_t)role * 64 * 512;
  float b2v = bh0[role * 64 + wn2 + lm];
  f32x4 acc2[2] = {};
  bf16x8 b2R[4];
#pragma unroll
  for (int p = 0; p < 4; ++p)
    b2R[p] = *(const bf16x8*)(B2 + (u32)(wn2 + lm) * 512u + (u32)(quad * 8 + p * 32));
#pragma unroll
  for (int it = 0; it < 16; ++it) {
    bf16x8 cur = b2R[it & 3];
    if (it + 4 < 16)
      b2R[it & 3] = *(const bf16x8*)(B2 + (u32)(wn2 + lm) * 512u + (u32)(quad * 8 + (it + 4) * 32));
    const int kc = it * 4;
    bf16x8 af[2];
#pragma unroll
    for (int i2 = 0; i2 < 2; ++i2)
      af[i2] = *(const bf16x8*)&sm[(i2 * 16 + lm) * 512 + (((quad + kc) ^ l7) * 8)];
#pragma unroll
    for (int i2 = 0; i2 < 2; ++i2)
      acc2[i2] = MFMA(af[i2], cur, acc2[i2], 0, 0, 0);
  }
  u16* h0s = sm + 16384;
#pragma unroll
  for (int i2 = 0; i2 < 2; ++i2) {
#pragma unroll
    for (int r2 = 0; r2 < 4; ++r2) {
      int row = i2 * 16 + quad * 4 + r2;
      int col = wn2 + lm;
      h0s[row * 68 + col] = f2b(fmaxf(acc2[i2][r2] + b2v, 0.f));
    }
  }
  __syncthreads();

  // ---- stage3
  {
    float* h1s = (float*)&sm[16384];
    const int r = tid >> 3;
    const int n0 = (tid & 7) * 4;
    const bool valid = (rowBase + r) < limit;
    const float* W1k = Wh1 + (size_t)role * 64 * 32;
    const float* W2k = Wh2 + (size_t)role * 32 * 32;
    float4 a1 = *(const float4*)(bh1 + role * 32 + n0);
#pragma unroll 8
    for (int j = 0; j < 64; ++j) {
      float hj = b2f(h0s[r * 68 + j]);
      float4 wv = *(const float4*)(W1k + j * 32 + n0);
      a1.x += hj * wv.x; a1.y += hj * wv.y; a1.z += hj * wv.z; a1.w += hj * wv.w;
    }
    a1.x = fmaxf(a1.x, 0.f); a1.y = fmaxf(a1.y, 0.f);
    a1.z = fmaxf(a1.z, 0.f); a1.w = fmaxf(a1.w, 0.f);
    __syncthreads();
    h1s[r * 36 + n0 + 0] = a1.x;
    h1s[r * 36 + n0 + 1] = a1.y;
    h1s[r * 36 + n0 + 2] = a1.z;
    h1s[r * 36 + n0 + 3] = a1.w;
    __syncthreads();
    float4 a2 = *(const float4*)(bh2 + role * 32 + n0);
#pragma unroll 8
    for (int n = 0; n < 32; ++n) {
      float hn = h1s[r * 36 + n];
      float4 wv = *(const float4*)(W2k + n * 32 + n0);
      a2.x += hn * wv.x; a2.y += hn * wv.y; a2.z += hn * wv.z; a2.w += hn * wv.w;
    }
    if (valid) {
      int g = bucket[roleBase + rowBase + r];
      float4 av = *(const float4*)(avail + (size_t)g * 32 + n0);
      float4 o;
      o.x = (av.x > 0.5f) ? a2.x : -1e10f;
      o.y = (av.y > 0.5f) ? a2.y : -1e10f;
      o.z = (av.z > 0.5f) ? a2.z : -1e10f;
      o.w = (av.w > 0.5f) ? a2.w : -1e10f;
      *(float4*)(outLogits + (size_t)g * 32 + n0) = o;
    }
  }
}

// ---------------------------------------------------------------- launcher
extern "C" void kernel_launch(void* const* d_in, const int* in_sizes, int n_in,
                              void* d_out, int out_size, void* d_ws, size_t ws_size,
                              hipStream_t stream)
{
  const float* rnn  = (const float*)d_in[0];
  const float* obs  = (const float*)d_in[1];
  const float* avail= (const float*)d_in[3];
  const int*   rid  = (const int*)d_in[4];
  const float* fn_s = (const float*)d_in[5];
  const float* fn_b = (const float*)d_in[6];
  const float* W0   = (const float*)d_in[7];
  const float* b0   = (const float*)d_in[8];
  const float* ln0s = (const float*)d_in[9];
  const float* ln0b = (const float*)d_in[10];
  const float* W1   = (const float*)d_in[11];
  const float* b1   = (const float*)d_in[12];
  const float* ln1s = (const float*)d_in[13];
  const float* ln1b = (const float*)d_in[14];
  const float* Wr0  = (const float*)d_in[15];
  const float* br0  = (const float*)d_in[16];
  const float* Wr1  = (const float*)d_in[17];
  const float* br1  = (const float*)d_in[18];
  const float* Wh0  = (const float*)d_in[19];
  const float* bh0  = (const float*)d_in[20];
  const float* Wh1  = (const float*)d_in[21];
  const float* bh1  = (const float*)d_in[22];
  const float* Wh2  = (const float*)d_in[23];
  const float* bh2  = (const float*)d_in[24];

  const int ROWS = 32768;

  char* w = (char*)d_ws;
  auto carve = [&](size_t bytes) { char* p = w; w += (bytes + 255) & ~(size_t)255; return p; };
  u16* obs_n  = (u16*)carve((size_t)ROWS * 256 * 2);
  u16* bufB   = (u16*)carve((size_t)ROWS * 512 * 2);   // e
  u16* W0t    = (u16*)carve((size_t)512 * 256 * 2);
  u16* W1t    = (u16*)carve((size_t)512 * 512 * 2);
  u16* Wr0t   = (u16*)carve((size_t)6 * 128 * 256 * 2);
  u16* Wr1t   = (u16*)carve((size_t)6 * 512 * 128 * 2);
  u16* Wh0t   = (u16*)carve((size_t)6 * 64 * 512 * 2);
  int* bucket = (int*)carve((size_t)ROWS * 4);
  int* blkCnt = (int*)carve((size_t)128 * NROLE * 4);
  int* baseArr= (int*)carve(256);
  int* cntArr = (int*)carve(256);

  float* outLogits = (float*)d_out + (size_t)1024 * 512;

  // mega0: weight transposes + role_count + rnn passthrough
  mega0<<<1408, 256, 0, stream>>>(W0, W1, Wr0, Wr1, Wh0, W0t, W1t, Wr0t, Wr1t, Wh0t,
                                  rid, blkCnt, rnn, (float*)d_out);

  // fused obs-LN + gemm0 + LN0 + gemm1 + LN1, 32-row tiles (0..1023) + fill2 (1024..1151)
  base2v<<<1152, 256, 0, stream>>>(obs, fn_s, fn_b, W0t, b0, ln0s, ln0b,
                                   W1t, b1, ln1s, ln1b, obs_n, bufB,
                                   rid, blkCnt, bucket, baseArr, cntArr);

  // fused role route + full head (round-2 verified)
  route_head<<<1029, 256, 0, stream>>>(obs_n, bufB, Wr0t, br0, Wr1t, br1, Wh0t, bh0,
                                       Wh1, bh1, Wh2, bh2, avail,
                                       bucket, baseArr, cntArr, outLogits);
}

// Round 9
// 269.593 us; speedup vs baseline: 1.1225x; 1.1113x over previous
//
#include <hip/hip_runtime.h>
#include <stdint.h>

typedef unsigned short u16;
typedef unsigned int u32;

using bf16x8 = __attribute__((ext_vector_type(8))) short;
using f32x4  = __attribute__((ext_vector_type(4))) float;

#define DEVINL __device__ __forceinline__

DEVINL float b2f(u16 u) { return __builtin_bit_cast(float, (u32)u << 16); }
DEVINL u16 f2b(float f) {
  u32 u = __builtin_bit_cast(u32, f);
  u += 0x7FFFu + ((u >> 16) & 1u);   // round-to-nearest-even
  return (u16)(u >> 16);
}

DEVINL void gll16(const u16* src, u16* dst) {
  __builtin_amdgcn_global_load_lds(
      (const __attribute__((address_space(1))) void*)(uintptr_t)src,
      (__attribute__((address_space(3))) void*)(uintptr_t)dst, 16, 0, 0);
}

#define MFMA __builtin_amdgcn_mfma_f32_16x16x32_bf16
#define NROLE 6

// ---------------------------------------------------------------- mega0:
// transposes (blocks 0..1151) | role_count (1152..1279) | rnn copy (1280..1407).
DEVINL void tp_tile(const float* __restrict__ s, u16* __restrict__ d,
                    int R, int C, int bx, int by, int z)
{
  __shared__ u16 tile[32][33];
  const size_t mstride = (size_t)R * C;
  s += (size_t)z * mstride;
  d += (size_t)z * mstride;
  int r0 = bx * 32, c0 = by * 32;
  int tx = threadIdx.x & 31, ty = threadIdx.x >> 5;
#pragma unroll
  for (int i = 0; i < 32; i += 8)
    tile[ty + i][tx] = f2b(s[(size_t)(r0 + ty + i) * C + (c0 + tx)]);
  __syncthreads();
#pragma unroll
  for (int i = 0; i < 32; i += 8)
    d[(size_t)(c0 + ty + i) * R + (r0 + tx)] = tile[tx][ty + i];
}

__global__ __launch_bounds__(256) void mega0(
    const float* W0, const float* W1, const float* Wr0, const float* Wr1, const float* Wh0,
    u16* W0t, u16* W1t, u16* Wr0t, u16* Wr1t, u16* Wh0t,
    const int* __restrict__ rid, int* __restrict__ blkCnt,
    const float* __restrict__ rnn, float* __restrict__ outRnn)
{
  int b = blockIdx.x;
  const int tid = threadIdx.x;
  if (b < 1152) {
    if (b < 128)      {            tp_tile(W0, W0t, 256, 512, b % 8,  b / 8, 0); }
    else if (b < 384) { b -= 128;  tp_tile(W1, W1t, 512, 512, b % 16, b / 16, 0); }
    else if (b < 576) { b -= 384;  int t = b / 8;  tp_tile(Wr0, Wr0t, 256, 128, b % 8,  t % 4,  t / 4); }
    else if (b < 960) { b -= 576;  int t = b / 4;  tp_tile(Wr1, Wr1t, 128, 512, b % 4,  t % 16, t / 16); }
    else              { b -= 960;  int t = b / 16; tp_tile(Wh0, Wh0t, 512, 64,  b % 16, t % 2,  t / 2); }
  } else if (b < 1280) {
    b -= 1152;
    __shared__ int h[NROLE];
    if (tid < NROLE) h[tid] = 0;
    __syncthreads();
    atomicAdd(&h[rid[b * 256 + tid]], 1);
    __syncthreads();
    if (tid < NROLE) blkCnt[b * NROLE + tid] = h[tid];
  } else {
    b -= 1280;
    const float4* src = (const float4*)rnn;
    float4* dst = (float4*)outRnn;
    int base = (b * 256 + tid) * 4;
#pragma unroll
    for (int i = 0; i < 4; ++i) dst[base + i] = src[base + i];
  }
}

// ---------------------------------------------------------------- base2 (round-6 verified, 64-row tile)
// + coalesced epilogue (the one surgical change vs round 6):
//   LN1 -> LDS linear [64][512] (overlays dead e0) -> coalesced uint4 copy.
//   Round-6's scalar u16 C-stores caused ~17 MB write amplification.
// blocks 0..511: fused obs-LN + gemm0 + LN0 + gemm1 + LN1 for 64 rows.
// blocks 512..639: fill2 (scan + bucket fill), verbatim.
// LDS 67584 B -> 2 blocks/CU:
//   A0  [0,32768)B   64x256 u16 swizzled (dead after gemm0)
//   e0  [0,65536)B   64x512 u16 swizzled (overlays A0); later out-tile linear
//   red [65536,67584)B  redS 256 f32 | redSS 256 f32
__global__ __launch_bounds__(256, 2) void base2(
    const float* __restrict__ obs, const float* __restrict__ fn_s,
    const float* __restrict__ fn_b, const u16* __restrict__ W0t,
    const float* __restrict__ b0, const float* __restrict__ ln0sc,
    const float* __restrict__ ln0bi, const u16* __restrict__ W1t,
    const float* __restrict__ b1, const float* __restrict__ ln1sc,
    const float* __restrict__ ln1bi, u16* __restrict__ obs_n,
    u16* __restrict__ C,
    const int* __restrict__ rid, const int* __restrict__ blkCnt,
    int* __restrict__ bucket, int* __restrict__ baseArr, int* __restrict__ cntArr)
{
  __shared__ __align__(16) u16 smem[33792];   // 67584 B
  const int tid = threadIdx.x;

  if (blockIdx.x >= 512) {
    // ---- fill2 branch (verbatim)
    const int bx = blockIdx.x - 512;
    int* c = (int*)smem;
    int* preArr = c + 768;
    int* scnt   = c + 776;
    int* sbase  = c + 784;
    int* h      = c + 792;
    for (int i = tid; i < 128 * NROLE; i += 256) c[i] = blkCnt[i];
    if (tid < NROLE) h[tid] = 0;
    __syncthreads();
    if (tid < NROLE) {
      int k = tid, run = 0, pre = 0;
      for (int b = 0; b < 128; ++b) { if (b == bx) pre = run; run += c[b * NROLE + k]; }
      scnt[k] = run; preArr[k] = pre;
    }
    __syncthreads();
    if (tid == 0) {
      int r = 0;
      for (int k = 0; k < NROLE; ++k) { sbase[k] = r; r += scnt[k]; }
    }
    __syncthreads();
    if (bx == 0 && tid < NROLE) { baseArr[tid] = sbase[tid]; cntArr[tid] = scnt[tid]; }
    int i = bx * 256 + tid;
    int k = rid[i];
    int pos = atomicAdd(&h[k], 1);
    bucket[sbase[k] + preArr[k] + pos] = i;
    return;
  }

  float* redS  = (float*)&smem[32768];   // [64][4]
  float* redSS = redS + 256;             // [64][4]
  const int rowBase = blockIdx.x * 64;
  const int lane = tid & 63, wave = tid >> 6;
  const int quad = lane >> 4, lm = lane & 15, l7 = lm & 7;
  const int wn = wave * 128;

  // ---- obs-LN staging (round-6 verbatim): A0 swizzled + obs_n to global
  {
    const int r = tid >> 2, q = tid & 3;
    const float* xr = obs + (size_t)(rowBase + r) * 256 + q * 64;
    float x[64];
#pragma unroll
    for (int jj = 0; jj < 16; ++jj)
      *(float4*)&x[jj * 4] = *(const float4*)(xr + jj * 4);
    float s = 0.f, s2 = 0.f;
#pragma unroll
    for (int p = 0; p < 64; ++p) { s += x[p]; s2 += x[p] * x[p]; }
    s  += __shfl_xor(s, 1, 64);  s  += __shfl_xor(s, 2, 64);
    s2 += __shfl_xor(s2, 1, 64); s2 += __shfl_xor(s2, 2, 64);
    float m = s * (1.f / 256.f);
    float var = s2 * (1.f / 256.f) - m * m;
    float inv = rsqrtf(var + 1e-5f);
    const float* fs = fn_s + q * 64;
    const float* fb = fn_b + q * 64;
    u16* og = obs_n + (size_t)(rowBase + r) * 256 + q * 64;
#pragma unroll
    for (int j = 0; j < 8; ++j) {
      float4 fs0 = *(const float4*)(fs + j * 8);
      float4 fs1 = *(const float4*)(fs + j * 8 + 4);
      float4 fb0 = *(const float4*)(fb + j * 8);
      float4 fb1 = *(const float4*)(fb + j * 8 + 4);
      u16 yy[8] __attribute__((aligned(16)));
      yy[0] = f2b((x[j*8+0] - m) * inv * fs0.x + fb0.x);
      yy[1] = f2b((x[j*8+1] - m) * inv * fs0.y + fb0.y);
      yy[2] = f2b((x[j*8+2] - m) * inv * fs0.z + fb0.z);
      yy[3] = f2b((x[j*8+3] - m) * inv * fs0.w + fb0.w);
      yy[4] = f2b((x[j*8+4] - m) * inv * fs1.x + fb1.x);
      yy[5] = f2b((x[j*8+5] - m) * inv * fs1.y + fb1.y);
      yy[6] = f2b((x[j*8+6] - m) * inv * fs1.z + fb1.z);
      yy[7] = f2b((x[j*8+7] - m) * inv * fs1.w + fb1.w);
      int cch = q * 8 + j;
      *(uint4*)&smem[r * 256 + ((cch ^ (r & 7)) * 8)] = *(uint4*)yy;
      *(uint4*)(og + j * 8) = *(uint4*)yy;
    }
  }

  // ---- gemm0: acc = A0 @ W0t^T   (K=256, N=512; wave = 128 cols); B ring-2
  u32 bOff0[8];
#pragma unroll
  for (int j = 0; j < 8; ++j)
    bOff0[j] = (u32)(wn + j * 16 + lm) * 256u + (u32)(quad * 8);
  f32x4 acc[4][8] = {};
  bf16x8 bR[2][8];
#pragma unroll
  for (int p = 0; p < 2; ++p)
#pragma unroll
    for (int j = 0; j < 8; ++j)
      bR[p][j] = *(const bf16x8*)(W0t + bOff0[j] + p * 32);
  __syncthreads();   // B1: A0 staged

#pragma unroll
  for (int g = 0; g < 8; ++g) {
    bf16x8 cur[8];
#pragma unroll
    for (int j = 0; j < 8; ++j) cur[j] = bR[g & 1][j];
    if (g + 2 < 8) {
#pragma unroll
      for (int j = 0; j < 8; ++j)
        bR[g & 1][j] = *(const bf16x8*)(W0t + bOff0[j] + (g + 2) * 32);
    }
    const int kc = g * 4;
    bf16x8 af[4];
#pragma unroll
    for (int i2 = 0; i2 < 4; ++i2)
      af[i2] = *(const bf16x8*)&smem[(i2 * 16 + lm) * 256 + (((quad + kc) ^ l7) * 8)];
#pragma unroll
    for (int i2 = 0; i2 < 4; ++i2)
#pragma unroll
      for (int j = 0; j < 8; ++j)
        acc[i2][j] = MFMA(af[i2], cur[j], acc[i2][j], 0, 0, 0);
  }

  // ---- ReLU + LN0 partials (biases in registers)
  {
    float b0v[8];
#pragma unroll
    for (int j = 0; j < 8; ++j) b0v[j] = b0[wn + j * 16 + lm];
#pragma unroll
    for (int i2 = 0; i2 < 4; ++i2) {
#pragma unroll
      for (int r2 = 0; r2 < 4; ++r2) {
        float s = 0.f, ss = 0.f;
#pragma unroll
        for (int j = 0; j < 8; ++j) {
          float v = fmaxf(acc[i2][j][r2] + b0v[j], 0.f);
          acc[i2][j][r2] = v;
          s += v; ss += v * v;
        }
#pragma unroll
        for (int o = 1; o < 16; o <<= 1) { s += __shfl_xor(s, o, 64); ss += __shfl_xor(ss, o, 64); }
        if (lm == 0) {
          int row = i2 * 16 + quad * 4 + r2;
          redS[row * 4 + wave] = s;
          redSS[row * 4 + wave] = ss;
        }
      }
    }
  }
  __syncthreads();   // B2: red0 done AND all A0 reads done

  // ---- LN0 finalize -> e0 bf16 into [0,65536)B (overlays dead A0)
  {
    float s0v[8], s0b[8];
#pragma unroll
    for (int j = 0; j < 8; ++j) {
      s0v[j] = ln0sc[wn + j * 16 + lm];
      s0b[j] = ln0bi[wn + j * 16 + lm];
    }
#pragma unroll
    for (int i2 = 0; i2 < 4; ++i2) {
#pragma unroll
      for (int r2 = 0; r2 < 4; ++r2) {
        int row = i2 * 16 + quad * 4 + r2;
        float ts  = redS[row * 4 + 0] + redS[row * 4 + 1] + redS[row * 4 + 2] + redS[row * 4 + 3];
        float tss = redSS[row * 4 + 0] + redSS[row * 4 + 1] + redSS[row * 4 + 2] + redSS[row * 4 + 3];
        float m = ts * (1.f / 512.f);
        float var = tss * (1.f / 512.f) - m * m;
        float inv = rsqrtf(var + 1e-5f);
#pragma unroll
        for (int j = 0; j < 8; ++j) {
          int col = wn + j * 16 + lm;
          float y = (acc[i2][j][r2] - m) * inv * s0v[j] + s0b[j];
          smem[row * 512 + (((col >> 3) ^ (row & 7)) * 8) + (col & 7)] = f2b(y);
        }
      }
    }
  }
  // gemm1 B preload before the barrier (hide L2 latency under the drain)
  u32 bOff1[8];
#pragma unroll
  for (int j = 0; j < 8; ++j)
    bOff1[j] = (u32)(wn + j * 16 + lm) * 512u + (u32)(quad * 8);
#pragma unroll
  for (int p = 0; p < 2; ++p)
#pragma unroll
    for (int j = 0; j < 8; ++j)
      bR[p][j] = *(const bf16x8*)(W1t + bOff1[j] + p * 32);
  __syncthreads();   // B3: e0 visible; red reusable

  // ---- gemm1: acc = e0 @ W1t^T   (K=512, N=512); B ring-2
#pragma unroll
  for (int i2 = 0; i2 < 4; ++i2)
#pragma unroll
    for (int j = 0; j < 8; ++j)
      acc[i2][j] = (f32x4){0.f, 0.f, 0.f, 0.f};
#pragma unroll
  for (int g = 0; g < 16; ++g) {
    bf16x8 cur[8];
#pragma unroll
    for (int j = 0; j < 8; ++j) cur[j] = bR[g & 1][j];
    if (g + 2 < 16) {
#pragma unroll
      for (int j = 0; j < 8; ++j)
        bR[g & 1][j] = *(const bf16x8*)(W1t + bOff1[j] + (g + 2) * 32);
    }
    const int kc = g * 4;
    bf16x8 af[4];
#pragma unroll
    for (int i2 = 0; i2 < 4; ++i2)
      af[i2] = *(const bf16x8*)&smem[(i2 * 16 + lm) * 512 + (((quad + kc) ^ l7) * 8)];
#pragma unroll
    for (int i2 = 0; i2 < 4; ++i2)
#pragma unroll
      for (int j = 0; j < 8; ++j)
        acc[i2][j] = MFMA(af[i2], cur[j], acc[i2][j], 0, 0, 0);
  }

  // ---- ReLU + LN1 partials
  {
    float b1v[8];
#pragma unroll
    for (int j = 0; j < 8; ++j) b1v[j] = b1[wn + j * 16 + lm];
#pragma unroll
    for (int i2 = 0; i2 < 4; ++i2) {
#pragma unroll
      for (int r2 = 0; r2 < 4; ++r2) {
        float s = 0.f, ss = 0.f;
#pragma unroll
        for (int j = 0; j < 8; ++j) {
          float v = fmaxf(acc[i2][j][r2] + b1v[j], 0.f);
          acc[i2][j][r2] = v;
          s += v; ss += v * v;
        }
#pragma unroll
        for (int o = 1; o < 16; o <<= 1) { s += __shfl_xor(s, o, 64); ss += __shfl_xor(ss, o, 64); }
        if (lm == 0) {
          int row = i2 * 16 + quad * 4 + r2;
          redS[row * 4 + wave] = s;
          redSS[row * 4 + wave] = ss;
        }
      }
    }
  }
  __syncthreads();   // B4: red1 done; all e0 reads done

  // ---- LN1 finalize -> LDS out-tile (linear [64][512], overlays dead e0)
  {
    float s1v[8], s1b[8];
#pragma unroll
    for (int j = 0; j < 8; ++j) {
      s1v[j] = ln1sc[wn + j * 16 + lm];
      s1b[j] = ln1bi[wn + j * 16 + lm];
    }
#pragma unroll
    for (int i2 = 0; i2 < 4; ++i2) {
#pragma unroll
      for (int r2 = 0; r2 < 4; ++r2) {
        int row = i2 * 16 + quad * 4 + r2;
        float ts  = redS[row * 4 + 0] + redS[row * 4 + 1] + redS[row * 4 + 2] + redS[row * 4 + 3];
        float tss = redSS[row * 4 + 0] + redSS[row * 4 + 1] + redSS[row * 4 + 2] + redSS[row * 4 + 3];
        float m = ts * (1.f / 512.f);
        float var = tss * (1.f / 512.f) - m * m;
        float inv = rsqrtf(var + 1e-5f);
#pragma unroll
        for (int j = 0; j < 8; ++j) {
          int col = wn + j * 16 + lm;
          float y = (acc[i2][j][r2] - m) * inv * s1v[j] + s1b[j];
          smem[row * 512 + col] = f2b(y);
        }
      }
    }
  }
  __syncthreads();   // B5: out-tile complete

  // ---- coalesced copy LDS -> bufB (64 KB; 4 KB per block-instruction)
  {
    u16* dst = C + (size_t)rowBase * 512;
#pragma unroll
    for (int it = 0; it < 16; ++it) {
      int idx = (it * 256 + tid) * 8;   // u16 units
      *(uint4*)(dst + idx) = *(const uint4*)&smem[idx];
    }
  }
}

// ---------------------------------------------------------------- route_head (round-2 verified, 67-68 us)
__global__ __launch_bounds__(256, 4) void route_head(
    const u16* __restrict__ obs_n, const u16* __restrict__ e,
    const u16* __restrict__ Wr0t, const float* __restrict__ br0,
    const u16* __restrict__ Wr1t, const float* __restrict__ br1,
    const u16* __restrict__ Wh0t, const float* __restrict__ bh0,
    const float* __restrict__ Wh1, const float* __restrict__ bh1,
    const float* __restrict__ Wh2, const float* __restrict__ bh2,
    const float* __restrict__ avail,
    const int* __restrict__ bucket, const int* __restrict__ baseArr,
    const int* __restrict__ cntArr, float* __restrict__ outLogits)
{
  __shared__ __align__(16) u16 sm[20480];   // 40960 B
  const int tid = threadIdx.x;

  int cA0, cA1, cA2, cA3, cA4, cA5, bA0, bA1, bA2, bA3, bA4, bA5;
  {
    int4 ca = *(const int4*)cntArr;  int2 cb = *(const int2*)(cntArr + 4);
    int4 ba = *(const int4*)baseArr; int2 bb = *(const int2*)(baseArr + 4);
    cA0 = ca.x; cA1 = ca.y; cA2 = ca.z; cA3 = ca.w; cA4 = cb.x; cA5 = cb.y;
    bA0 = ba.x; bA1 = ba.y; bA2 = ba.z; bA3 = ba.w; bA4 = bb.x; bA5 = bb.y;
  }
  int role = -1, rem = blockIdx.x, cnt = 0, roleBase = 0;
#define TRY_ROLE(k, ck, bk)                                        \
  if (role < 0) {                                                  \
    int tiles = ((ck) + 31) >> 5;                                  \
    if (rem < tiles) { role = (k); cnt = (ck); roleBase = (bk); }  \
    else rem -= tiles;                                             \
  }
  TRY_ROLE(0, cA0, bA0) TRY_ROLE(1, cA1, bA1) TRY_ROLE(2, cA2, bA2)
  TRY_ROLE(3, cA3, bA3) TRY_ROLE(4, cA4, bA4) TRY_ROLE(5, cA5, bA5)
#undef TRY_ROLE
  if (role < 0) return;
  const int limit = cnt;
  const int rowBase = rem * 32;

  const int lane = tid & 63, wave = tid >> 6;
  const int quad = lane >> 4, lm = lane & 15, l7 = lm & 7;

#pragma unroll
  for (int r = 0; r < 8; ++r) {
    int lrow = r * 4 + wave;
    int i = rowBase + lrow;
    if (i >= limit) i = rowBase;
    int grow = bucket[roleBase + i];
    int chunk = tid & 63;
    int sw = (chunk & 56) | ((chunk ^ lrow) & 7);
    gll16(e + (u32)grow * 512u + (u32)(sw * 8), &sm[r * 2048 + wave * 512]);
  }

  int growA0, growA1;
  {
    int i0 = rowBase + lm;        if (i0 >= limit) i0 = rowBase;
    int i1 = rowBase + 16 + lm;   if (i1 >= limit) i1 = rowBase;
    growA0 = bucket[roleBase + i0];
    growA1 = bucket[roleBase + i1];
  }
  const u16* Ag0 = obs_n + (size_t)growA0 * 256;
  const u16* Ag1 = obs_n + (size_t)growA1 * 256;

  // ---- stage0
  const int wn0 = wave * 32;
  const u16* B0 = Wr0t + (size_t)role * 128 * 256;
  f32x4 acc0[2][2] = {};
  bf16x8 b0R[2][2];
#pragma unroll
  for (int p = 0; p < 2; ++p)
#pragma unroll
    for (int j = 0; j < 2; ++j)
      b0R[p][j] = *(const bf16x8*)(B0 + (u32)(wn0 + j * 16 + lm) * 256u + (u32)(quad * 8 + p * 32));
  bf16x8 aR[4][2];
#pragma unroll
  for (int p = 0; p < 4; ++p) {
    aR[p][0] = *(const bf16x8*)(Ag0 + (u32)(quad * 8 + p * 32));
    aR[p][1] = *(const bf16x8*)(Ag1 + (u32)(quad * 8 + p * 32));
  }
  float bias0[2] = { br0[role * 128 + wn0 + lm], br0[role * 128 + wn0 + 16 + lm] };
#pragma unroll
  for (int it = 0; it < 8; ++it) {
    bf16x8 a0 = aR[it & 3][0], a1 = aR[it & 3][1];
    bf16x8 cur0 = b0R[it & 1][0], cur1 = b0R[it & 1][1];
    if (it + 2 < 8) {
#pragma unroll
      for (int j = 0; j < 2; ++j)
        b0R[it & 1][j] = *(const bf16x8*)(B0 + (u32)(wn0 + j * 16 + lm) * 256u + (u32)(quad * 8 + (it + 2) * 32));
    }
    if (it + 4 < 8) {
      aR[it & 3][0] = *(const bf16x8*)(Ag0 + (u32)(quad * 8 + (it + 4) * 32));
      aR[it & 3][1] = *(const bf16x8*)(Ag1 + (u32)(quad * 8 + (it + 4) * 32));
    }
    acc0[0][0] = MFMA(a0, cur0, acc0[0][0], 0, 0, 0);
    acc0[0][1] = MFMA(a0, cur1, acc0[0][1], 0, 0, 0);
    acc0[1][0] = MFMA(a1, cur0, acc0[1][0], 0, 0, 0);
    acc0[1][1] = MFMA(a1, cur1, acc0[1][1], 0, 0, 0);
  }
  u16* r1 = sm + 16384;
#pragma unroll
  for (int i2 = 0; i2 < 2; ++i2) {
#pragma unroll
    for (int r2 = 0; r2 < 4; ++r2) {
      int row = i2 * 16 + quad * 4 + r2;
#pragma unroll
      for (int j = 0; j < 2; ++j) {
        int col = wn0 + j * 16 + lm;
        float v = fmaxf(acc0[i2][j][r2] + bias0[j], 0.f);
        r1[row * 128 + (((col >> 3) ^ (row & 7)) * 8) + (col & 7)] = f2b(v);
      }
    }
  }
  __syncthreads();   // B1: r1 ready; drains e-staging vmcnt

  // ---- stage1: two 64-col halves
  const int wn1 = wave * 128;
  const u16* B1 = Wr1t + (size_t)role * 512 * 128;
#pragma unroll
  for (int h = 0; h < 2; ++h) {
    const int wnh = wn1 + h * 64;
    float b1v[4];
#pragma unroll
    for (int j = 0; j < 4; ++j) b1v[j] = br1[role * 512 + wnh + j * 16 + lm];
    f32x4 acc1[2][4] = {};
    bf16x8 b1P[4];
#pragma unroll
    for (int j = 0; j < 4; ++j)
      b1P[j] = *(const bf16x8*)(B1 + (u32)(wnh + j * 16 + lm) * 128u + (u32)(quad * 8));
#pragma unroll
    for (int kk = 0; kk < 128; kk += 32) {
      bf16x8 b1N[4];
      if (kk + 32 < 128) {
#pragma unroll
        for (int j = 0; j < 4; ++j)
          b1N[j] = *(const bf16x8*)(B1 + (u32)(wnh + j * 16 + lm) * 128u + (u32)(quad * 8 + kk + 32));
      }
      const int kc = kk >> 3;
      bf16x8 af[2];
#pragma unroll
      for (int i2 = 0; i2 < 2; ++i2)
        af[i2] = *(const bf16x8*)&r1[(i2 * 16 + lm) * 128 + (((quad + kc) ^ l7) * 8)];
#pragma unroll
      for (int i2 = 0; i2 < 2; ++i2)
#pragma unroll
        for (int j = 0; j < 4; ++j)
          acc1[i2][j] = MFMA(af[i2], b1P[j], acc1[i2][j], 0, 0, 0);
      if (kk + 32 < 128) {
#pragma unroll
        for (int j = 0; j < 4; ++j) b1P[j] = b1N[j];
      }
    }
#pragma unroll
    for (int i2 = 0; i2 < 2; ++i2) {
#pragma unroll
      for (int r2 = 0; r2 < 4; ++r2) {
        int row = i2 * 16 + quad * 4 + r2;
#pragma unroll
        for (int j = 0; j < 4; ++j) {
          int col = wnh + j * 16 + lm;
          int addr = row * 512 + (((col >> 3) ^ (row & 7)) * 8) + (col & 7);
          float v = fmaxf(acc1[i2][j][r2] + b1v[j], 0.f) + b2f(sm[addr]);
          sm[addr] = f2b(v);
        }
      }
    }
  }
  __syncthreads();

  // ---- stage2
  const int wn2 = wave * 16;
  const u16* B2 = Wh0t + (size_t)role * 64 * 512;
  float b2v = bh0[role * 64 + wn2 + lm];
  f32x4 acc2[2] = {};
  bf16x8 b2R[4];
#pragma unroll
  for (int p = 0; p < 4; ++p)
    b2R[p] = *(const bf16x8*)(B2 + (u32)(wn2 + lm) * 512u + (u32)(quad * 8 + p * 32));
#pragma unroll
  for (int it = 0; it < 16; ++it) {
    bf16x8 cur = b2R[it & 3];
    if (it + 4 < 16)
      b2R[it & 3] = *(const bf16x8*)(B2 + (u32)(wn2 + lm) * 512u + (u32)(quad * 8 + (it + 4) * 32));
    const int kc = it * 4;
    bf16x8 af[2];
#pragma unroll
    for (int i2 = 0; i2 < 2; ++i2)
      af[i2] = *(const bf16x8*)&sm[(i2 * 16 + lm) * 512 + (((quad + kc) ^ l7) * 8)];
#pragma unroll
    for (int i2 = 0; i2 < 2; ++i2)
      acc2[i2] = MFMA(af[i2], cur, acc2[i2], 0, 0, 0);
  }
  u16* h0s = sm + 16384;
#pragma unroll
  for (int i2 = 0; i2 < 2; ++i2) {
#pragma unroll
    for (int r2 = 0; r2 < 4; ++r2) {
      int row = i2 * 16 + quad * 4 + r2;
      int col = wn2 + lm;
      h0s[row * 68 + col] = f2b(fmaxf(acc2[i2][r2] + b2v, 0.f));
    }
  }
  __syncthreads();

  // ---- stage3
  {
    float* h1s = (float*)&sm[16384];
    const int r = tid >> 3;
    const int n0 = (tid & 7) * 4;
    const bool valid = (rowBase + r) < limit;
    const float* W1k = Wh1 + (size_t)role * 64 * 32;
    const float* W2k = Wh2 + (size_t)role * 32 * 32;
    float4 a1 = *(const float4*)(bh1 + role * 32 + n0);
#pragma unroll 8
    for (int j = 0; j < 64; ++j) {
      float hj = b2f(h0s[r * 68 + j]);
      float4 wv = *(const float4*)(W1k + j * 32 + n0);
      a1.x += hj * wv.x; a1.y += hj * wv.y; a1.z += hj * wv.z; a1.w += hj * wv.w;
    }
    a1.x = fmaxf(a1.x, 0.f); a1.y = fmaxf(a1.y, 0.f);
    a1.z = fmaxf(a1.z, 0.f); a1.w = fmaxf(a1.w, 0.f);
    __syncthreads();
    h1s[r * 36 + n0 + 0] = a1.x;
    h1s[r * 36 + n0 + 1] = a1.y;
    h1s[r * 36 + n0 + 2] = a1.z;
    h1s[r * 36 + n0 + 3] = a1.w;
    __syncthreads();
    float4 a2 = *(const float4*)(bh2 + role * 32 + n0);
#pragma unroll 8
    for (int n = 0; n < 32; ++n) {
      float hn = h1s[r * 36 + n];
      float4 wv = *(const float4*)(W2k + n * 32 + n0);
      a2.x += hn * wv.x; a2.y += hn * wv.y; a2.z += hn * wv.z; a2.w += hn * wv.w;
    }
    if (valid) {
      int g = bucket[roleBase + rowBase + r];
      float4 av = *(const float4*)(avail + (size_t)g * 32 + n0);
      float4 o;
      o.x = (av.x > 0.5f) ? a2.x : -1e10f;
      o.y = (av.y > 0.5f) ? a2.y : -1e10f;
      o.z = (av.z > 0.5f) ? a2.z : -1e10f;
      o.w = (av.w > 0.5f) ? a2.w : -1e10f;
      *(float4*)(outLogits + (size_t)g * 32 + n0) = o;
    }
  }
}

// ---------------------------------------------------------------- launcher
extern "C" void kernel_launch(void* const* d_in, const int* in_sizes, int n_in,
                              void* d_out, int out_size, void* d_ws, size_t ws_size,
                              hipStream_t stream)
{
  const float* rnn  = (const float*)d_in[0];
  const float* obs  = (const float*)d_in[1];
  const float* avail= (const float*)d_in[3];
  const int*   rid  = (const int*)d_in[4];
  const float* fn_s = (const float*)d_in[5];
  const float* fn_b = (const float*)d_in[6];
  const float* W0   = (const float*)d_in[7];
  const float* b0   = (const float*)d_in[8];
  const float* ln0s = (const float*)d_in[9];
  const float* ln0b = (const float*)d_in[10];
  const float* W1   = (const float*)d_in[11];
  const float* b1   = (const float*)d_in[12];
  const float* ln1s = (const float*)d_in[13];
  const float* ln1b = (const float*)d_in[14];
  const float* Wr0  = (const float*)d_in[15];
  const float* br0  = (const float*)d_in[16];
  const float* Wr1  = (const float*)d_in[17];
  const float* br1  = (const float*)d_in[18];
  const float* Wh0  = (const float*)d_in[19];
  const float* bh0  = (const float*)d_in[20];
  const float* Wh1  = (const float*)d_in[21];
  const float* bh1  = (const float*)d_in[22];
  const float* Wh2  = (const float*)d_in[23];
  const float* bh2  = (const float*)d_in[24];

  const int ROWS = 32768;

  char* w = (char*)d_ws;
  auto carve = [&](size_t bytes) { char* p = w; w += (bytes + 255) & ~(size_t)255; return p; };
  u16* obs_n  = (u16*)carve((size_t)ROWS * 256 * 2);
  u16* bufB   = (u16*)carve((size_t)ROWS * 512 * 2);   // e
  u16* W0t    = (u16*)carve((size_t)512 * 256 * 2);
  u16* W1t    = (u16*)carve((size_t)512 * 512 * 2);
  u16* Wr0t   = (u16*)carve((size_t)6 * 128 * 256 * 2);
  u16* Wr1t   = (u16*)carve((size_t)6 * 512 * 128 * 2);
  u16* Wh0t   = (u16*)carve((size_t)6 * 64 * 512 * 2);
  int* bucket = (int*)carve((size_t)ROWS * 4);
  int* blkCnt = (int*)carve((size_t)128 * NROLE * 4);
  int* baseArr= (int*)carve(256);
  int* cntArr = (int*)carve(256);

  float* outLogits = (float*)d_out + (size_t)1024 * 512;

  // mega0: weight transposes + role_count + rnn passthrough
  mega0<<<1408, 256, 0, stream>>>(W0, W1, Wr0, Wr1, Wh0, W0t, W1t, Wr0t, Wr1t, Wh0t,
                                  rid, blkCnt, rnn, (float*)d_out);

  // fused obs-LN + gemm0 + LN0 + gemm1 + LN1 (blocks 0..511) and fill2 (512..639)
  base2<<<640, 256, 0, stream>>>(obs, fn_s, fn_b, W0t, b0, ln0s, ln0b,
                                 W1t, b1, ln1s, ln1b, obs_n, bufB,
                                 rid, blkCnt, bucket, baseArr, cntArr);

  // fused role route + full head (round-2 verified)
  route_head<<<1029, 256, 0, stream>>>(obs_n, bufB, Wr0t, br0, Wr1t, br1, Wh0t, bh0,
                                       Wh1, bh1, Wh2, bh2, avail,
                                       bucket, baseArr, cntArr, outLogits);
}

// Round 10
// 266.943 us; speedup vs baseline: 1.1336x; 1.0099x over previous
//
#include <hip/hip_runtime.h>
#include <stdint.h>

typedef unsigned short u16;
typedef unsigned int u32;

using bf16x8 = __attribute__((ext_vector_type(8))) short;
using f32x4  = __attribute__((ext_vector_type(4))) float;

#define DEVINL __device__ __forceinline__

DEVINL float b2f(u16 u) { return __builtin_bit_cast(float, (u32)u << 16); }
DEVINL u16 f2b(float f) {
  u32 u = __builtin_bit_cast(u32, f);
  u += 0x7FFFu + ((u >> 16) & 1u);   // round-to-nearest-even
  return (u16)(u >> 16);
}

DEVINL void gll16(const u16* src, u16* dst) {
  __builtin_amdgcn_global_load_lds(
      (const __attribute__((address_space(1))) void*)(uintptr_t)src,
      (__attribute__((address_space(3))) void*)(uintptr_t)dst, 16, 0, 0);
}

#define MFMA __builtin_amdgcn_mfma_f32_16x16x32_bf16
#define NROLE 6

// ---------------------------------------------------------------- mega0:
// transposes (blocks 0..1151) | role_count (1152..1279) | rnn copy (1280..1407).
DEVINL void tp_tile(const float* __restrict__ s, u16* __restrict__ d,
                    int R, int C, int bx, int by, int z)
{
  __shared__ u16 tile[32][33];
  const size_t mstride = (size_t)R * C;
  s += (size_t)z * mstride;
  d += (size_t)z * mstride;
  int r0 = bx * 32, c0 = by * 32;
  int tx = threadIdx.x & 31, ty = threadIdx.x >> 5;
#pragma unroll
  for (int i = 0; i < 32; i += 8)
    tile[ty + i][tx] = f2b(s[(size_t)(r0 + ty + i) * C + (c0 + tx)]);
  __syncthreads();
#pragma unroll
  for (int i = 0; i < 32; i += 8)
    d[(size_t)(c0 + ty + i) * R + (r0 + tx)] = tile[tx][ty + i];
}

__global__ __launch_bounds__(256) void mega0(
    const float* W0, const float* W1, const float* Wr0, const float* Wr1, const float* Wh0,
    u16* W0t, u16* W1t, u16* Wr0t, u16* Wr1t, u16* Wh0t,
    const int* __restrict__ rid, int* __restrict__ blkCnt,
    const float* __restrict__ rnn, float* __restrict__ outRnn)
{
  int b = blockIdx.x;
  const int tid = threadIdx.x;
  if (b < 1152) {
    if (b < 128)      {            tp_tile(W0, W0t, 256, 512, b % 8,  b / 8, 0); }
    else if (b < 384) { b -= 128;  tp_tile(W1, W1t, 512, 512, b % 16, b / 16, 0); }
    else if (b < 576) { b -= 384;  int t = b / 8;  tp_tile(Wr0, Wr0t, 256, 128, b % 8,  t % 4,  t / 4); }
    else if (b < 960) { b -= 576;  int t = b / 4;  tp_tile(Wr1, Wr1t, 128, 512, b % 4,  t % 16, t / 16); }
    else              { b -= 960;  int t = b / 16; tp_tile(Wh0, Wh0t, 512, 64,  b % 16, t % 2,  t / 2); }
  } else if (b < 1280) {
    b -= 1152;
    __shared__ int h[NROLE];
    if (tid < NROLE) h[tid] = 0;
    __syncthreads();
    atomicAdd(&h[rid[b * 256 + tid]], 1);
    __syncthreads();
    if (tid < NROLE) blkCnt[b * NROLE + tid] = h[tid];
  } else {
    b -= 1280;
    const float4* src = (const float4*)rnn;
    float4* dst = (float4*)outRnn;
    int base = (b * 256 + tid) * 4;
#pragma unroll
    for (int i = 0; i < 4; ++i) dst[base + i] = src[base + i];
  }
}

// ---------------------------------------------------------------- base2 (64-row tile, round-6/9 verified)
// Change vs round 9: obs_n is no longer written via the scattered 16B-per-
// lane staging stores (which cost ~2x HBM sector amplification on 16.8 MB).
// Instead, after gemm0 (A0 still live), an unswizzling LDS->global copy
// writes obs_n fully coalesced (1 KB contiguous per wave-instruction).
// blocks 0..511: fused obs-LN + gemm0 + LN0 + gemm1 + LN1 for 64 rows.
// blocks 512..639: fill2 (scan + bucket fill), verbatim.
// LDS 67584 B -> 2 blocks/CU:
//   A0  [0,32768)B   64x256 u16 swizzled (dead after B2)
//   e0  [0,65536)B   64x512 u16 swizzled (overlays A0); later out-tile linear
//   red [65536,67584)B  redS 256 f32 | redSS 256 f32
__global__ __launch_bounds__(256, 2) void base2(
    const float* __restrict__ obs, const float* __restrict__ fn_s,
    const float* __restrict__ fn_b, const u16* __restrict__ W0t,
    const float* __restrict__ b0, const float* __restrict__ ln0sc,
    const float* __restrict__ ln0bi, const u16* __restrict__ W1t,
    const float* __restrict__ b1, const float* __restrict__ ln1sc,
    const float* __restrict__ ln1bi, u16* __restrict__ obs_n,
    u16* __restrict__ C,
    const int* __restrict__ rid, const int* __restrict__ blkCnt,
    int* __restrict__ bucket, int* __restrict__ baseArr, int* __restrict__ cntArr)
{
  __shared__ __align__(16) u16 smem[33792];   // 67584 B
  const int tid = threadIdx.x;

  if (blockIdx.x >= 512) {
    // ---- fill2 branch (verbatim)
    const int bx = blockIdx.x - 512;
    int* c = (int*)smem;
    int* preArr = c + 768;
    int* scnt   = c + 776;
    int* sbase  = c + 784;
    int* h      = c + 792;
    for (int i = tid; i < 128 * NROLE; i += 256) c[i] = blkCnt[i];
    if (tid < NROLE) h[tid] = 0;
    __syncthreads();
    if (tid < NROLE) {
      int k = tid, run = 0, pre = 0;
      for (int b = 0; b < 128; ++b) { if (b == bx) pre = run; run += c[b * NROLE + k]; }
      scnt[k] = run; preArr[k] = pre;
    }
    __syncthreads();
    if (tid == 0) {
      int r = 0;
      for (int k = 0; k < NROLE; ++k) { sbase[k] = r; r += scnt[k]; }
    }
    __syncthreads();
    if (bx == 0 && tid < NROLE) { baseArr[tid] = sbase[tid]; cntArr[tid] = scnt[tid]; }
    int i = bx * 256 + tid;
    int k = rid[i];
    int pos = atomicAdd(&h[k], 1);
    bucket[sbase[k] + preArr[k] + pos] = i;
    return;
  }

  float* redS  = (float*)&smem[32768];   // [64][4]
  float* redSS = redS + 256;             // [64][4]
  const int rowBase = blockIdx.x * 64;
  const int lane = tid & 63, wave = tid >> 6;
  const int quad = lane >> 4, lm = lane & 15, l7 = lm & 7;
  const int wn = wave * 128;

  // ---- obs-LN staging: A0 swizzled to LDS only (global obs_n written later,
  // coalesced, from LDS).
  {
    const int r = tid >> 2, q = tid & 3;
    const float* xr = obs + (size_t)(rowBase + r) * 256 + q * 64;
    float x[64];
#pragma unroll
    for (int jj = 0; jj < 16; ++jj)
      *(float4*)&x[jj * 4] = *(const float4*)(xr + jj * 4);
    float s = 0.f, s2 = 0.f;
#pragma unroll
    for (int p = 0; p < 64; ++p) { s += x[p]; s2 += x[p] * x[p]; }
    s  += __shfl_xor(s, 1, 64);  s  += __shfl_xor(s, 2, 64);
    s2 += __shfl_xor(s2, 1, 64); s2 += __shfl_xor(s2, 2, 64);
    float m = s * (1.f / 256.f);
    float var = s2 * (1.f / 256.f) - m * m;
    float inv = rsqrtf(var + 1e-5f);
    const float* fs = fn_s + q * 64;
    const float* fb = fn_b + q * 64;
#pragma unroll
    for (int j = 0; j < 8; ++j) {
      float4 fs0 = *(const float4*)(fs + j * 8);
      float4 fs1 = *(const float4*)(fs + j * 8 + 4);
      float4 fb0 = *(const float4*)(fb + j * 8);
      float4 fb1 = *(const float4*)(fb + j * 8 + 4);
      u16 yy[8] __attribute__((aligned(16)));
      yy[0] = f2b((x[j*8+0] - m) * inv * fs0.x + fb0.x);
      yy[1] = f2b((x[j*8+1] - m) * inv * fs0.y + fb0.y);
      yy[2] = f2b((x[j*8+2] - m) * inv * fs0.z + fb0.z);
      yy[3] = f2b((x[j*8+3] - m) * inv * fs0.w + fb0.w);
      yy[4] = f2b((x[j*8+4] - m) * inv * fs1.x + fb1.x);
      yy[5] = f2b((x[j*8+5] - m) * inv * fs1.y + fb1.y);
      yy[6] = f2b((x[j*8+6] - m) * inv * fs1.z + fb1.z);
      yy[7] = f2b((x[j*8+7] - m) * inv * fs1.w + fb1.w);
      int cch = q * 8 + j;
      *(uint4*)&smem[r * 256 + ((cch ^ (r & 7)) * 8)] = *(uint4*)yy;
    }
  }

  // ---- gemm0: acc = A0 @ W0t^T   (K=256, N=512; wave = 128 cols); B ring-2
  u32 bOff0[8];
#pragma unroll
  for (int j = 0; j < 8; ++j)
    bOff0[j] = (u32)(wn + j * 16 + lm) * 256u + (u32)(quad * 8);
  f32x4 acc[4][8] = {};
  bf16x8 bR[2][8];
#pragma unroll
  for (int p = 0; p < 2; ++p)
#pragma unroll
    for (int j = 0; j < 8; ++j)
      bR[p][j] = *(const bf16x8*)(W0t + bOff0[j] + p * 32);
  __syncthreads();   // B1: A0 staged

#pragma unroll
  for (int g = 0; g < 8; ++g) {
    bf16x8 cur[8];
#pragma unroll
    for (int j = 0; j < 8; ++j) cur[j] = bR[g & 1][j];
    if (g + 2 < 8) {
#pragma unroll
      for (int j = 0; j < 8; ++j)
        bR[g & 1][j] = *(const bf16x8*)(W0t + bOff0[j] + (g + 2) * 32);
    }
    const int kc = g * 4;
    bf16x8 af[4];
#pragma unroll
    for (int i2 = 0; i2 < 4; ++i2)
      af[i2] = *(const bf16x8*)&smem[(i2 * 16 + lm) * 256 + (((quad + kc) ^ l7) * 8)];
#pragma unroll
    for (int i2 = 0; i2 < 4; ++i2)
#pragma unroll
      for (int j = 0; j < 8; ++j)
        acc[i2][j] = MFMA(af[i2], cur[j], acc[i2][j], 0, 0, 0);
  }

  // ---- coalesced obs_n write: unswizzle A0 LDS -> global (32 KB/block).
  // A0 is read-only here and stays intact until the e0 overwrite after B2,
  // which no wave reaches before its own copy completes (B2 fences).
  {
    u16* dst = obs_n + (size_t)rowBase * 256;
#pragma unroll
    for (int it = 0; it < 8; ++it) {
      int li = it * 256 + tid;          // linear uint4 index, 0..2047
      int r = li >> 5, c = li & 31;     // row 0..63, chunk 0..31
      *(uint4*)(dst + li * 8) =
          *(const uint4*)&smem[r * 256 + ((c ^ (r & 7)) * 8)];
    }
  }

  // ---- ReLU + LN0 partials (biases in registers)
  {
    float b0v[8];
#pragma unroll
    for (int j = 0; j < 8; ++j) b0v[j] = b0[wn + j * 16 + lm];
#pragma unroll
    for (int i2 = 0; i2 < 4; ++i2) {
#pragma unroll
      for (int r2 = 0; r2 < 4; ++r2) {
        float s = 0.f, ss = 0.f;
#pragma unroll
        for (int j = 0; j < 8; ++j) {
          float v = fmaxf(acc[i2][j][r2] + b0v[j], 0.f);
          acc[i2][j][r2] = v;
          s += v; ss += v * v;
        }
#pragma unroll
        for (int o = 1; o < 16; o <<= 1) { s += __shfl_xor(s, o, 64); ss += __shfl_xor(ss, o, 64); }
        if (lm == 0) {
          int row = i2 * 16 + quad * 4 + r2;
          redS[row * 4 + wave] = s;
          redSS[row * 4 + wave] = ss;
        }
      }
    }
  }
  __syncthreads();   // B2: red0 done, A0 reads done, obs_n copies done

  // ---- LN0 finalize -> e0 bf16 into [0,65536)B (overlays dead A0)
  {
    float s0v[8], s0b[8];
#pragma unroll
    for (int j = 0; j < 8; ++j) {
      s0v[j] = ln0sc[wn + j * 16 + lm];
      s0b[j] = ln0bi[wn + j * 16 + lm];
    }
#pragma unroll
    for (int i2 = 0; i2 < 4; ++i2) {
#pragma unroll
      for (int r2 = 0; r2 < 4; ++r2) {
        int row = i2 * 16 + quad * 4 + r2;
        float ts  = redS[row * 4 + 0] + redS[row * 4 + 1] + redS[row * 4 + 2] + redS[row * 4 + 3];
        float tss = redSS[row * 4 + 0] + redSS[row * 4 + 1] + redSS[row * 4 + 2] + redSS[row * 4 + 3];
        float m = ts * (1.f / 512.f);
        float var = tss * (1.f / 512.f) - m * m;
        float inv = rsqrtf(var + 1e-5f);
#pragma unroll
        for (int j = 0; j < 8; ++j) {
          int col = wn + j * 16 + lm;
          float y = (acc[i2][j][r2] - m) * inv * s0v[j] + s0b[j];
          smem[row * 512 + (((col >> 3) ^ (row & 7)) * 8) + (col & 7)] = f2b(y);
        }
      }
    }
  }
  // gemm1 B preload before the barrier (hide L2 latency under the drain)
  u32 bOff1[8];
#pragma unroll
  for (int j = 0; j < 8; ++j)
    bOff1[j] = (u32)(wn + j * 16 + lm) * 512u + (u32)(quad * 8);
#pragma unroll
  for (int p = 0; p < 2; ++p)
#pragma unroll
    for (int j = 0; j < 8; ++j)
      bR[p][j] = *(const bf16x8*)(W1t + bOff1[j] + p * 32);
  __syncthreads();   // B3: e0 visible; red reusable

  // ---- gemm1: acc = e0 @ W1t^T   (K=512, N=512); B ring-2
#pragma unroll
  for (int i2 = 0; i2 < 4; ++i2)
#pragma unroll
    for (int j = 0; j < 8; ++j)
      acc[i2][j] = (f32x4){0.f, 0.f, 0.f, 0.f};
#pragma unroll
  for (int g = 0; g < 16; ++g) {
    bf16x8 cur[8];
#pragma unroll
    for (int j = 0; j < 8; ++j) cur[j] = bR[g & 1][j];
    if (g + 2 < 16) {
#pragma unroll
      for (int j = 0; j < 8; ++j)
        bR[g & 1][j] = *(const bf16x8*)(W1t + bOff1[j] + (g + 2) * 32);
    }
    const int kc = g * 4;
    bf16x8 af[4];
#pragma unroll
    for (int i2 = 0; i2 < 4; ++i2)
      af[i2] = *(const bf16x8*)&smem[(i2 * 16 + lm) * 512 + (((quad + kc) ^ l7) * 8)];
#pragma unroll
    for (int i2 = 0; i2 < 4; ++i2)
#pragma unroll
      for (int j = 0; j < 8; ++j)
        acc[i2][j] = MFMA(af[i2], cur[j], acc[i2][j], 0, 0, 0);
  }

  // ---- ReLU + LN1 partials
  {
    float b1v[8];
#pragma unroll
    for (int j = 0; j < 8; ++j) b1v[j] = b1[wn + j * 16 + lm];
#pragma unroll
    for (int i2 = 0; i2 < 4; ++i2) {
#pragma unroll
      for (int r2 = 0; r2 < 4; ++r2) {
        float s = 0.f, ss = 0.f;
#pragma unroll
        for (int j = 0; j < 8; ++j) {
          float v = fmaxf(acc[i2][j][r2] + b1v[j], 0.f);
          acc[i2][j][r2] = v;
          s += v; ss += v * v;
        }
#pragma unroll
        for (int o = 1; o < 16; o <<= 1) { s += __shfl_xor(s, o, 64); ss += __shfl_xor(ss, o, 64); }
        if (lm == 0) {
          int row = i2 * 16 + quad * 4 + r2;
          redS[row * 4 + wave] = s;
          redSS[row * 4 + wave] = ss;
        }
      }
    }
  }
  __syncthreads();   // B4: red1 done; all e0 reads done

  // ---- LN1 finalize -> LDS out-tile (linear [64][512], overlays dead e0)
  {
    float s1v[8], s1b[8];
#pragma unroll
    for (int j = 0; j < 8; ++j) {
      s1v[j] = ln1sc[wn + j * 16 + lm];
      s1b[j] = ln1bi[wn + j * 16 + lm];
    }
#pragma unroll
    for (int i2 = 0; i2 < 4; ++i2) {
#pragma unroll
      for (int r2 = 0; r2 < 4; ++r2) {
        int row = i2 * 16 + quad * 4 + r2;
        float ts  = redS[row * 4 + 0] + redS[row * 4 + 1] + redS[row * 4 + 2] + redS[row * 4 + 3];
        float tss = redSS[row * 4 + 0] + redSS[row * 4 + 1] + redSS[row * 4 + 2] + redSS[row * 4 + 3];
        float m = ts * (1.f / 512.f);
        float var = tss * (1.f / 512.f) - m * m;
        float inv = rsqrtf(var + 1e-5f);
#pragma unroll
        for (int j = 0; j < 8; ++j) {
          int col = wn + j * 16 + lm;
          float y = (acc[i2][j][r2] - m) * inv * s1v[j] + s1b[j];
          smem[row * 512 + col] = f2b(y);
        }
      }
    }
  }
  __syncthreads();   // B5: out-tile complete

  // ---- coalesced copy LDS -> bufB (64 KB; 4 KB per block-instruction)
  {
    u16* dst = C + (size_t)rowBase * 512;
#pragma unroll
    for (int it = 0; it < 16; ++it) {
      int idx = (it * 256 + tid) * 8;   // u16 units
      *(uint4*)(dst + idx) = *(const uint4*)&smem[idx];
    }
  }
}

// ---------------------------------------------------------------- route_head (round-2 verified, 67-68 us)
__global__ __launch_bounds__(256, 4) void route_head(
    const u16* __restrict__ obs_n, const u16* __restrict__ e,
    const u16* __restrict__ Wr0t, const float* __restrict__ br0,
    const u16* __restrict__ Wr1t, const float* __restrict__ br1,
    const u16* __restrict__ Wh0t, const float* __restrict__ bh0,
    const float* __restrict__ Wh1, const float* __restrict__ bh1,
    const float* __restrict__ Wh2, const float* __restrict__ bh2,
    const float* __restrict__ avail,
    const int* __restrict__ bucket, const int* __restrict__ baseArr,
    const int* __restrict__ cntArr, float* __restrict__ outLogits)
{
  __shared__ __align__(16) u16 sm[20480];   // 40960 B
  const int tid = threadIdx.x;

  int cA0, cA1, cA2, cA3, cA4, cA5, bA0, bA1, bA2, bA3, bA4, bA5;
  {
    int4 ca = *(const int4*)cntArr;  int2 cb = *(const int2*)(cntArr + 4);
    int4 ba = *(const int4*)baseArr; int2 bb = *(const int2*)(baseArr + 4);
    cA0 = ca.x; cA1 = ca.y; cA2 = ca.z; cA3 = ca.w; cA4 = cb.x; cA5 = cb.y;
    bA0 = ba.x; bA1 = ba.y; bA2 = ba.z; bA3 = ba.w; bA4 = bb.x; bA5 = bb.y;
  }
  int role = -1, rem = blockIdx.x, cnt = 0, roleBase = 0;
#define TRY_ROLE(k, ck, bk)                                        \
  if (role < 0) {                                                  \
    int tiles = ((ck) + 31) >> 5;                                  \
    if (rem < tiles) { role = (k); cnt = (ck); roleBase = (bk); }  \
    else rem -= tiles;                                             \
  }
  TRY_ROLE(0, cA0, bA0) TRY_ROLE(1, cA1, bA1) TRY_ROLE(2, cA2, bA2)
  TRY_ROLE(3, cA3, bA3) TRY_ROLE(4, cA4, bA4) TRY_ROLE(5, cA5, bA5)
#undef TRY_ROLE
  if (role < 0) return;
  const int limit = cnt;
  const int rowBase = rem * 32;

  const int lane = tid & 63, wave = tid >> 6;
  const int quad = lane >> 4, lm = lane & 15, l7 = lm & 7;

#pragma unroll
  for (int r = 0; r < 8; ++r) {
    int lrow = r * 4 + wave;
    int i = rowBase + lrow;
    if (i >= limit) i = rowBase;
    int grow = bucket[roleBase + i];
    int chunk = tid & 63;
    int sw = (chunk & 56) | ((chunk ^ lrow) & 7);
    gll16(e + (u32)grow * 512u + (u32)(sw * 8), &sm[r * 2048 + wave * 512]);
  }

  int growA0, growA1;
  {
    int i0 = rowBase + lm;        if (i0 >= limit) i0 = rowBase;
    int i1 = rowBase + 16 + lm;   if (i1 >= limit) i1 = rowBase;
    growA0 = bucket[roleBase + i0];
    growA1 = bucket[roleBase + i1];
  }
  const u16* Ag0 = obs_n + (size_t)growA0 * 256;
  const u16* Ag1 = obs_n + (size_t)growA1 * 256;

  // ---- stage0
  const int wn0 = wave * 32;
  const u16* B0 = Wr0t + (size_t)role * 128 * 256;
  f32x4 acc0[2][2] = {};
  bf16x8 b0R[2][2];
#pragma unroll
  for (int p = 0; p < 2; ++p)
#pragma unroll
    for (int j = 0; j < 2; ++j)
      b0R[p][j] = *(const bf16x8*)(B0 + (u32)(wn0 + j * 16 + lm) * 256u + (u32)(quad * 8 + p * 32));
  bf16x8 aR[4][2];
#pragma unroll
  for (int p = 0; p < 4; ++p) {
    aR[p][0] = *(const bf16x8*)(Ag0 + (u32)(quad * 8 + p * 32));
    aR[p][1] = *(const bf16x8*)(Ag1 + (u32)(quad * 8 + p * 32));
  }
  float bias0[2] = { br0[role * 128 + wn0 + lm], br0[role * 128 + wn0 + 16 + lm] };
#pragma unroll
  for (int it = 0; it < 8; ++it) {
    bf16x8 a0 = aR[it & 3][0], a1 = aR[it & 3][1];
    bf16x8 cur0 = b0R[it & 1][0], cur1 = b0R[it & 1][1];
    if (it + 2 < 8) {
#pragma unroll
      for (int j = 0; j < 2; ++j)
        b0R[it & 1][j] = *(const bf16x8*)(B0 + (u32)(wn0 + j * 16 + lm) * 256u + (u32)(quad * 8 + (it + 2) * 32));
    }
    if (it + 4 < 8) {
      aR[it & 3][0] = *(const bf16x8*)(Ag0 + (u32)(quad * 8 + (it + 4) * 32));
      aR[it & 3][1] = *(const bf16x8*)(Ag1 + (u32)(quad * 8 + (it + 4) * 32));
    }
    acc0[0][0] = MFMA(a0, cur0, acc0[0][0], 0, 0, 0);
    acc0[0][1] = MFMA(a0, cur1, acc0[0][1], 0, 0, 0);
    acc0[1][0] = MFMA(a1, cur0, acc0[1][0], 0, 0, 0);
    acc0[1][1] = MFMA(a1, cur1, acc0[1][1], 0, 0, 0);
  }
  u16* r1 = sm + 16384;
#pragma unroll
  for (int i2 = 0; i2 < 2; ++i2) {
#pragma unroll
    for (int r2 = 0; r2 < 4; ++r2) {
      int row = i2 * 16 + quad * 4 + r2;
#pragma unroll
      for (int j = 0; j < 2; ++j) {
        int col = wn0 + j * 16 + lm;
        float v = fmaxf(acc0[i2][j][r2] + bias0[j], 0.f);
        r1[row * 128 + (((col >> 3) ^ (row & 7)) * 8) + (col & 7)] = f2b(v);
      }
    }
  }
  __syncthreads();   // B1: r1 ready; drains e-staging vmcnt

  // ---- stage1: two 64-col halves
  const int wn1 = wave * 128;
  const u16* B1 = Wr1t + (size_t)role * 512 * 128;
#pragma unroll
  for (int h = 0; h < 2; ++h) {
    const int wnh = wn1 + h * 64;
    float b1v[4];
#pragma unroll
    for (int j = 0; j < 4; ++j) b1v[j] = br1[role * 512 + wnh + j * 16 + lm];
    f32x4 acc1[2][4] = {};
    bf16x8 b1P[4];
#pragma unroll
    for (int j = 0; j < 4; ++j)
      b1P[j] = *(const bf16x8*)(B1 + (u32)(wnh + j * 16 + lm) * 128u + (u32)(quad * 8));
#pragma unroll
    for (int kk = 0; kk < 128; kk += 32) {
      bf16x8 b1N[4];
      if (kk + 32 < 128) {
#pragma unroll
        for (int j = 0; j < 4; ++j)
          b1N[j] = *(const bf16x8*)(B1 + (u32)(wnh + j * 16 + lm) * 128u + (u32)(quad * 8 + kk + 32));
      }
      const int kc = kk >> 3;
      bf16x8 af[2];
#pragma unroll
      for (int i2 = 0; i2 < 2; ++i2)
        af[i2] = *(const bf16x8*)&r1[(i2 * 16 + lm) * 128 + (((quad + kc) ^ l7) * 8)];
#pragma unroll
      for (int i2 = 0; i2 < 2; ++i2)
#pragma unroll
        for (int j = 0; j < 4; ++j)
          acc1[i2][j] = MFMA(af[i2], b1P[j], acc1[i2][j], 0, 0, 0);
      if (kk + 32 < 128) {
#pragma unroll
        for (int j = 0; j < 4; ++j) b1P[j] = b1N[j];
      }
    }
#pragma unroll
    for (int i2 = 0; i2 < 2; ++i2) {
#pragma unroll
      for (int r2 = 0; r2 < 4; ++r2) {
        int row = i2 * 16 + quad * 4 + r2;
#pragma unroll
        for (int j = 0; j < 4; ++j) {
          int col = wnh + j * 16 + lm;
          int addr = row * 512 + (((col >> 3) ^ (row & 7)) * 8) + (col & 7);
          float v = fmaxf(acc1[i2][j][r2] + b1v[j], 0.f) + b2f(sm[addr]);
          sm[addr] = f2b(v);
        }
      }
    }
  }
  __syncthreads();

  // ---- stage2
  const int wn2 = wave * 16;
  const u16* B2 = Wh0t + (size_t)role * 64 * 512;
  float b2v = bh0[role * 64 + wn2 + lm];
  f32x4 acc2[2] = {};
  bf16x8 b2R[4];
#pragma unroll
  for (int p = 0; p < 4; ++p)
    b2R[p] = *(const bf16x8*)(B2 + (u32)(wn2 + lm) * 512u + (u32)(quad * 8 + p * 32));
#pragma unroll
  for (int it = 0; it < 16; ++it) {
    bf16x8 cur = b2R[it & 3];
    if (it + 4 < 16)
      b2R[it & 3] = *(const bf16x8*)(B2 + (u32)(wn2 + lm) * 512u + (u32)(quad * 8 + (it + 4) * 32));
    const int kc = it * 4;
    bf16x8 af[2];
#pragma unroll
    for (int i2 = 0; i2 < 2; ++i2)
      af[i2] = *(const bf16x8*)&sm[(i2 * 16 + lm) * 512 + (((quad + kc) ^ l7) * 8)];
#pragma unroll
    for (int i2 = 0; i2 < 2; ++i2)
      acc2[i2] = MFMA(af[i2], cur, acc2[i2], 0, 0, 0);
  }
  u16* h0s = sm + 16384;
#pragma unroll
  for (int i2 = 0; i2 < 2; ++i2) {
#pragma unroll
    for (int r2 = 0; r2 < 4; ++r2) {
      int row = i2 * 16 + quad * 4 + r2;
      int col = wn2 + lm;
      h0s[row * 68 + col] = f2b(fmaxf(acc2[i2][r2] + b2v, 0.f));
    }
  }
  __syncthreads();

  // ---- stage3
  {
    float* h1s = (float*)&sm[16384];
    const int r = tid >> 3;
    const int n0 = (tid & 7) * 4;
    const bool valid = (rowBase + r) < limit;
    const float* W1k = Wh1 + (size_t)role * 64 * 32;
    const float* W2k = Wh2 + (size_t)role * 32 * 32;
    float4 a1 = *(const float4*)(bh1 + role * 32 + n0);
#pragma unroll 8
    for (int j = 0; j < 64; ++j) {
      float hj = b2f(h0s[r * 68 + j]);
      float4 wv = *(const float4*)(W1k + j * 32 + n0);
      a1.x += hj * wv.x; a1.y += hj * wv.y; a1.z += hj * wv.z; a1.w += hj * wv.w;
    }
    a1.x = fmaxf(a1.x, 0.f); a1.y = fmaxf(a1.y, 0.f);
    a1.z = fmaxf(a1.z, 0.f); a1.w = fmaxf(a1.w, 0.f);
    __syncthreads();
    h1s[r * 36 + n0 + 0] = a1.x;
    h1s[r * 36 + n0 + 1] = a1.y;
    h1s[r * 36 + n0 + 2] = a1.z;
    h1s[r * 36 + n0 + 3] = a1.w;
    __syncthreads();
    float4 a2 = *(const float4*)(bh2 + role * 32 + n0);
#pragma unroll 8
    for (int n = 0; n < 32; ++n) {
      float hn = h1s[r * 36 + n];
      float4 wv = *(const float4*)(W2k + n * 32 + n0);
      a2.x += hn * wv.x; a2.y += hn * wv.y; a2.z += hn * wv.z; a2.w += hn * wv.w;
    }
    if (valid) {
      int g = bucket[roleBase + rowBase + r];
      float4 av = *(const float4*)(avail + (size_t)g * 32 + n0);
      float4 o;
      o.x = (av.x > 0.5f) ? a2.x : -1e10f;
      o.y = (av.y > 0.5f) ? a2.y : -1e10f;
      o.z = (av.z > 0.5f) ? a2.z : -1e10f;
      o.w = (av.w > 0.5f) ? a2.w : -1e10f;
      *(float4*)(outLogits + (size_t)g * 32 + n0) = o;
    }
  }
}

// ---------------------------------------------------------------- launcher
extern "C" void kernel_launch(void* const* d_in, const int* in_sizes, int n_in,
                              void* d_out, int out_size, void* d_ws, size_t ws_size,
                              hipStream_t stream)
{
  const float* rnn  = (const float*)d_in[0];
  const float* obs  = (const float*)d_in[1];
  const float* avail= (const float*)d_in[3];
  const int*   rid  = (const int*)d_in[4];
  const float* fn_s = (const float*)d_in[5];
  const float* fn_b = (const float*)d_in[6];
  const float* W0   = (const float*)d_in[7];
  const float* b0   = (const float*)d_in[8];
  const float* ln0s = (const float*)d_in[9];
  const float* ln0b = (const float*)d_in[10];
  const float* W1   = (const float*)d_in[11];
  const float* b1   = (const float*)d_in[12];
  const float* ln1s = (const float*)d_in[13];
  const float* ln1b = (const float*)d_in[14];
  const float* Wr0  = (const float*)d_in[15];
  const float* br0  = (const float*)d_in[16];
  const float* Wr1  = (const float*)d_in[17];
  const float* br1  = (const float*)d_in[18];
  const float* Wh0  = (const float*)d_in[19];
  const float* bh0  = (const float*)d_in[20];
  const float* Wh1  = (const float*)d_in[21];
  const float* bh1  = (const float*)d_in[22];
  const float* Wh2  = (const float*)d_in[23];
  const float* bh2  = (const float*)d_in[24];

  const int ROWS = 32768;

  char* w = (char*)d_ws;
  auto carve = [&](size_t bytes) { char* p = w; w += (bytes + 255) & ~(size_t)255; return p; };
  u16* obs_n  = (u16*)carve((size_t)ROWS * 256 * 2);
  u16* bufB   = (u16*)carve((size_t)ROWS * 512 * 2);   // e
  u16* W0t    = (u16*)carve((size_t)512 * 256 * 2);
  u16* W1t    = (u16*)carve((size_t)512 * 512 * 2);
  u16* Wr0t   = (u16*)carve((size_t)6 * 128 * 256 * 2);
  u16* Wr1t   = (u16*)carve((size_t)6 * 512 * 128 * 2);
  u16* Wh0t   = (u16*)carve((size_t)6 * 64 * 512 * 2);
  int* bucket = (int*)carve((size_t)ROWS * 4);
  int* blkCnt = (int*)carve((size_t)128 * NROLE * 4);
  int* baseArr= (int*)carve(256);
  int* cntArr = (int*)carve(256);

  float* outLogits = (float*)d_out + (size_t)1024 * 512;

  // mega0: weight transposes + role_count + rnn passthrough
  mega0<<<1408, 256, 0, stream>>>(W0, W1, Wr0, Wr1, Wh0, W0t, W1t, Wr0t, Wr1t, Wh0t,
                                  rid, blkCnt, rnn, (float*)d_out);

  // fused obs-LN + gemm0 + LN0 + gemm1 + LN1 (blocks 0..511) and fill2 (512..639)
  base2<<<640, 256, 0, stream>>>(obs, fn_s, fn_b, W0t, b0, ln0s, ln0b,
                                 W1t, b1, ln1s, ln1b, obs_n, bufB,
                                 rid, blkCnt, bucket, baseArr, cntArr);

  // fused role route + full head (round-2 verified)
  route_head<<<1029, 256, 0, stream>>>(obs_n, bufB, Wr0t, br0, Wr1t, br1, Wh0t, bh0,
                                       Wh1, bh1, Wh2, bh2, avail,
                                       bucket, baseArr, cntArr, outLogits);
}

// Round 11
// 266.149 us; speedup vs baseline: 1.1370x; 1.0030x over previous
//
#include <hip/hip_runtime.h>
#include <stdint.h>

typedef unsigned short u16;
typedef unsigned int u32;

using bf16x8 = __attribute__((ext_vector_type(8))) short;
using f32x4  = __attribute__((ext_vector_type(4))) float;

#define DEVINL __device__ __forceinline__

DEVINL float b2f(u16 u) { return __builtin_bit_cast(float, (u32)u << 16); }
DEVINL u16 f2b(float f) {
  u32 u = __builtin_bit_cast(u32, f);
  u += 0x7FFFu + ((u >> 16) & 1u);   // round-to-nearest-even
  return (u16)(u >> 16);
}

DEVINL void gll16(const u16* src, u16* dst) {
  __builtin_amdgcn_global_load_lds(
      (const __attribute__((address_space(1))) void*)(uintptr_t)src,
      (__attribute__((address_space(3))) void*)(uintptr_t)dst, 16, 0, 0);
}

#define MFMA __builtin_amdgcn_mfma_f32_16x16x32_bf16
#define NROLE 6

// ---------------------------------------------------------------- tp_tile:
// 32x32 f32->bf16 transpose through caller-provided LDS scratch (>=1056 u16).
DEVINL void tp_tile(u16* __restrict__ tile, const float* __restrict__ s,
                    u16* __restrict__ d, int R, int C, int bx, int by, int z)
{
  const size_t mstride = (size_t)R * C;
  s += (size_t)z * mstride;
  d += (size_t)z * mstride;
  int r0 = bx * 32, c0 = by * 32;
  int tx = threadIdx.x & 31, ty = threadIdx.x >> 5;
#pragma unroll
  for (int i = 0; i < 32; i += 8)
    tile[(ty + i) * 33 + tx] = f2b(s[(size_t)(r0 + ty + i) * C + (c0 + tx)]);
  __syncthreads();
#pragma unroll
  for (int i = 0; i < 32; i += 8)
    d[(size_t)(c0 + ty + i) * R + (r0 + tx)] = tile[tx * 33 + (ty + i)];
}

// ---------------------------------------------------------------- mega0 (640 blocks):
// W0/W1 transposes (0..383) | role_count (384..511) | rnn copy (512..639).
// Route-only transposes (Wr0/Wr1/Wh0) moved into base2's grid (they feed
// only route_head, which launches after base2).
__global__ __launch_bounds__(256) void mega0(
    const float* W0, const float* W1, u16* W0t, u16* W1t,
    const int* __restrict__ rid, int* __restrict__ blkCnt,
    const float* __restrict__ rnn, float* __restrict__ outRnn)
{
  int b = blockIdx.x;
  const int tid = threadIdx.x;
  __shared__ u16 tile[32 * 33];
  if (b < 384) {
    if (b < 128) { tp_tile(tile, W0, W0t, 256, 512, b % 8,  b / 8, 0); }
    else         { b -= 128; tp_tile(tile, W1, W1t, 512, 512, b % 16, b / 16, 0); }
  } else if (b < 512) {
    b -= 384;
    __shared__ int h[NROLE];
    if (tid < NROLE) h[tid] = 0;
    __syncthreads();
    atomicAdd(&h[rid[b * 256 + tid]], 1);
    __syncthreads();
    if (tid < NROLE) blkCnt[b * NROLE + tid] = h[tid];
  } else {
    b -= 512;
    const float4* src = (const float4*)rnn;
    float4* dst = (float4*)outRnn;
    int base = (b * 256 + tid) * 4;
#pragma unroll
    for (int i = 0; i < 4; ++i) dst[base + i] = src[base + i];
  }
}

// ---------------------------------------------------------------- base2 (1408 blocks):
// 0..511: fused obs-LN + gemm0 + LN0 + gemm1 + LN1 (round-10 verified, 87 us)
// 512..639: fill2 (scan + bucket fill), verbatim
// 640..1407: route-weight transposes (Wr0t/Wr1t/Wh0t), verbatim tp_tile,
//            hidden in base2's idle CU slots; outputs consumed by route_head.
// LDS 67584 B -> 2 blocks/CU.
__global__ __launch_bounds__(256, 2) void base2(
    const float* __restrict__ obs, const float* __restrict__ fn_s,
    const float* __restrict__ fn_b, const u16* __restrict__ W0t,
    const float* __restrict__ b0, const float* __restrict__ ln0sc,
    const float* __restrict__ ln0bi, const u16* __restrict__ W1t,
    const float* __restrict__ b1, const float* __restrict__ ln1sc,
    const float* __restrict__ ln1bi, u16* __restrict__ obs_n,
    u16* __restrict__ C,
    const float* Wr0, u16* Wr0t, const float* Wr1, u16* Wr1t,
    const float* Wh0, u16* Wh0t,
    const int* __restrict__ rid, const int* __restrict__ blkCnt,
    int* __restrict__ bucket, int* __restrict__ baseArr, int* __restrict__ cntArr)
{
  __shared__ __align__(16) u16 smem[33792];   // 67584 B
  const int tid = threadIdx.x;

  if (blockIdx.x >= 640) {
    // ---- route-weight transpose branch (uses smem as tp scratch)
    int b = blockIdx.x - 640;
    if (b < 192)      {            int t = b / 8;  tp_tile(smem, Wr0, Wr0t, 256, 128, b % 8,  t % 4,  t / 4); }
    else if (b < 576) { b -= 192;  int t = b / 4;  tp_tile(smem, Wr1, Wr1t, 128, 512, b % 4,  t % 16, t / 16); }
    else              { b -= 576;  int t = b / 16; tp_tile(smem, Wh0, Wh0t, 512, 64,  b % 16, t % 2,  t / 2); }
    return;
  }

  if (blockIdx.x >= 512) {
    // ---- fill2 branch (verbatim)
    const int bx = blockIdx.x - 512;
    int* c = (int*)smem;
    int* preArr = c + 768;
    int* scnt   = c + 776;
    int* sbase  = c + 784;
    int* h      = c + 792;
    for (int i = tid; i < 128 * NROLE; i += 256) c[i] = blkCnt[i];
    if (tid < NROLE) h[tid] = 0;
    __syncthreads();
    if (tid < NROLE) {
      int k = tid, run = 0, pre = 0;
      for (int b = 0; b < 128; ++b) { if (b == bx) pre = run; run += c[b * NROLE + k]; }
      scnt[k] = run; preArr[k] = pre;
    }
    __syncthreads();
    if (tid == 0) {
      int r = 0;
      for (int k = 0; k < NROLE; ++k) { sbase[k] = r; r += scnt[k]; }
    }
    __syncthreads();
    if (bx == 0 && tid < NROLE) { baseArr[tid] = sbase[tid]; cntArr[tid] = scnt[tid]; }
    int i = bx * 256 + tid;
    int k = rid[i];
    int pos = atomicAdd(&h[k], 1);
    bucket[sbase[k] + preArr[k] + pos] = i;
    return;
  }

  float* redS  = (float*)&smem[32768];   // [64][4]
  float* redSS = redS + 256;             // [64][4]
  const int rowBase = blockIdx.x * 64;
  const int lane = tid & 63, wave = tid >> 6;
  const int quad = lane >> 4, lm = lane & 15, l7 = lm & 7;
  const int wn = wave * 128;

  // ---- obs-LN staging: A0 swizzled to LDS only (coalesced global write later)
  {
    const int r = tid >> 2, q = tid & 3;
    const float* xr = obs + (size_t)(rowBase + r) * 256 + q * 64;
    float x[64];
#pragma unroll
    for (int jj = 0; jj < 16; ++jj)
      *(float4*)&x[jj * 4] = *(const float4*)(xr + jj * 4);
    float s = 0.f, s2 = 0.f;
#pragma unroll
    for (int p = 0; p < 64; ++p) { s += x[p]; s2 += x[p] * x[p]; }
    s  += __shfl_xor(s, 1, 64);  s  += __shfl_xor(s, 2, 64);
    s2 += __shfl_xor(s2, 1, 64); s2 += __shfl_xor(s2, 2, 64);
    float m = s * (1.f / 256.f);
    float var = s2 * (1.f / 256.f) - m * m;
    float inv = rsqrtf(var + 1e-5f);
    const float* fs = fn_s + q * 64;
    const float* fb = fn_b + q * 64;
#pragma unroll
    for (int j = 0; j < 8; ++j) {
      float4 fs0 = *(const float4*)(fs + j * 8);
      float4 fs1 = *(const float4*)(fs + j * 8 + 4);
      float4 fb0 = *(const float4*)(fb + j * 8);
      float4 fb1 = *(const float4*)(fb + j * 8 + 4);
      u16 yy[8] __attribute__((aligned(16)));
      yy[0] = f2b((x[j*8+0] - m) * inv * fs0.x + fb0.x);
      yy[1] = f2b((x[j*8+1] - m) * inv * fs0.y + fb0.y);
      yy[2] = f2b((x[j*8+2] - m) * inv * fs0.z + fb0.z);
      yy[3] = f2b((x[j*8+3] - m) * inv * fs0.w + fb0.w);
      yy[4] = f2b((x[j*8+4] - m) * inv * fs1.x + fb1.x);
      yy[5] = f2b((x[j*8+5] - m) * inv * fs1.y + fb1.y);
      yy[6] = f2b((x[j*8+6] - m) * inv * fs1.z + fb1.z);
      yy[7] = f2b((x[j*8+7] - m) * inv * fs1.w + fb1.w);
      int cch = q * 8 + j;
      *(uint4*)&smem[r * 256 + ((cch ^ (r & 7)) * 8)] = *(uint4*)yy;
    }
  }

  // ---- gemm0: acc = A0 @ W0t^T   (K=256, N=512; wave = 128 cols); B ring-2
  u32 bOff0[8];
#pragma unroll
  for (int j = 0; j < 8; ++j)
    bOff0[j] = (u32)(wn + j * 16 + lm) * 256u + (u32)(quad * 8);
  f32x4 acc[4][8] = {};
  bf16x8 bR[2][8];
#pragma unroll
  for (int p = 0; p < 2; ++p)
#pragma unroll
    for (int j = 0; j < 8; ++j)
      bR[p][j] = *(const bf16x8*)(W0t + bOff0[j] + p * 32);
  __syncthreads();   // B1: A0 staged

#pragma unroll
  for (int g = 0; g < 8; ++g) {
    bf16x8 cur[8];
#pragma unroll
    for (int j = 0; j < 8; ++j) cur[j] = bR[g & 1][j];
    if (g + 2 < 8) {
#pragma unroll
      for (int j = 0; j < 8; ++j)
        bR[g & 1][j] = *(const bf16x8*)(W0t + bOff0[j] + (g + 2) * 32);
    }
    const int kc = g * 4;
    bf16x8 af[4];
#pragma unroll
    for (int i2 = 0; i2 < 4; ++i2)
      af[i2] = *(const bf16x8*)&smem[(i2 * 16 + lm) * 256 + (((quad + kc) ^ l7) * 8)];
#pragma unroll
    for (int i2 = 0; i2 < 4; ++i2)
#pragma unroll
      for (int j = 0; j < 8; ++j)
        acc[i2][j] = MFMA(af[i2], cur[j], acc[i2][j], 0, 0, 0);
  }

  // ---- coalesced obs_n write: unswizzle A0 LDS -> global (round-10 verified)
  {
    u16* dst = obs_n + (size_t)rowBase * 256;
#pragma unroll
    for (int it = 0; it < 8; ++it) {
      int li = it * 256 + tid;          // linear uint4 index, 0..2047
      int r = li >> 5, c = li & 31;     // row 0..63, chunk 0..31
      *(uint4*)(dst + li * 8) =
          *(const uint4*)&smem[r * 256 + ((c ^ (r & 7)) * 8)];
    }
  }

  // ---- ReLU + LN0 partials (biases in registers)
  {
    float b0v[8];
#pragma unroll
    for (int j = 0; j < 8; ++j) b0v[j] = b0[wn + j * 16 + lm];
#pragma unroll
    for (int i2 = 0; i2 < 4; ++i2) {
#pragma unroll
      for (int r2 = 0; r2 < 4; ++r2) {
        float s = 0.f, ss = 0.f;
#pragma unroll
        for (int j = 0; j < 8; ++j) {
          float v = fmaxf(acc[i2][j][r2] + b0v[j], 0.f);
          acc[i2][j][r2] = v;
          s += v; ss += v * v;
        }
#pragma unroll
        for (int o = 1; o < 16; o <<= 1) { s += __shfl_xor(s, o, 64); ss += __shfl_xor(ss, o, 64); }
        if (lm == 0) {
          int row = i2 * 16 + quad * 4 + r2;
          redS[row * 4 + wave] = s;
          redSS[row * 4 + wave] = ss;
        }
      }
    }
  }
  __syncthreads();   // B2: red0 done, A0 reads done, obs_n copies done

  // ---- LN0 finalize -> e0 bf16 into [0,65536)B (overlays dead A0)
  {
    float s0v[8], s0b[8];
#pragma unroll
    for (int j = 0; j < 8; ++j) {
      s0v[j] = ln0sc[wn + j * 16 + lm];
      s0b[j] = ln0bi[wn + j * 16 + lm];
    }
#pragma unroll
    for (int i2 = 0; i2 < 4; ++i2) {
#pragma unroll
      for (int r2 = 0; r2 < 4; ++r2) {
        int row = i2 * 16 + quad * 4 + r2;
        float ts  = redS[row * 4 + 0] + redS[row * 4 + 1] + redS[row * 4 + 2] + redS[row * 4 + 3];
        float tss = redSS[row * 4 + 0] + redSS[row * 4 + 1] + redSS[row * 4 + 2] + redSS[row * 4 + 3];
        float m = ts * (1.f / 512.f);
        float var = tss * (1.f / 512.f) - m * m;
        float inv = rsqrtf(var + 1e-5f);
#pragma unroll
        for (int j = 0; j < 8; ++j) {
          int col = wn + j * 16 + lm;
          float y = (acc[i2][j][r2] - m) * inv * s0v[j] + s0b[j];
          smem[row * 512 + (((col >> 3) ^ (row & 7)) * 8) + (col & 7)] = f2b(y);
        }
      }
    }
  }
  // gemm1 B preload before the barrier (hide L2 latency under the drain)
  u32 bOff1[8];
#pragma unroll
  for (int j = 0; j < 8; ++j)
    bOff1[j] = (u32)(wn + j * 16 + lm) * 512u + (u32)(quad * 8);
#pragma unroll
  for (int p = 0; p < 2; ++p)
#pragma unroll
    for (int j = 0; j < 8; ++j)
      bR[p][j] = *(const bf16x8*)(W1t + bOff1[j] + p * 32);
  __syncthreads();   // B3: e0 visible; red reusable

  // ---- gemm1: acc = e0 @ W1t^T   (K=512, N=512); B ring-2
#pragma unroll
  for (int i2 = 0; i2 < 4; ++i2)
#pragma unroll
    for (int j = 0; j < 8; ++j)
      acc[i2][j] = (f32x4){0.f, 0.f, 0.f, 0.f};
#pragma unroll
  for (int g = 0; g < 16; ++g) {
    bf16x8 cur[8];
#pragma unroll
    for (int j = 0; j < 8; ++j) cur[j] = bR[g & 1][j];
    if (g + 2 < 16) {
#pragma unroll
      for (int j = 0; j < 8; ++j)
        bR[g & 1][j] = *(const bf16x8*)(W1t + bOff1[j] + (g + 2) * 32);
    }
    const int kc = g * 4;
    bf16x8 af[4];
#pragma unroll
    for (int i2 = 0; i2 < 4; ++i2)
      af[i2] = *(const bf16x8*)&smem[(i2 * 16 + lm) * 512 + (((quad + kc) ^ l7) * 8)];
#pragma unroll
    for (int i2 = 0; i2 < 4; ++i2)
#pragma unroll
      for (int j = 0; j < 8; ++j)
        acc[i2][j] = MFMA(af[i2], cur[j], acc[i2][j], 0, 0, 0);
  }

  // ---- ReLU + LN1 partials
  {
    float b1v[8];
#pragma unroll
    for (int j = 0; j < 8; ++j) b1v[j] = b1[wn + j * 16 + lm];
#pragma unroll
    for (int i2 = 0; i2 < 4; ++i2) {
#pragma unroll
      for (int r2 = 0; r2 < 4; ++r2) {
        float s = 0.f, ss = 0.f;
#pragma unroll
        for (int j = 0; j < 8; ++j) {
          float v = fmaxf(acc[i2][j][r2] + b1v[j], 0.f);
          acc[i2][j][r2] = v;
          s += v; ss += v * v;
        }
#pragma unroll
        for (int o = 1; o < 16; o <<= 1) { s += __shfl_xor(s, o, 64); ss += __shfl_xor(ss, o, 64); }
        if (lm == 0) {
          int row = i2 * 16 + quad * 4 + r2;
          redS[row * 4 + wave] = s;
          redSS[row * 4 + wave] = ss;
        }
      }
    }
  }
  __syncthreads();   // B4: red1 done; all e0 reads done

  // ---- LN1 finalize -> LDS out-tile (linear [64][512], overlays dead e0)
  {
    float s1v[8], s1b[8];
#pragma unroll
    for (int j = 0; j < 8; ++j) {
      s1v[j] = ln1sc[wn + j * 16 + lm];
      s1b[j] = ln1bi[wn + j * 16 + lm];
    }
#pragma unroll
    for (int i2 = 0; i2 < 4; ++i2) {
#pragma unroll
      for (int r2 = 0; r2 < 4; ++r2) {
        int row = i2 * 16 + quad * 4 + r2;
        float ts  = redS[row * 4 + 0] + redS[row * 4 + 1] + redS[row * 4 + 2] + redS[row * 4 + 3];
        float tss = redSS[row * 4 + 0] + redSS[row * 4 + 1] + redSS[row * 4 + 2] + redSS[row * 4 + 3];
        float m = ts * (1.f / 512.f);
        float var = tss * (1.f / 512.f) - m * m;
        float inv = rsqrtf(var + 1e-5f);
#pragma unroll
        for (int j = 0; j < 8; ++j) {
          int col = wn + j * 16 + lm;
          float y = (acc[i2][j][r2] - m) * inv * s1v[j] + s1b[j];
          smem[row * 512 + col] = f2b(y);
        }
      }
    }
  }
  __syncthreads();   // B5: out-tile complete

  // ---- coalesced copy LDS -> bufB (64 KB; 4 KB per block-instruction)
  {
    u16* dst = C + (size_t)rowBase * 512;
#pragma unroll
    for (int it = 0; it < 16; ++it) {
      int idx = (it * 256 + tid) * 8;   // u16 units
      *(uint4*)(dst + idx) = *(const uint4*)&smem[idx];
    }
  }
}

// ---------------------------------------------------------------- route_head (round-2 verified, 67-68 us)
__global__ __launch_bounds__(256, 4) void route_head(
    const u16* __restrict__ obs_n, const u16* __restrict__ e,
    const u16* __restrict__ Wr0t, const float* __restrict__ br0,
    const u16* __restrict__ Wr1t, const float* __restrict__ br1,
    const u16* __restrict__ Wh0t, const float* __restrict__ bh0,
    const float* __restrict__ Wh1, const float* __restrict__ bh1,
    const float* __restrict__ Wh2, const float* __restrict__ bh2,
    const float* __restrict__ avail,
    const int* __restrict__ bucket, const int* __restrict__ baseArr,
    const int* __restrict__ cntArr, float* __restrict__ outLogits)
{
  __shared__ __align__(16) u16 sm[20480];   // 40960 B
  const int tid = threadIdx.x;

  int cA0, cA1, cA2, cA3, cA4, cA5, bA0, bA1, bA2, bA3, bA4, bA5;
  {
    int4 ca = *(const int4*)cntArr;  int2 cb = *(const int2*)(cntArr + 4);
    int4 ba = *(const int4*)baseArr; int2 bb = *(const int2*)(baseArr + 4);
    cA0 = ca.x; cA1 = ca.y; cA2 = ca.z; cA3 = ca.w; cA4 = cb.x; cA5 = cb.y;
    bA0 = ba.x; bA1 = ba.y; bA2 = ba.z; bA3 = ba.w; bA4 = bb.x; bA5 = bb.y;
  }
  int role = -1, rem = blockIdx.x, cnt = 0, roleBase = 0;
#define TRY_ROLE(k, ck, bk)                                        \
  if (role < 0) {                                                  \
    int tiles = ((ck) + 31) >> 5;                                  \
    if (rem < tiles) { role = (k); cnt = (ck); roleBase = (bk); }  \
    else rem -= tiles;                                             \
  }
  TRY_ROLE(0, cA0, bA0) TRY_ROLE(1, cA1, bA1) TRY_ROLE(2, cA2, bA2)
  TRY_ROLE(3, cA3, bA3) TRY_ROLE(4, cA4, bA4) TRY_ROLE(5, cA5, bA5)
#undef TRY_ROLE
  if (role < 0) return;
  const int limit = cnt;
  const int rowBase = rem * 32;

  const int lane = tid & 63, wave = tid >> 6;
  const int quad = lane >> 4, lm = lane & 15, l7 = lm & 7;

#pragma unroll
  for (int r = 0; r < 8; ++r) {
    int lrow = r * 4 + wave;
    int i = rowBase + lrow;
    if (i >= limit) i = rowBase;
    int grow = bucket[roleBase + i];
    int chunk = tid & 63;
    int sw = (chunk & 56) | ((chunk ^ lrow) & 7);
    gll16(e + (u32)grow * 512u + (u32)(sw * 8), &sm[r * 2048 + wave * 512]);
  }

  int growA0, growA1;
  {
    int i0 = rowBase + lm;        if (i0 >= limit) i0 = rowBase;
    int i1 = rowBase + 16 + lm;   if (i1 >= limit) i1 = rowBase;
    growA0 = bucket[roleBase + i0];
    growA1 = bucket[roleBase + i1];
  }
  const u16* Ag0 = obs_n + (size_t)growA0 * 256;
  const u16* Ag1 = obs_n + (size_t)growA1 * 256;

  // ---- stage0
  const int wn0 = wave * 32;
  const u16* B0 = Wr0t + (size_t)role * 128 * 256;
  f32x4 acc0[2][2] = {};
  bf16x8 b0R[2][2];
#pragma unroll
  for (int p = 0; p < 2; ++p)
#pragma unroll
    for (int j = 0; j < 2; ++j)
      b0R[p][j] = *(const bf16x8*)(B0 + (u32)(wn0 + j * 16 + lm) * 256u + (u32)(quad * 8 + p * 32));
  bf16x8 aR[4][2];
#pragma unroll
  for (int p = 0; p < 4; ++p) {
    aR[p][0] = *(const bf16x8*)(Ag0 + (u32)(quad * 8 + p * 32));
    aR[p][1] = *(const bf16x8*)(Ag1 + (u32)(quad * 8 + p * 32));
  }
  float bias0[2] = { br0[role * 128 + wn0 + lm], br0[role * 128 + wn0 + 16 + lm] };
#pragma unroll
  for (int it = 0; it < 8; ++it) {
    bf16x8 a0 = aR[it & 3][0], a1 = aR[it & 3][1];
    bf16x8 cur0 = b0R[it & 1][0], cur1 = b0R[it & 1][1];
    if (it + 2 < 8) {
#pragma unroll
      for (int j = 0; j < 2; ++j)
        b0R[it & 1][j] = *(const bf16x8*)(B0 + (u32)(wn0 + j * 16 + lm) * 256u + (u32)(quad * 8 + (it + 2) * 32));
    }
    if (it + 4 < 8) {
      aR[it & 3][0] = *(const bf16x8*)(Ag0 + (u32)(quad * 8 + (it + 4) * 32));
      aR[it & 3][1] = *(const bf16x8*)(Ag1 + (u32)(quad * 8 + (it + 4) * 32));
    }
    acc0[0][0] = MFMA(a0, cur0, acc0[0][0], 0, 0, 0);
    acc0[0][1] = MFMA(a0, cur1, acc0[0][1], 0, 0, 0);
    acc0[1][0] = MFMA(a1, cur0, acc0[1][0], 0, 0, 0);
    acc0[1][1] = MFMA(a1, cur1, acc0[1][1], 0, 0, 0);
  }
  u16* r1 = sm + 16384;
#pragma unroll
  for (int i2 = 0; i2 < 2; ++i2) {
#pragma unroll
    for (int r2 = 0; r2 < 4; ++r2) {
      int row = i2 * 16 + quad * 4 + r2;
#pragma unroll
      for (int j = 0; j < 2; ++j) {
        int col = wn0 + j * 16 + lm;
        float v = fmaxf(acc0[i2][j][r2] + bias0[j], 0.f);
        r1[row * 128 + (((col >> 3) ^ (row & 7)) * 8) + (col & 7)] = f2b(v);
      }
    }
  }
  __syncthreads();   // B1: r1 ready; drains e-staging vmcnt

  // ---- stage1: two 64-col halves
  const int wn1 = wave * 128;
  const u16* B1 = Wr1t + (size_t)role * 512 * 128;
#pragma unroll
  for (int h = 0; h < 2; ++h) {
    const int wnh = wn1 + h * 64;
    float b1v[4];
#pragma unroll
    for (int j = 0; j < 4; ++j) b1v[j] = br1[role * 512 + wnh + j * 16 + lm];
    f32x4 acc1[2][4] = {};
    bf16x8 b1P[4];
#pragma unroll
    for (int j = 0; j < 4; ++j)
      b1P[j] = *(const bf16x8*)(B1 + (u32)(wnh + j * 16 + lm) * 128u + (u32)(quad * 8));
#pragma unroll
    for (int kk = 0; kk < 128; kk += 32) {
      bf16x8 b1N[4];
      if (kk + 32 < 128) {
#pragma unroll
        for (int j = 0; j < 4; ++j)
          b1N[j] = *(const bf16x8*)(B1 + (u32)(wnh + j * 16 + lm) * 128u + (u32)(quad * 8 + kk + 32));
      }
      const int kc = kk >> 3;
      bf16x8 af[2];
#pragma unroll
      for (int i2 = 0; i2 < 2; ++i2)
        af[i2] = *(const bf16x8*)&r1[(i2 * 16 + lm) * 128 + (((quad + kc) ^ l7) * 8)];
#pragma unroll
      for (int i2 = 0; i2 < 2; ++i2)
#pragma unroll
        for (int j = 0; j < 4; ++j)
          acc1[i2][j] = MFMA(af[i2], b1P[j], acc1[i2][j], 0, 0, 0);
      if (kk + 32 < 128) {
#pragma unroll
        for (int j = 0; j < 4; ++j) b1P[j] = b1N[j];
      }
    }
#pragma unroll
    for (int i2 = 0; i2 < 2; ++i2) {
#pragma unroll
      for (int r2 = 0; r2 < 4; ++r2) {
        int row = i2 * 16 + quad * 4 + r2;
#pragma unroll
        for (int j = 0; j < 4; ++j) {
          int col = wnh + j * 16 + lm;
          int addr = row * 512 + (((col >> 3) ^ (row & 7)) * 8) + (col & 7);
          float v = fmaxf(acc1[i2][j][r2] + b1v[j], 0.f) + b2f(sm[addr]);
          sm[addr] = f2b(v);
        }
      }
    }
  }
  __syncthreads();

  // ---- stage2
  const int wn2 = wave * 16;
  const u16* B2 = Wh0t + (size_t)role * 64 * 512;
  float b2v = bh0[role * 64 + wn2 + lm];
  f32x4 acc2[2] = {};
  bf16x8 b2R[4];
#pragma unroll
  for (int p = 0; p < 4; ++p)
    b2R[p] = *(const bf16x8*)(B2 + (u32)(wn2 + lm) * 512u + (u32)(quad * 8 + p * 32));
#pragma unroll
  for (int it = 0; it < 16; ++it) {
    bf16x8 cur = b2R[it & 3];
    if (it + 4 < 16)
      b2R[it & 3] = *(const bf16x8*)(B2 + (u32)(wn2 + lm) * 512u + (u32)(quad * 8 + (it + 4) * 32));
    const int kc = it * 4;
    bf16x8 af[2];
#pragma unroll
    for (int i2 = 0; i2 < 2; ++i2)
      af[i2] = *(const bf16x8*)&sm[(i2 * 16 + lm) * 512 + (((quad + kc) ^ l7) * 8)];
#pragma unroll
    for (int i2 = 0; i2 < 2; ++i2)
      acc2[i2] = MFMA(af[i2], cur, acc2[i2], 0, 0, 0);
  }
  u16* h0s = sm + 16384;
#pragma unroll
  for (int i2 = 0; i2 < 2; ++i2) {
#pragma unroll
    for (int r2 = 0; r2 < 4; ++r2) {
      int row = i2 * 16 + quad * 4 + r2;
      int col = wn2 + lm;
      h0s[row * 68 + col] = f2b(fmaxf(acc2[i2][r2] + b2v, 0.f));
    }
  }
  __syncthreads();

  // ---- stage3
  {
    float* h1s = (float*)&sm[16384];
    const int r = tid >> 3;
    const int n0 = (tid & 7) * 4;
    const bool valid = (rowBase + r) < limit;
    const float* W1k = Wh1 + (size_t)role * 64 * 32;
    const float* W2k = Wh2 + (size_t)role * 32 * 32;
    float4 a1 = *(const float4*)(bh1 + role * 32 + n0);
#pragma unroll 8
    for (int j = 0; j < 64; ++j) {
      float hj = b2f(h0s[r * 68 + j]);
      float4 wv = *(const float4*)(W1k + j * 32 + n0);
      a1.x += hj * wv.x; a1.y += hj * wv.y; a1.z += hj * wv.z; a1.w += hj * wv.w;
    }
    a1.x = fmaxf(a1.x, 0.f); a1.y = fmaxf(a1.y, 0.f);
    a1.z = fmaxf(a1.z, 0.f); a1.w = fmaxf(a1.w, 0.f);
    __syncthreads();
    h1s[r * 36 + n0 + 0] = a1.x;
    h1s[r * 36 + n0 + 1] = a1.y;
    h1s[r * 36 + n0 + 2] = a1.z;
    h1s[r * 36 + n0 + 3] = a1.w;
    __syncthreads();
    float4 a2 = *(const float4*)(bh2 + role * 32 + n0);
#pragma unroll 8
    for (int n = 0; n < 32; ++n) {
      float hn = h1s[r * 36 + n];
      float4 wv = *(const float4*)(W2k + n * 32 + n0);
      a2.x += hn * wv.x; a2.y += hn * wv.y; a2.z += hn * wv.z; a2.w += hn * wv.w;
    }
    if (valid) {
      int g = bucket[roleBase + rowBase + r];
      float4 av = *(const float4*)(avail + (size_t)g * 32 + n0);
      float4 o;
      o.x = (av.x > 0.5f) ? a2.x : -1e10f;
      o.y = (av.y > 0.5f) ? a2.y : -1e10f;
      o.z = (av.z > 0.5f) ? a2.z : -1e10f;
      o.w = (av.w > 0.5f) ? a2.w : -1e10f;
      *(float4*)(outLogits + (size_t)g * 32 + n0) = o;
    }
  }
}

// ---------------------------------------------------------------- launcher
extern "C" void kernel_launch(void* const* d_in, const int* in_sizes, int n_in,
                              void* d_out, int out_size, void* d_ws, size_t ws_size,
                              hipStream_t stream)
{
  const float* rnn  = (const float*)d_in[0];
  const float* obs  = (const float*)d_in[1];
  const float* avail= (const float*)d_in[3];
  const int*   rid  = (const int*)d_in[4];
  const float* fn_s = (const float*)d_in[5];
  const float* fn_b = (const float*)d_in[6];
  const float* W0   = (const float*)d_in[7];
  const float* b0   = (const float*)d_in[8];
  const float* ln0s = (const float*)d_in[9];
  const float* ln0b = (const float*)d_in[10];
  const float* W1   = (const float*)d_in[11];
  const float* b1   = (const float*)d_in[12];
  const float* ln1s = (const float*)d_in[13];
  const float* ln1b = (const float*)d_in[14];
  const float* Wr0  = (const float*)d_in[15];
  const float* br0  = (const float*)d_in[16];
  const float* Wr1  = (const float*)d_in[17];
  const float* br1  = (const float*)d_in[18];
  const float* Wh0  = (const float*)d_in[19];
  const float* bh0  = (const float*)d_in[20];
  const float* Wh1  = (const float*)d_in[21];
  const float* bh1  = (const float*)d_in[22];
  const float* Wh2  = (const float*)d_in[23];
  const float* bh2  = (const float*)d_in[24];

  const int ROWS = 32768;

  char* w = (char*)d_ws;
  auto carve = [&](size_t bytes) { char* p = w; w += (bytes + 255) & ~(size_t)255; return p; };
  u16* obs_n  = (u16*)carve((size_t)ROWS * 256 * 2);
  u16* bufB   = (u16*)carve((size_t)ROWS * 512 * 2);   // e
  u16* W0t    = (u16*)carve((size_t)512 * 256 * 2);
  u16* W1t    = (u16*)carve((size_t)512 * 512 * 2);
  u16* Wr0t   = (u16*)carve((size_t)6 * 128 * 256 * 2);
  u16* Wr1t   = (u16*)carve((size_t)6 * 512 * 128 * 2);
  u16* Wh0t   = (u16*)carve((size_t)6 * 64 * 512 * 2);
  int* bucket = (int*)carve((size_t)ROWS * 4);
  int* blkCnt = (int*)carve((size_t)128 * NROLE * 4);
  int* baseArr= (int*)carve(256);
  int* cntArr = (int*)carve(256);

  float* outLogits = (float*)d_out + (size_t)1024 * 512;

  // mega0: base-MLP weight transposes + role_count + rnn passthrough (640 blocks)
  mega0<<<640, 256, 0, stream>>>(W0, W1, W0t, W1t, rid, blkCnt, rnn, (float*)d_out);

  // base2: fused base MLP (0..511) + fill2 (512..639) + route-weight
  // transposes (640..1407, hidden in idle CU slots)
  base2<<<1408, 256, 0, stream>>>(obs, fn_s, fn_b, W0t, b0, ln0s, ln0b,
                                  W1t, b1, ln1s, ln1b, obs_n, bufB,
                                  Wr0, Wr0t, Wr1, Wr1t, Wh0, Wh0t,
                                  rid, blkCnt, bucket, baseArr, cntArr);

  // fused role route + full head (round-2 verified)
  route_head<<<1029, 256, 0, stream>>>(obs_n, bufB, Wr0t, br0, Wr1t, br1, Wh0t, bh0,
                                       Wh1, bh1, Wh2, bh2, avail,
                                       bucket, baseArr, cntArr, outLogits);
}

// Round 12
// 266.001 us; speedup vs baseline: 1.1376x; 1.0006x over previous
//
#include <hip/hip_runtime.h>
#include <stdint.h>

typedef unsigned short u16;
typedef unsigned int u32;

using bf16x8 = __attribute__((ext_vector_type(8))) short;
using f32x4  = __attribute__((ext_vector_type(4))) float;

#define DEVINL __device__ __forceinline__

DEVINL float b2f(u16 u) { return __builtin_bit_cast(float, (u32)u << 16); }
DEVINL u16 f2b(float f) {
  u32 u = __builtin_bit_cast(u32, f);
  u += 0x7FFFu + ((u >> 16) & 1u);   // round-to-nearest-even
  return (u16)(u >> 16);
}

DEVINL void gll16(const u16* src, u16* dst) {
  __builtin_amdgcn_global_load_lds(
      (const __attribute__((address_space(1))) void*)(uintptr_t)src,
      (__attribute__((address_space(3))) void*)(uintptr_t)dst, 16, 0, 0);
}

#define MFMA __builtin_amdgcn_mfma_f32_16x16x32_bf16
#define NROLE 6

// ---------------------------------------------------------------- mega0:
// transposes (blocks 0..1151) | role_count (1152..1279) | rnn copy (1280..1407).
// NOTE: transposes stay here (round-11 lesson: fusing them into base2's
// 67.5KB-LDS kernel makes every tiny transpose block pay the max LDS
// footprint -> blocks gemm co-residency, base2 87->135 us).
DEVINL void tp_tile(const float* __restrict__ s, u16* __restrict__ d,
                    int R, int C, int bx, int by, int z)
{
  __shared__ u16 tile[32][33];
  const size_t mstride = (size_t)R * C;
  s += (size_t)z * mstride;
  d += (size_t)z * mstride;
  int r0 = bx * 32, c0 = by * 32;
  int tx = threadIdx.x & 31, ty = threadIdx.x >> 5;
#pragma unroll
  for (int i = 0; i < 32; i += 8)
    tile[ty + i][tx] = f2b(s[(size_t)(r0 + ty + i) * C + (c0 + tx)]);
  __syncthreads();
#pragma unroll
  for (int i = 0; i < 32; i += 8)
    d[(size_t)(c0 + ty + i) * R + (r0 + tx)] = tile[tx][ty + i];
}

__global__ __launch_bounds__(256) void mega0(
    const float* W0, const float* W1, const float* Wr0, const float* Wr1, const float* Wh0,
    u16* W0t, u16* W1t, u16* Wr0t, u16* Wr1t, u16* Wh0t,
    const int* __restrict__ rid, int* __restrict__ blkCnt,
    const float* __restrict__ rnn, float* __restrict__ outRnn)
{
  int b = blockIdx.x;
  const int tid = threadIdx.x;
  if (b < 1152) {
    if (b < 128)      {            tp_tile(W0, W0t, 256, 512, b % 8,  b / 8, 0); }
    else if (b < 384) { b -= 128;  tp_tile(W1, W1t, 512, 512, b % 16, b / 16, 0); }
    else if (b < 576) { b -= 384;  int t = b / 8;  tp_tile(Wr0, Wr0t, 256, 128, b % 8,  t % 4,  t / 4); }
    else if (b < 960) { b -= 576;  int t = b / 4;  tp_tile(Wr1, Wr1t, 128, 512, b % 4,  t % 16, t / 16); }
    else              { b -= 960;  int t = b / 16; tp_tile(Wh0, Wh0t, 512, 64,  b % 16, t % 2,  t / 2); }
  } else if (b < 1280) {
    b -= 1152;
    __shared__ int h[NROLE];
    if (tid < NROLE) h[tid] = 0;
    __syncthreads();
    atomicAdd(&h[rid[b * 256 + tid]], 1);
    __syncthreads();
    if (tid < NROLE) blkCnt[b * NROLE + tid] = h[tid];
  } else {
    b -= 1280;
    const float4* src = (const float4*)rnn;
    float4* dst = (float4*)outRnn;
    int base = (b * 256 + tid) * 4;
#pragma unroll
    for (int i = 0; i < 4; ++i) dst[base + i] = src[base + i];
  }
}

// ---------------------------------------------------------------- base2 (round-10 verified, 87.5 us)
// 64-row tile; obs_n written coalesced from LDS (unswizzling copy) after
// gemm0 -- the scattered 16B/lane staging stores cost ~47 us of issue
// serialization (round-10 measured 134.8 -> 87.5).
// blocks 0..511: fused obs-LN + gemm0 + LN0 + gemm1 + LN1 for 64 rows.
// blocks 512..639: fill2 (scan + bucket fill), verbatim.
// LDS 67584 B -> 2 blocks/CU:
//   A0  [0,32768)B   64x256 u16 swizzled (dead after B2)
//   e0  [0,65536)B   64x512 u16 swizzled (overlays A0); later out-tile linear
//   red [65536,67584)B  redS 256 f32 | redSS 256 f32
__global__ __launch_bounds__(256, 2) void base2(
    const float* __restrict__ obs, const float* __restrict__ fn_s,
    const float* __restrict__ fn_b, const u16* __restrict__ W0t,
    const float* __restrict__ b0, const float* __restrict__ ln0sc,
    const float* __restrict__ ln0bi, const u16* __restrict__ W1t,
    const float* __restrict__ b1, const float* __restrict__ ln1sc,
    const float* __restrict__ ln1bi, u16* __restrict__ obs_n,
    u16* __restrict__ C,
    const int* __restrict__ rid, const int* __restrict__ blkCnt,
    int* __restrict__ bucket, int* __restrict__ baseArr, int* __restrict__ cntArr)
{
  __shared__ __align__(16) u16 smem[33792];   // 67584 B
  const int tid = threadIdx.x;

  if (blockIdx.x >= 512) {
    // ---- fill2 branch (verbatim)
    const int bx = blockIdx.x - 512;
    int* c = (int*)smem;
    int* preArr = c + 768;
    int* scnt   = c + 776;
    int* sbase  = c + 784;
    int* h      = c + 792;
    for (int i = tid; i < 128 * NROLE; i += 256) c[i] = blkCnt[i];
    if (tid < NROLE) h[tid] = 0;
    __syncthreads();
    if (tid < NROLE) {
      int k = tid, run = 0, pre = 0;
      for (int b = 0; b < 128; ++b) { if (b == bx) pre = run; run += c[b * NROLE + k]; }
      scnt[k] = run; preArr[k] = pre;
    }
    __syncthreads();
    if (tid == 0) {
      int r = 0;
      for (int k = 0; k < NROLE; ++k) { sbase[k] = r; r += scnt[k]; }
    }
    __syncthreads();
    if (bx == 0 && tid < NROLE) { baseArr[tid] = sbase[tid]; cntArr[tid] = scnt[tid]; }
    int i = bx * 256 + tid;
    int k = rid[i];
    int pos = atomicAdd(&h[k], 1);
    bucket[sbase[k] + preArr[k] + pos] = i;
    return;
  }

  float* redS  = (float*)&smem[32768];   // [64][4]
  float* redSS = redS + 256;             // [64][4]
  const int rowBase = blockIdx.x * 64;
  const int lane = tid & 63, wave = tid >> 6;
  const int quad = lane >> 4, lm = lane & 15, l7 = lm & 7;
  const int wn = wave * 128;

  // ---- obs-LN staging: A0 swizzled to LDS only (coalesced global write later)
  {
    const int r = tid >> 2, q = tid & 3;
    const float* xr = obs + (size_t)(rowBase + r) * 256 + q * 64;
    float x[64];
#pragma unroll
    for (int jj = 0; jj < 16; ++jj)
      *(float4*)&x[jj * 4] = *(const float4*)(xr + jj * 4);
    float s = 0.f, s2 = 0.f;
#pragma unroll
    for (int p = 0; p < 64; ++p) { s += x[p]; s2 += x[p] * x[p]; }
    s  += __shfl_xor(s, 1, 64);  s  += __shfl_xor(s, 2, 64);
    s2 += __shfl_xor(s2, 1, 64); s2 += __shfl_xor(s2, 2, 64);
    float m = s * (1.f / 256.f);
    float var = s2 * (1.f / 256.f) - m * m;
    float inv = rsqrtf(var + 1e-5f);
    const float* fs = fn_s + q * 64;
    const float* fb = fn_b + q * 64;
#pragma unroll
    for (int j = 0; j < 8; ++j) {
      float4 fs0 = *(const float4*)(fs + j * 8);
      float4 fs1 = *(const float4*)(fs + j * 8 + 4);
      float4 fb0 = *(const float4*)(fb + j * 8);
      float4 fb1 = *(const float4*)(fb + j * 8 + 4);
      u16 yy[8] __attribute__((aligned(16)));
      yy[0] = f2b((x[j*8+0] - m) * inv * fs0.x + fb0.x);
      yy[1] = f2b((x[j*8+1] - m) * inv * fs0.y + fb0.y);
      yy[2] = f2b((x[j*8+2] - m) * inv * fs0.z + fb0.z);
      yy[3] = f2b((x[j*8+3] - m) * inv * fs0.w + fb0.w);
      yy[4] = f2b((x[j*8+4] - m) * inv * fs1.x + fb1.x);
      yy[5] = f2b((x[j*8+5] - m) * inv * fs1.y + fb1.y);
      yy[6] = f2b((x[j*8+6] - m) * inv * fs1.z + fb1.z);
      yy[7] = f2b((x[j*8+7] - m) * inv * fs1.w + fb1.w);
      int cch = q * 8 + j;
      *(uint4*)&smem[r * 256 + ((cch ^ (r & 7)) * 8)] = *(uint4*)yy;
    }
  }

  // ---- gemm0: acc = A0 @ W0t^T   (K=256, N=512; wave = 128 cols); B ring-2
  u32 bOff0[8];
#pragma unroll
  for (int j = 0; j < 8; ++j)
    bOff0[j] = (u32)(wn + j * 16 + lm) * 256u + (u32)(quad * 8);
  f32x4 acc[4][8] = {};
  bf16x8 bR[2][8];
#pragma unroll
  for (int p = 0; p < 2; ++p)
#pragma unroll
    for (int j = 0; j < 8; ++j)
      bR[p][j] = *(const bf16x8*)(W0t + bOff0[j] + p * 32);
  __syncthreads();   // B1: A0 staged

#pragma unroll
  for (int g = 0; g < 8; ++g) {
    bf16x8 cur[8];
#pragma unroll
    for (int j = 0; j < 8; ++j) cur[j] = bR[g & 1][j];
    if (g + 2 < 8) {
#pragma unroll
      for (int j = 0; j < 8; ++j)
        bR[g & 1][j] = *(const bf16x8*)(W0t + bOff0[j] + (g + 2) * 32);
    }
    const int kc = g * 4;
    bf16x8 af[4];
#pragma unroll
    for (int i2 = 0; i2 < 4; ++i2)
      af[i2] = *(const bf16x8*)&smem[(i2 * 16 + lm) * 256 + (((quad + kc) ^ l7) * 8)];
#pragma unroll
    for (int i2 = 0; i2 < 4; ++i2)
#pragma unroll
      for (int j = 0; j < 8; ++j)
        acc[i2][j] = MFMA(af[i2], cur[j], acc[i2][j], 0, 0, 0);
  }

  // ---- coalesced obs_n write: unswizzle A0 LDS -> global (32 KB/block).
  // A0 is read-only here and stays intact until the e0 overwrite after B2,
  // which no wave reaches before its own copy completes (B2 fences).
  {
    u16* dst = obs_n + (size_t)rowBase * 256;
#pragma unroll
    for (int it = 0; it < 8; ++it) {
      int li = it * 256 + tid;          // linear uint4 index, 0..2047
      int r = li >> 5, c = li & 31;     // row 0..63, chunk 0..31
      *(uint4*)(dst + li * 8) =
          *(const uint4*)&smem[r * 256 + ((c ^ (r & 7)) * 8)];
    }
  }

  // ---- ReLU + LN0 partials (biases in registers)
  {
    float b0v[8];
#pragma unroll
    for (int j = 0; j < 8; ++j) b0v[j] = b0[wn + j * 16 + lm];
#pragma unroll
    for (int i2 = 0; i2 < 4; ++i2) {
#pragma unroll
      for (int r2 = 0; r2 < 4; ++r2) {
        float s = 0.f, ss = 0.f;
#pragma unroll
        for (int j = 0; j < 8; ++j) {
          float v = fmaxf(acc[i2][j][r2] + b0v[j], 0.f);
          acc[i2][j][r2] = v;
          s += v; ss += v * v;
        }
#pragma unroll
        for (int o = 1; o < 16; o <<= 1) { s += __shfl_xor(s, o, 64); ss += __shfl_xor(ss, o, 64); }
        if (lm == 0) {
          int row = i2 * 16 + quad * 4 + r2;
          redS[row * 4 + wave] = s;
          redSS[row * 4 + wave] = ss;
        }
      }
    }
  }
  __syncthreads();   // B2: red0 done, A0 reads done, obs_n copies done

  // ---- LN0 finalize -> e0 bf16 into [0,65536)B (overlays dead A0)
  {
    float s0v[8], s0b[8];
#pragma unroll
    for (int j = 0; j < 8; ++j) {
      s0v[j] = ln0sc[wn + j * 16 + lm];
      s0b[j] = ln0bi[wn + j * 16 + lm];
    }
#pragma unroll
    for (int i2 = 0; i2 < 4; ++i2) {
#pragma unroll
      for (int r2 = 0; r2 < 4; ++r2) {
        int row = i2 * 16 + quad * 4 + r2;
        float ts  = redS[row * 4 + 0] + redS[row * 4 + 1] + redS[row * 4 + 2] + redS[row * 4 + 3];
        float tss = redSS[row * 4 + 0] + redSS[row * 4 + 1] + redSS[row * 4 + 2] + redSS[row * 4 + 3];
        float m = ts * (1.f / 512.f);
        float var = tss * (1.f / 512.f) - m * m;
        float inv = rsqrtf(var + 1e-5f);
#pragma unroll
        for (int j = 0; j < 8; ++j) {
          int col = wn + j * 16 + lm;
          float y = (acc[i2][j][r2] - m) * inv * s0v[j] + s0b[j];
          smem[row * 512 + (((col >> 3) ^ (row & 7)) * 8) + (col & 7)] = f2b(y);
        }
      }
    }
  }
  // gemm1 B preload before the barrier (hide L2 latency under the drain)
  u32 bOff1[8];
#pragma unroll
  for (int j = 0; j < 8; ++j)
    bOff1[j] = (u32)(wn + j * 16 + lm) * 512u + (u32)(quad * 8);
#pragma unroll
  for (int p = 0; p < 2; ++p)
#pragma unroll
    for (int j = 0; j < 8; ++j)
      bR[p][j] = *(const bf16x8*)(W1t + bOff1[j] + p * 32);
  __syncthreads();   // B3: e0 visible; red reusable

  // ---- gemm1: acc = e0 @ W1t^T   (K=512, N=512); B ring-2
#pragma unroll
  for (int i2 = 0; i2 < 4; ++i2)
#pragma unroll
    for (int j = 0; j < 8; ++j)
      acc[i2][j] = (f32x4){0.f, 0.f, 0.f, 0.f};
#pragma unroll
  for (int g = 0; g < 16; ++g) {
    bf16x8 cur[8];
#pragma unroll
    for (int j = 0; j < 8; ++j) cur[j] = bR[g & 1][j];
    if (g + 2 < 16) {
#pragma unroll
      for (int j = 0; j < 8; ++j)
        bR[g & 1][j] = *(const bf16x8*)(W1t + bOff1[j] + (g + 2) * 32);
    }
    const int kc = g * 4;
    bf16x8 af[4];
#pragma unroll
    for (int i2 = 0; i2 < 4; ++i2)
      af[i2] = *(const bf16x8*)&smem[(i2 * 16 + lm) * 512 + (((quad + kc) ^ l7) * 8)];
#pragma unroll
    for (int i2 = 0; i2 < 4; ++i2)
#pragma unroll
      for (int j = 0; j < 8; ++j)
        acc[i2][j] = MFMA(af[i2], cur[j], acc[i2][j], 0, 0, 0);
  }

  // ---- ReLU + LN1 partials
  {
    float b1v[8];
#pragma unroll
    for (int j = 0; j < 8; ++j) b1v[j] = b1[wn + j * 16 + lm];
#pragma unroll
    for (int i2 = 0; i2 < 4; ++i2) {
#pragma unroll
      for (int r2 = 0; r2 < 4; ++r2) {
        float s = 0.f, ss = 0.f;
#pragma unroll
        for (int j = 0; j < 8; ++j) {
          float v = fmaxf(acc[i2][j][r2] + b1v[j], 0.f);
          acc[i2][j][r2] = v;
          s += v; ss += v * v;
        }
#pragma unroll
        for (int o = 1; o < 16; o <<= 1) { s += __shfl_xor(s, o, 64); ss += __shfl_xor(ss, o, 64); }
        if (lm == 0) {
          int row = i2 * 16 + quad * 4 + r2;
          redS[row * 4 + wave] = s;
          redSS[row * 4 + wave] = ss;
        }
      }
    }
  }
  __syncthreads();   // B4: red1 done; all e0 reads done

  // ---- LN1 finalize -> LDS out-tile (linear [64][512], overlays dead e0)
  {
    float s1v[8], s1b[8];
#pragma unroll
    for (int j = 0; j < 8; ++j) {
      s1v[j] = ln1sc[wn + j * 16 + lm];
      s1b[j] = ln1bi[wn + j * 16 + lm];
    }
#pragma unroll
    for (int i2 = 0; i2 < 4; ++i2) {
#pragma unroll
      for (int r2 = 0; r2 < 4; ++r2) {
        int row = i2 * 16 + quad * 4 + r2;
        float ts  = redS[row * 4 + 0] + redS[row * 4 + 1] + redS[row * 4 + 2] + redS[row * 4 + 3];
        float tss = redSS[row * 4 + 0] + redSS[row * 4 + 1] + redSS[row * 4 + 2] + redSS[row * 4 + 3];
        float m = ts * (1.f / 512.f);
        float var = tss * (1.f / 512.f) - m * m;
        float inv = rsqrtf(var + 1e-5f);
#pragma unroll
        for (int j = 0; j < 8; ++j) {
          int col = wn + j * 16 + lm;
          float y = (acc[i2][j][r2] - m) * inv * s1v[j] + s1b[j];
          smem[row * 512 + col] = f2b(y);
        }
      }
    }
  }
  __syncthreads();   // B5: out-tile complete

  // ---- coalesced copy LDS -> bufB (64 KB; 4 KB per block-instruction)
  {
    u16* dst = C + (size_t)rowBase * 512;
#pragma unroll
    for (int it = 0; it < 16; ++it) {
      int idx = (it * 256 + tid) * 8;   // u16 units
      *(uint4*)(dst + idx) = *(const uint4*)&smem[idx];
    }
  }
}

// ---------------------------------------------------------------- route_head (round-2 verified, 67-68 us)
__global__ __launch_bounds__(256, 4) void route_head(
    const u16* __restrict__ obs_n, const u16* __restrict__ e,
    const u16* __restrict__ Wr0t, const float* __restrict__ br0,
    const u16* __restrict__ Wr1t, const float* __restrict__ br1,
    const u16* __restrict__ Wh0t, const float* __restrict__ bh0,
    const float* __restrict__ Wh1, const float* __restrict__ bh1,
    const float* __restrict__ Wh2, const float* __restrict__ bh2,
    const float* __restrict__ avail,
    const int* __restrict__ bucket, const int* __restrict__ baseArr,
    const int* __restrict__ cntArr, float* __restrict__ outLogits)
{
  __shared__ __align__(16) u16 sm[20480];   // 40960 B
  const int tid = threadIdx.x;

  int cA0, cA1, cA2, cA3, cA4, cA5, bA0, bA1, bA2, bA3, bA4, bA5;
  {
    int4 ca = *(const int4*)cntArr;  int2 cb = *(const int2*)(cntArr + 4);
    int4 ba = *(const int4*)baseArr; int2 bb = *(const int2*)(baseArr + 4);
    cA0 = ca.x; cA1 = ca.y; cA2 = ca.z; cA3 = ca.w; cA4 = cb.x; cA5 = cb.y;
    bA0 = ba.x; bA1 = ba.y; bA2 = ba.z; bA3 = ba.w; bA4 = bb.x; bA5 = bb.y;
  }
  int role = -1, rem = blockIdx.x, cnt = 0, roleBase = 0;
#define TRY_ROLE(k, ck, bk)                                        \
  if (role < 0) {                                                  \
    int tiles = ((ck) + 31) >> 5;                                  \
    if (rem < tiles) { role = (k); cnt = (ck); roleBase = (bk); }  \
    else rem -= tiles;                                             \
  }
  TRY_ROLE(0, cA0, bA0) TRY_ROLE(1, cA1, bA1) TRY_ROLE(2, cA2, bA2)
  TRY_ROLE(3, cA3, bA3) TRY_ROLE(4, cA4, bA4) TRY_ROLE(5, cA5, bA5)
#undef TRY_ROLE
  if (role < 0) return;
  const int limit = cnt;
  const int rowBase = rem * 32;

  const int lane = tid & 63, wave = tid >> 6;
  const int quad = lane >> 4, lm = lane & 15, l7 = lm & 7;

#pragma unroll
  for (int r = 0; r < 8; ++r) {
    int lrow = r * 4 + wave;
    int i = rowBase + lrow;
    if (i >= limit) i = rowBase;
    int grow = bucket[roleBase + i];
    int chunk = tid & 63;
    int sw = (chunk & 56) | ((chunk ^ lrow) & 7);
    gll16(e + (u32)grow * 512u + (u32)(sw * 8), &sm[r * 2048 + wave * 512]);
  }

  int growA0, growA1;
  {
    int i0 = rowBase + lm;        if (i0 >= limit) i0 = rowBase;
    int i1 = rowBase + 16 + lm;   if (i1 >= limit) i1 = rowBase;
    growA0 = bucket[roleBase + i0];
    growA1 = bucket[roleBase + i1];
  }
  const u16* Ag0 = obs_n + (size_t)growA0 * 256;
  const u16* Ag1 = obs_n + (size_t)growA1 * 256;

  // ---- stage0
  const int wn0 = wave * 32;
  const u16* B0 = Wr0t + (size_t)role * 128 * 256;
  f32x4 acc0[2][2] = {};
  bf16x8 b0R[2][2];
#pragma unroll
  for (int p = 0; p < 2; ++p)
#pragma unroll
    for (int j = 0; j < 2; ++j)
      b0R[p][j] = *(const bf16x8*)(B0 + (u32)(wn0 + j * 16 + lm) * 256u + (u32)(quad * 8 + p * 32));
  bf16x8 aR[4][2];
#pragma unroll
  for (int p = 0; p < 4; ++p) {
    aR[p][0] = *(const bf16x8*)(Ag0 + (u32)(quad * 8 + p * 32));
    aR[p][1] = *(const bf16x8*)(Ag1 + (u32)(quad * 8 + p * 32));
  }
  float bias0[2] = { br0[role * 128 + wn0 + lm], br0[role * 128 + wn0 + 16 + lm] };
#pragma unroll
  for (int it = 0; it < 8; ++it) {
    bf16x8 a0 = aR[it & 3][0], a1 = aR[it & 3][1];
    bf16x8 cur0 = b0R[it & 1][0], cur1 = b0R[it & 1][1];
    if (it + 2 < 8) {
#pragma unroll
      for (int j = 0; j < 2; ++j)
        b0R[it & 1][j] = *(const bf16x8*)(B0 + (u32)(wn0 + j * 16 + lm) * 256u + (u32)(quad * 8 + (it + 2) * 32));
    }
    if (it + 4 < 8) {
      aR[it & 3][0] = *(const bf16x8*)(Ag0 + (u32)(quad * 8 + (it + 4) * 32));
      aR[it & 3][1] = *(const bf16x8*)(Ag1 + (u32)(quad * 8 + (it + 4) * 32));
    }
    acc0[0][0] = MFMA(a0, cur0, acc0[0][0], 0, 0, 0);
    acc0[0][1] = MFMA(a0, cur1, acc0[0][1], 0, 0, 0);
    acc0[1][0] = MFMA(a1, cur0, acc0[1][0], 0, 0, 0);
    acc0[1][1] = MFMA(a1, cur1, acc0[1][1], 0, 0, 0);
  }
  u16* r1 = sm + 16384;
#pragma unroll
  for (int i2 = 0; i2 < 2; ++i2) {
#pragma unroll
    for (int r2 = 0; r2 < 4; ++r2) {
      int row = i2 * 16 + quad * 4 + r2;
#pragma unroll
      for (int j = 0; j < 2; ++j) {
        int col = wn0 + j * 16 + lm;
        float v = fmaxf(acc0[i2][j][r2] + bias0[j], 0.f);
        r1[row * 128 + (((col >> 3) ^ (row & 7)) * 8) + (col & 7)] = f2b(v);
      }
    }
  }
  __syncthreads();   // B1: r1 ready; drains e-staging vmcnt

  // ---- stage1: two 64-col halves
  const int wn1 = wave * 128;
  const u16* B1 = Wr1t + (size_t)role * 512 * 128;
#pragma unroll
  for (int h = 0; h < 2; ++h) {
    const int wnh = wn1 + h * 64;
    float b1v[4];
#pragma unroll
    for (int j = 0; j < 4; ++j) b1v[j] = br1[role * 512 + wnh + j * 16 + lm];
    f32x4 acc1[2][4] = {};
    bf16x8 b1P[4];
#pragma unroll
    for (int j = 0; j < 4; ++j)
      b1P[j] = *(const bf16x8*)(B1 + (u32)(wnh + j * 16 + lm) * 128u + (u32)(quad * 8));
#pragma unroll
    for (int kk = 0; kk < 128; kk += 32) {
      bf16x8 b1N[4];
      if (kk + 32 < 128) {
#pragma unroll
        for (int j = 0; j < 4; ++j)
          b1N[j] = *(const bf16x8*)(B1 + (u32)(wnh + j * 16 + lm) * 128u + (u32)(quad * 8 + kk + 32));
      }
      const int kc = kk >> 3;
      bf16x8 af[2];
#pragma unroll
      for (int i2 = 0; i2 < 2; ++i2)
        af[i2] = *(const bf16x8*)&r1[(i2 * 16 + lm) * 128 + (((quad + kc) ^ l7) * 8)];
#pragma unroll
      for (int i2 = 0; i2 < 2; ++i2)
#pragma unroll
        for (int j = 0; j < 4; ++j)
          acc1[i2][j] = MFMA(af[i2], b1P[j], acc1[i2][j], 0, 0, 0);
      if (kk + 32 < 128) {
#pragma unroll
        for (int j = 0; j < 4; ++j) b1P[j] = b1N[j];
      }
    }
#pragma unroll
    for (int i2 = 0; i2 < 2; ++i2) {
#pragma unroll
      for (int r2 = 0; r2 < 4; ++r2) {
        int row = i2 * 16 + quad * 4 + r2;
#pragma unroll
        for (int j = 0; j < 4; ++j) {
          int col = wnh + j * 16 + lm;
          int addr = row * 512 + (((col >> 3) ^ (row & 7)) * 8) + (col & 7);
          float v = fmaxf(acc1[i2][j][r2] + b1v[j], 0.f) + b2f(sm[addr]);
          sm[addr] = f2b(v);
        }
      }
    }
  }
  __syncthreads();

  // ---- stage2
  const int wn2 = wave * 16;
  const u16* B2 = Wh0t + (size_t)role * 64 * 512;
  float b2v = bh0[role * 64 + wn2 + lm];
  f32x4 acc2[2] = {};
  bf16x8 b2R[4];
#pragma unroll
  for (int p = 0; p < 4; ++p)
    b2R[p] = *(const bf16x8*)(B2 + (u32)(wn2 + lm) * 512u + (u32)(quad * 8 + p * 32));
#pragma unroll
  for (int it = 0; it < 16; ++it) {
    bf16x8 cur = b2R[it & 3];
    if (it + 4 < 16)
      b2R[it & 3] = *(const bf16x8*)(B2 + (u32)(wn2 + lm) * 512u + (u32)(quad * 8 + (it + 4) * 32));
    const int kc = it * 4;
    bf16x8 af[2];
#pragma unroll
    for (int i2 = 0; i2 < 2; ++i2)
      af[i2] = *(const bf16x8*)&sm[(i2 * 16 + lm) * 512 + (((quad + kc) ^ l7) * 8)];
#pragma unroll
    for (int i2 = 0; i2 < 2; ++i2)
      acc2[i2] = MFMA(af[i2], cur, acc2[i2], 0, 0, 0);
  }
  u16* h0s = sm + 16384;
#pragma unroll
  for (int i2 = 0; i2 < 2; ++i2) {
#pragma unroll
    for (int r2 = 0; r2 < 4; ++r2) {
      int row = i2 * 16 + quad * 4 + r2;
      int col = wn2 + lm;
      h0s[row * 68 + col] = f2b(fmaxf(acc2[i2][r2] + b2v, 0.f));
    }
  }
  __syncthreads();

  // ---- stage3
  {
    float* h1s = (float*)&sm[16384];
    const int r = tid >> 3;
    const int n0 = (tid & 7) * 4;
    const bool valid = (rowBase + r) < limit;
    const float* W1k = Wh1 + (size_t)role * 64 * 32;
    const float* W2k = Wh2 + (size_t)role * 32 * 32;
    float4 a1 = *(const float4*)(bh1 + role * 32 + n0);
#pragma unroll 8
    for (int j = 0; j < 64; ++j) {
      float hj = b2f(h0s[r * 68 + j]);
      float4 wv = *(const float4*)(W1k + j * 32 + n0);
      a1.x += hj * wv.x; a1.y += hj * wv.y; a1.z += hj * wv.z; a1.w += hj * wv.w;
    }
    a1.x = fmaxf(a1.x, 0.f); a1.y = fmaxf(a1.y, 0.f);
    a1.z = fmaxf(a1.z, 0.f); a1.w = fmaxf(a1.w, 0.f);
    __syncthreads();
    h1s[r * 36 + n0 + 0] = a1.x;
    h1s[r * 36 + n0 + 1] = a1.y;
    h1s[r * 36 + n0 + 2] = a1.z;
    h1s[r * 36 + n0 + 3] = a1.w;
    __syncthreads();
    float4 a2 = *(const float4*)(bh2 + role * 32 + n0);
#pragma unroll 8
    for (int n = 0; n < 32; ++n) {
      float hn = h1s[r * 36 + n];
      float4 wv = *(const float4*)(W2k + n * 32 + n0);
      a2.x += hn * wv.x; a2.y += hn * wv.y; a2.z += hn * wv.z; a2.w += hn * wv.w;
    }
    if (valid) {
      int g = bucket[roleBase + rowBase + r];
      float4 av = *(const float4*)(avail + (size_t)g * 32 + n0);
      float4 o;
      o.x = (av.x > 0.5f) ? a2.x : -1e10f;
      o.y = (av.y > 0.5f) ? a2.y : -1e10f;
      o.z = (av.z > 0.5f) ? a2.z : -1e10f;
      o.w = (av.w > 0.5f) ? a2.w : -1e10f;
      *(float4*)(outLogits + (size_t)g * 32 + n0) = o;
    }
  }
}

// ---------------------------------------------------------------- launcher
extern "C" void kernel_launch(void* const* d_in, const int* in_sizes, int n_in,
                              void* d_out, int out_size, void* d_ws, size_t ws_size,
                              hipStream_t stream)
{
  const float* rnn  = (const float*)d_in[0];
  const float* obs  = (const float*)d_in[1];
  const float* avail= (const float*)d_in[3];
  const int*   rid  = (const int*)d_in[4];
  const float* fn_s = (const float*)d_in[5];
  const float* fn_b = (const float*)d_in[6];
  const float* W0   = (const float*)d_in[7];
  const float* b0   = (const float*)d_in[8];
  const float* ln0s = (const float*)d_in[9];
  const float* ln0b = (const float*)d_in[10];
  const float* W1   = (const float*)d_in[11];
  const float* b1   = (const float*)d_in[12];
  const float* ln1s = (const float*)d_in[13];
  const float* ln1b = (const float*)d_in[14];
  const float* Wr0  = (const float*)d_in[15];
  const float* br0  = (const float*)d_in[16];
  const float* Wr1  = (const float*)d_in[17];
  const float* br1  = (const float*)d_in[18];
  const float* Wh0  = (const float*)d_in[19];
  const float* bh0  = (const float*)d_in[20];
  const float* Wh1  = (const float*)d_in[21];
  const float* bh1  = (const float*)d_in[22];
  const float* Wh2  = (const float*)d_in[23];
  const float* bh2  = (const float*)d_in[24];

  const int ROWS = 32768;

  char* w = (char*)d_ws;
  auto carve = [&](size_t bytes) { char* p = w; w += (bytes + 255) & ~(size_t)255; return p; };
  u16* obs_n  = (u16*)carve((size_t)ROWS * 256 * 2);
  u16* bufB   = (u16*)carve((size_t)ROWS * 512 * 2);   // e
  u16* W0t    = (u16*)carve((size_t)512 * 256 * 2);
  u16* W1t    = (u16*)carve((size_t)512 * 512 * 2);
  u16* Wr0t   = (u16*)carve((size_t)6 * 128 * 256 * 2);
  u16* Wr1t   = (u16*)carve((size_t)6 * 512 * 128 * 2);
  u16* Wh0t   = (u16*)carve((size_t)6 * 64 * 512 * 2);
  int* bucket = (int*)carve((size_t)ROWS * 4);
  int* blkCnt = (int*)carve((size_t)128 * NROLE * 4);
  int* baseArr= (int*)carve(256);
  int* cntArr = (int*)carve(256);

  float* outLogits = (float*)d_out + (size_t)1024 * 512;

  // mega0: weight transposes + role_count + rnn passthrough
  mega0<<<1408, 256, 0, stream>>>(W0, W1, Wr0, Wr1, Wh0, W0t, W1t, Wr0t, Wr1t, Wh0t,
                                  rid, blkCnt, rnn, (float*)d_out);

  // fused obs-LN + gemm0 + LN0 + gemm1 + LN1 (blocks 0..511) and fill2 (512..639)
  base2<<<640, 256, 0, stream>>>(obs, fn_s, fn_b, W0t, b0, ln0s, ln0b,
                                 W1t, b1, ln1s, ln1b, obs_n, bufB,
                                 rid, blkCnt, bucket, baseArr, cntArr);

  // fused role route + full head (round-2 verified)
  route_head<<<1029, 256, 0, stream>>>(obs_n, bufB, Wr0t, br0, Wr1t, br1, Wh0t, bh0,
                                       Wh1, bh1, Wh2, bh2, avail,
                                       bucket, baseArr, cntArr, outLogits);
}